// Round 1
// baseline (859.293 us; speedup 1.0000x reference)
//
#include <hip/hip_runtime.h>
#include <math.h>

#define N_NODES 50000
#define N_EDGES 20000
#define NNZ_CT  500000

// ---------------- GEMM: C[M,N] = A[M,K] * B[K,N], fp32, tiled ----------------
#define BM 128
#define BN 64
#define BK 16

__global__ __launch_bounds__(256) void gemm_f32(
    const float* __restrict__ A, const float* __restrict__ B,
    float* __restrict__ C, int M, int N, int K)
{
    __shared__ float As[BK][BM];
    __shared__ float Bs[BK][BN];
    const int tid = threadIdx.x;
    const int m0 = blockIdx.y * BM;
    const int n0 = blockIdx.x * BN;
    const int tx = tid & 15;   // 16 col-groups of 4 cols
    const int ty = tid >> 4;   // 16 row-groups of 8 rows

    float acc[8][4];
#pragma unroll
    for (int i = 0; i < 8; i++)
#pragma unroll
        for (int j = 0; j < 4; j++) acc[i][j] = 0.f;

    for (int k0 = 0; k0 < K; k0 += BK) {
        // A tile: 128x16 floats = 512 float4, 2 per thread
#pragma unroll
        for (int l = 0; l < 2; l++) {
            int idx = tid + l * 256;        // 0..511
            int row = idx >> 2;             // 0..127
            int kq  = (idx & 3) * 4;        // 0,4,8,12
            int gr = m0 + row; if (gr >= M) gr = M - 1;  // clamp; stores guarded
            float4 v = *(const float4*)(A + (size_t)gr * K + k0 + kq);
            As[kq + 0][row] = v.x;
            As[kq + 1][row] = v.y;
            As[kq + 2][row] = v.z;
            As[kq + 3][row] = v.w;
        }
        // B tile: 16x64 floats, 4 scalars per thread (col-guarded for N=40)
        {
            int col4 = (tid & 15) * 4;
            int kr   = tid >> 4;
            const float* brow = B + (size_t)(k0 + kr) * N;
#pragma unroll
            for (int j = 0; j < 4; j++) {
                int gc = n0 + col4 + j;
                Bs[kr][col4 + j] = (gc < N) ? brow[gc] : 0.f;
            }
        }
        __syncthreads();
#pragma unroll
        for (int k = 0; k < BK; k++) {
            float a[8], b[4];
#pragma unroll
            for (int i = 0; i < 8; i++) a[i] = As[k][ty * 8 + i];
#pragma unroll
            for (int j = 0; j < 4; j++) b[j] = Bs[k][tx * 4 + j];
#pragma unroll
            for (int i = 0; i < 8; i++)
#pragma unroll
                for (int j = 0; j < 4; j++)
                    acc[i][j] = fmaf(a[i], b[j], acc[i][j]);
        }
        __syncthreads();
    }
#pragma unroll
    for (int i = 0; i < 8; i++) {
        int gr = m0 + ty * 8 + i;
        if (gr >= M) continue;
        int gc0 = n0 + tx * 4;
        if (gc0 + 3 < N) {
            float4 v = { acc[i][0], acc[i][1], acc[i][2], acc[i][3] };
            *(float4*)(C + (size_t)gr * N + gc0) = v;
        } else {
#pragma unroll
            for (int j = 0; j < 4; j++)
                if (gc0 + j < N) C[(size_t)gr * N + gc0 + j] = acc[i][j];
        }
    }
}

// ---------------- degree count ----------------
__global__ void count_kernel(const int* __restrict__ node_idx,
                             const int* __restrict__ edge_idx,
                             int* __restrict__ cnt_e, int* __restrict__ cnt_v)
{
    int i = blockIdx.x * blockDim.x + threadIdx.x;
    if (i < NNZ_CT) {
        atomicAdd(&cnt_e[edge_idx[i]], 1);
        atomicAdd(&cnt_v[node_idx[i]], 1);
    }
}

// ---------------- single-block exclusive scan + inverse degree ----------------
__global__ __launch_bounds__(1024) void scan_kernel(const int* __restrict__ cnt,
                                                    int* __restrict__ off,
                                                    float* __restrict__ invdeg, int n)
{
    __shared__ int sbuf[1024];
    __shared__ int carry_s;
    int tid = threadIdx.x;
    if (tid == 0) carry_s = 0;
    __syncthreads();
    for (int base = 0; base < n; base += 1024) {
        int i = base + tid;
        int x = (i < n) ? cnt[i] : 0;
        sbuf[tid] = x;
        __syncthreads();
        for (int o = 1; o < 1024; o <<= 1) {
            int t = (tid >= o) ? sbuf[tid - o] : 0;
            __syncthreads();
            sbuf[tid] += t;
            __syncthreads();
        }
        int incl = sbuf[tid];
        int carry = carry_s;
        if (i < n) {
            off[i] = carry + incl - x;
            invdeg[i] = 1.0f / fmaxf((float)x, 1.0f);
        }
        __syncthreads();
        if (tid == 0) carry_s = carry + sbuf[1023];
        __syncthreads();
    }
    if (tid == 0) off[n] = carry_s;
}

// ---------------- CSR fill ----------------
__global__ void fill_kernel(const int* __restrict__ node_idx,
                            const int* __restrict__ edge_idx,
                            const int* __restrict__ off_e, const int* __restrict__ off_v,
                            int* __restrict__ cur_e, int* __restrict__ cur_v,
                            int* __restrict__ csr_e_nodes, int* __restrict__ csr_v_edges)
{
    int i = blockIdx.x * blockDim.x + threadIdx.x;
    if (i < NNZ_CT) {
        int v = node_idx[i], e = edge_idx[i];
        int pe = atomicAdd(&cur_e[e], 1);
        csr_e_nodes[off_e[e] + pe] = v;
        int pv = atomicAdd(&cur_v[v], 1);
        csr_v_edges[off_v[v] + pv] = e;
    }
}

// ---------------- mean-aggregation, F=256, wave per segment ----------------
__global__ __launch_bounds__(256) void agg_mean256(
    const float* __restrict__ src, float* __restrict__ dst,
    const int* __restrict__ offs, const int* __restrict__ lists,
    const float* __restrict__ invdeg, const float* __restrict__ bias,
    int nseg, int do_relu)
{
    int w = (blockIdx.x * 256 + threadIdx.x) >> 6;
    int lane = threadIdx.x & 63;
    if (w >= nseg) return;
    int s = offs[w], e = offs[w + 1];
    float4 acc = make_float4(0.f, 0.f, 0.f, 0.f);
    for (int j = s; j < e; ++j) {
        int r = lists[j];
        const float4 v = *(const float4*)(src + (size_t)r * 256 + lane * 4);
        acc.x += v.x; acc.y += v.y; acc.z += v.z; acc.w += v.w;
    }
    float sc = invdeg[w];
    acc.x *= sc; acc.y *= sc; acc.z *= sc; acc.w *= sc;
    if (bias) {
        const float4 b = *(const float4*)(bias + lane * 4);
        acc.x += b.x; acc.y += b.y; acc.z += b.z; acc.w += b.w;
    }
    if (do_relu) {
        acc.x = fmaxf(acc.x, 0.f); acc.y = fmaxf(acc.y, 0.f);
        acc.z = fmaxf(acc.z, 0.f); acc.w = fmaxf(acc.w, 0.f);
    }
    *(float4*)(dst + (size_t)w * 256 + lane * 4) = acc;
}

// ---------------- mean-aggregation, F=40 (edges) ----------------
__global__ __launch_bounds__(256) void agg_mean40(
    const float* __restrict__ src, float* __restrict__ dst,
    const int* __restrict__ offs, const int* __restrict__ lists,
    const float* __restrict__ invdeg, int nseg)
{
    int w = (blockIdx.x * 256 + threadIdx.x) >> 6;
    int lane = threadIdx.x & 63;
    if (w >= nseg) return;
    int s = offs[w], e = offs[w + 1];
    float acc = 0.f;
    if (lane < 40) {
        for (int j = s; j < e; ++j) {
            int r = lists[j];
            acc += src[(size_t)r * 40 + lane];
        }
        dst[(size_t)w * 40 + lane] = acc * invdeg[w];
    }
}

// ------- final E->V mean at F=40 + bias + log_softmax, wave per node -------
__global__ __launch_bounds__(256) void agg_v40_lsm(
    const float* __restrict__ efeat, float* __restrict__ out,
    const int* __restrict__ offs, const int* __restrict__ lists,
    const float* __restrict__ invdeg, const float* __restrict__ bias,
    int nseg)
{
    int w = (blockIdx.x * 256 + threadIdx.x) >> 6;
    int lane = threadIdx.x & 63;
    if (w >= nseg) return;
    int s = offs[w], e = offs[w + 1];
    float acc = 0.f;
    if (lane < 40) {
        for (int j = s; j < e; ++j) {
            int r = lists[j];
            acc += efeat[(size_t)r * 40 + lane];
        }
    }
    float val = (lane < 40) ? (acc * invdeg[w] + bias[lane]) : -1e30f;
    float m = val;
#pragma unroll
    for (int o = 32; o; o >>= 1) m = fmaxf(m, __shfl_xor(m, o));
    float ex = (lane < 40) ? expf(val - m) : 0.f;
    float ssum = ex;
#pragma unroll
    for (int o = 32; o; o >>= 1) ssum += __shfl_xor(ssum, o);
    if (lane < 40) out[(size_t)w * 40 + lane] = val - m - logf(ssum);
}

// ---------------- launch ----------------
extern "C" void kernel_launch(void* const* d_in, const int* in_sizes, int n_in,
                              void* d_out, int out_size, void* d_ws, size_t ws_size,
                              hipStream_t stream)
{
    const float* X        = (const float*)d_in[0];
    const int*   node_idx = (const int*)d_in[1];
    const int*   edge_idx = (const int*)d_in[2];
    const float* W1 = (const float*)d_in[3];
    const float* b1 = (const float*)d_in[4];
    const float* W2 = (const float*)d_in[5];
    const float* b2 = (const float*)d_in[6];
    const float* W3 = (const float*)d_in[7];
    const float* b3 = (const float*)d_in[8];
    float* out = (float*)d_out;

    char* p = (char*)d_ws;
    auto alloc = [&](size_t bytes) -> char* {
        char* r = p;
        p += (bytes + 255) & ~(size_t)255;
        return r;
    };
    int*   cnt_e = (int*)alloc((size_t)N_EDGES * 4);
    int*   cnt_v = (int*)alloc((size_t)N_NODES * 4);
    int*   cur_e = (int*)alloc((size_t)N_EDGES * 4);
    int*   cur_v = (int*)alloc((size_t)N_NODES * 4);
    int*   off_e = (int*)alloc((size_t)(N_EDGES + 1) * 4);
    int*   off_v = (int*)alloc((size_t)(N_NODES + 1) * 4);
    float* inv_e = (float*)alloc((size_t)N_EDGES * 4);
    float* inv_v = (float*)alloc((size_t)N_NODES * 4);
    int*   csr_e = (int*)alloc((size_t)NNZ_CT * 4);   // node ids grouped by edge
    int*   csr_v = (int*)alloc((size_t)NNZ_CT * 4);   // edge ids grouped by node
    float* bufA  = (float*)alloc((size_t)N_NODES * 256 * 4);
    float* bufB  = (float*)alloc((size_t)N_NODES * 256 * 4);
    float* bufE  = (float*)alloc((size_t)N_EDGES * 256 * 4);

    // zero the counters (cnt_e..cur_v span, incl. alignment padding)
    size_t zspan = (size_t)((char*)cur_v + (size_t)N_NODES * 4 - (char*)cnt_e);
    hipMemsetAsync(cnt_e, 0, zspan, stream);

    count_kernel<<<(NNZ_CT + 255) / 256, 256, 0, stream>>>(node_idx, edge_idx, cnt_e, cnt_v);
    scan_kernel<<<1, 1024, 0, stream>>>(cnt_e, off_e, inv_e, N_EDGES);
    scan_kernel<<<1, 1024, 0, stream>>>(cnt_v, off_v, inv_v, N_NODES);
    fill_kernel<<<(NNZ_CT + 255) / 256, 256, 0, stream>>>(
        node_idx, edge_idx, off_e, off_v, cur_e, cur_v, csr_e, csr_v);

    dim3 g256(256 / BN, (N_NODES + BM - 1) / BM);
    dim3 g40(1, (N_NODES + BM - 1) / BM);
    const int gE = (N_EDGES + 3) / 4;   // 4 waves/block
    const int gV = (N_NODES + 3) / 4;

    // layer 1: P1 = X@W1 -> bufA; e_feat -> bufE; H1 = relu(mean+b1) -> bufB
    gemm_f32<<<g256, 256, 0, stream>>>(X, W1, bufA, N_NODES, 256, 256);
    agg_mean256<<<gE, 256, 0, stream>>>(bufA, bufE, off_e, csr_e, inv_e, nullptr, N_EDGES, 0);
    agg_mean256<<<gV, 256, 0, stream>>>(bufE, bufB, off_v, csr_v, inv_v, b1, N_NODES, 1);

    // layer 2: P2 -> bufA; e_feat -> bufE; H2 -> bufB
    gemm_f32<<<g256, 256, 0, stream>>>(bufB, W2, bufA, N_NODES, 256, 256);
    agg_mean256<<<gE, 256, 0, stream>>>(bufA, bufE, off_e, csr_e, inv_e, nullptr, N_EDGES, 0);
    agg_mean256<<<gV, 256, 0, stream>>>(bufE, bufB, off_v, csr_v, inv_v, b2, N_NODES, 1);

    // layer 3: P3 [V,40] -> bufA; e_feat40 -> bufE; out = log_softmax(mean+b3)
    gemm_f32<<<g40, 256, 0, stream>>>(bufB, W3, bufA, N_NODES, 40, 256);
    agg_mean40<<<gE, 256, 0, stream>>>(bufA, bufE, off_e, csr_e, inv_e, N_EDGES);
    agg_v40_lsm<<<gV, 256, 0, stream>>>(bufE, out, off_v, csr_v, inv_v, b3, N_NODES);
    (void)in_sizes; (void)n_in; (void)out_size; (void)ws_size;
}

// Round 2
// 696.505 us; speedup vs baseline: 1.2337x; 1.2337x over previous
//
#include <hip/hip_runtime.h>
#include <math.h>

#define N_NODES 50000
#define N_EDGES 20000
#define NNZ_CT  500000
#define KDIM    256          // inner dim of all GEMMs
#define K32     8            // KDIM/32

typedef __attribute__((ext_vector_type(8))) short    short8v;
typedef __attribute__((ext_vector_type(4))) float    f32x4;
typedef __attribute__((ext_vector_type(8))) unsigned short ushort8v;
typedef __attribute__((ext_vector_type(4))) unsigned short ushort4v;

#define GLD16(g, l) __builtin_amdgcn_global_load_lds( \
    (const __attribute__((address_space(1))) unsigned int*)(g), \
    (__attribute__((address_space(3))) unsigned int*)(l), 16, 0, 0)

// split f into bf16 hi + bf16 lo (RNE both)
__device__ __forceinline__ void bf16_split(float f, unsigned short& h, unsigned short& l) {
    unsigned u = __float_as_uint(f);
    unsigned hb = (u + 0x7FFFu + ((u >> 16) & 1u)) >> 16;
    h = (unsigned short)hb;
    float r = f - __uint_as_float(hb << 16);
    unsigned ru = __float_as_uint(r);
    l = (unsigned short)((ru + 0x7FFFu + ((ru >> 16) & 1u)) >> 16);
}

// ---- convert fp32 A[M,256] -> fragment-tiled bf16 hi/lo ----
// layout: [(m16)*8 + k32]*512 + lane*8 + j, lane = (row&15) + 16*((k&31)>>3), j = k&7
__global__ __launch_bounds__(256) void convert_A_tiled(
    const float* __restrict__ A, unsigned short* __restrict__ Ah,
    unsigned short* __restrict__ Al, int m16_count)
{
    int t = blockIdx.x * 256 + threadIdx.x;
    if (t >= m16_count * 8 * 64) return;
    int lane = t & 63, k32 = (t >> 6) & 7, m16 = t >> 9;
    int row = m16 * 16 + (lane & 15);
    int k0  = k32 * 32 + (lane >> 4) * 8;
    const float* src = A + (size_t)row * KDIM + k0;
    float f[8];
    *(float4*)(f)     = *(const float4*)(src);
    *(float4*)(f + 4) = *(const float4*)(src + 4);
    ushort8v h, l;
#pragma unroll
    for (int j = 0; j < 8; j++) { unsigned short hh, ll; bf16_split(f[j], hh, ll); h[j] = hh; l[j] = ll; }
    size_t off = (((size_t)m16 * 8 + k32) << 9) + lane * 8;
    *(ushort8v*)(Ah + off) = h;
    *(ushort8v*)(Al + off) = l;
}

// ---- convert fp32 B[K,Ncols] -> fragment-tiled bf16 hi/lo (zero-pad cols) ----
__global__ __launch_bounds__(256) void convert_B_tiled(
    const float* __restrict__ B, unsigned short* __restrict__ Bh,
    unsigned short* __restrict__ Bl, int Ncols, int n16_count)
{
    int t = blockIdx.x * 256 + threadIdx.x;
    if (t >= n16_count * 8 * 64) return;
    int lane = t & 63, k32 = (t >> 6) & 7, n16 = t >> 9;
    int col = n16 * 16 + (lane & 15);
    int k0  = k32 * 32 + (lane >> 4) * 8;
    ushort8v h, l;
#pragma unroll
    for (int j = 0; j < 8; j++) {
        float f = (col < Ncols) ? B[(size_t)(k0 + j) * Ncols + col] : 0.f;
        unsigned short hh, ll; bf16_split(f, hh, ll); h[j] = hh; l[j] = ll;
    }
    size_t off = (((size_t)n16 * 8 + k32) << 9) + lane * 8;
    *(ushort8v*)(Bh + off) = h;
    *(ushort8v*)(Bl + off) = l;
}

// ---- MFMA split-bf16 GEMM: C[M,Ncols] = A*B, K=256, 128x128 tile ----
__global__ __launch_bounds__(256) void gemm_mfma_split(
    const unsigned short* __restrict__ Ah, const unsigned short* __restrict__ Al,
    const unsigned short* __restrict__ Bh, const unsigned short* __restrict__ Bl,
    float* __restrict__ C, int M, int Ncols, int ldC)
{
    __shared__ unsigned short lds[16384];      // A chunks [0,8192), B chunks [8192,16384)
    const int tid  = threadIdx.x;
    const int lane = tid & 63, wid = tid >> 6;
    const int wr = wid >> 1, wc = wid & 1;
    const int m0t = blockIdx.y * 8;            // base m16 tile
    const int n0t = blockIdx.x * 8;            // base n16 tile

    f32x4 acc[4][4] = {};

    for (int k32 = 0; k32 < K32; ++k32) {
#pragma unroll
        for (int i = 0; i < 4; ++i) {
            int c = i * 4 + wid;               // 0..15
            int half = c >> 3, st = c & 7;
            const unsigned short* gA = (half ? Al : Ah)
                + (((size_t)(m0t + st) * 8 + k32) << 9) + lane * 8;
            GLD16(gA, &lds[c * 512 + lane * 8]);
            const unsigned short* gB = (half ? Bl : Bh)
                + (((size_t)(n0t + st) * 8 + k32) << 9) + lane * 8;
            GLD16(gB, &lds[8192 + c * 512 + lane * 8]);
        }
        __syncthreads();
        short8v ah[4], al[4], bh[4], bl[4];
#pragma unroll
        for (int x = 0; x < 4; ++x) {
            ah[x] = *(const short8v*)&lds[(wr * 4 + x) * 512 + lane * 8];
            al[x] = *(const short8v*)&lds[(8 + wr * 4 + x) * 512 + lane * 8];
            bh[x] = *(const short8v*)&lds[8192 + (wc * 4 + x) * 512 + lane * 8];
            bl[x] = *(const short8v*)&lds[8192 + (8 + wc * 4 + x) * 512 + lane * 8];
        }
#pragma unroll
        for (int mi = 0; mi < 4; ++mi)
#pragma unroll
            for (int ni = 0; ni < 4; ++ni) {
                acc[mi][ni] = __builtin_amdgcn_mfma_f32_16x16x32_bf16(ah[mi], bh[ni], acc[mi][ni], 0, 0, 0);
                acc[mi][ni] = __builtin_amdgcn_mfma_f32_16x16x32_bf16(ah[mi], bl[ni], acc[mi][ni], 0, 0, 0);
                acc[mi][ni] = __builtin_amdgcn_mfma_f32_16x16x32_bf16(al[mi], bh[ni], acc[mi][ni], 0, 0, 0);
            }
        __syncthreads();
    }

#pragma unroll
    for (int mi = 0; mi < 4; ++mi) {
        int row0 = (m0t + wr * 4 + mi) * 16 + (lane >> 4) * 4;
#pragma unroll
        for (int ni = 0; ni < 4; ++ni) {
            int col = (n0t + wc * 4 + ni) * 16 + (lane & 15);
            if (col >= Ncols) continue;
#pragma unroll
            for (int r = 0; r < 4; ++r) {
                int row = row0 + r;
                if (row < M) C[(size_t)row * ldC + col] = acc[mi][ni][r];
            }
        }
    }
}

// ---------------- degree count ----------------
__global__ void count_kernel(const int* __restrict__ node_idx,
                             const int* __restrict__ edge_idx,
                             int* __restrict__ cnt_e, int* __restrict__ cnt_v)
{
    int i = blockIdx.x * blockDim.x + threadIdx.x;
    if (i < NNZ_CT) {
        atomicAdd(&cnt_e[edge_idx[i]], 1);
        atomicAdd(&cnt_v[node_idx[i]], 1);
    }
}

// -------- single-block shuffle-based exclusive scan + inverse degree --------
__global__ __launch_bounds__(1024) void scan_kernel(const int* __restrict__ cnt,
                                                    int* __restrict__ off,
                                                    float* __restrict__ invdeg, int n)
{
    __shared__ int wsum[16];
    __shared__ int carry_s;
    int tid = threadIdx.x, lane = tid & 63, wid = tid >> 6;
    if (tid == 0) carry_s = 0;
    __syncthreads();
    for (int base = 0; base < n; base += 1024) {
        int i = base + tid;
        int x = (i < n) ? cnt[i] : 0;
        int incl = x;
#pragma unroll
        for (int o = 1; o < 64; o <<= 1) { int t = __shfl_up(incl, o, 64); if (lane >= o) incl += t; }
        if (lane == 63) wsum[wid] = incl;
        __syncthreads();
        if (wid == 0) {
            int v = (lane < 16) ? wsum[lane] : 0;
#pragma unroll
            for (int o = 1; o < 16; o <<= 1) { int t = __shfl_up(v, o, 64); if (lane >= o) v += t; }
            if (lane < 16) wsum[lane] = v;
        }
        __syncthreads();
        int wpre = (wid == 0) ? 0 : wsum[wid - 1];
        int carry = carry_s;
        if (i < n) {
            off[i] = carry + wpre + incl - x;
            invdeg[i] = 1.0f / fmaxf((float)x, 1.0f);
        }
        __syncthreads();
        if (tid == 1023) carry_s = carry + wpre + incl;
        __syncthreads();
    }
    if (tid == 0) off[n] = carry_s;
}

// ---------------- CSR fill ----------------
__global__ void fill_kernel(const int* __restrict__ node_idx,
                            const int* __restrict__ edge_idx,
                            const int* __restrict__ off_e, const int* __restrict__ off_v,
                            int* __restrict__ cur_e, int* __restrict__ cur_v,
                            int* __restrict__ csr_e_nodes, int* __restrict__ csr_v_edges)
{
    int i = blockIdx.x * blockDim.x + threadIdx.x;
    if (i < NNZ_CT) {
        int v = node_idx[i], e = edge_idx[i];
        int pe = atomicAdd(&cur_e[e], 1);
        csr_e_nodes[off_e[e] + pe] = v;
        int pv = atomicAdd(&cur_v[v], 1);
        csr_v_edges[off_v[v] + pv] = e;
    }
}

// ---- V->E mean aggregation, F=256, fp32 out, wave per segment ----
__global__ __launch_bounds__(256) void agg_e256(
    const float* __restrict__ src, float* __restrict__ dst,
    const int* __restrict__ offs, const int* __restrict__ lists,
    const float* __restrict__ invdeg, int nseg)
{
    int w = (blockIdx.x * 256 + threadIdx.x) >> 6;
    int lane = threadIdx.x & 63;
    if (w >= nseg) return;
    int s = offs[w], e = offs[w + 1];
    float4 acc = make_float4(0.f, 0.f, 0.f, 0.f);
    for (int j = s; j < e; ++j) {
        int r = lists[j];
        const float4 v = *(const float4*)(src + (size_t)r * 256 + lane * 4);
        acc.x += v.x; acc.y += v.y; acc.z += v.z; acc.w += v.w;
    }
    float sc = invdeg[w];
    acc.x *= sc; acc.y *= sc; acc.z *= sc; acc.w *= sc;
    *(float4*)(dst + (size_t)w * 256 + lane * 4) = acc;
}

// ---- E->V mean + bias + relu, writes fragment-tiled bf16 hi/lo ----
__global__ __launch_bounds__(256) void agg_v256_tiled(
    const float* __restrict__ src, unsigned short* __restrict__ Hh,
    unsigned short* __restrict__ Hl,
    const int* __restrict__ offs, const int* __restrict__ lists,
    const float* __restrict__ invdeg, const float* __restrict__ bias, int nseg)
{
    int w = (blockIdx.x * 256 + threadIdx.x) >> 6;
    int lane = threadIdx.x & 63;
    if (w >= nseg) return;
    int s = offs[w], e = offs[w + 1];
    float4 acc = make_float4(0.f, 0.f, 0.f, 0.f);
    for (int j = s; j < e; ++j) {
        int r = lists[j];
        const float4 v = *(const float4*)(src + (size_t)r * 256 + lane * 4);
        acc.x += v.x; acc.y += v.y; acc.z += v.z; acc.w += v.w;
    }
    float sc = invdeg[w];
    const float4 b = *(const float4*)(bias + lane * 4);
    float f[4] = { fmaxf(acc.x * sc + b.x, 0.f), fmaxf(acc.y * sc + b.y, 0.f),
                   fmaxf(acc.z * sc + b.z, 0.f), fmaxf(acc.w * sc + b.w, 0.f) };
    int c0 = lane * 4;
    int m16 = w >> 4, k32 = c0 >> 5;
    int lanet = (w & 15) + 16 * ((c0 & 31) >> 3);
    int j0 = c0 & 7;
    size_t off = (((size_t)m16 * 8 + k32) << 9) + lanet * 8 + j0;
    ushort4v h, l;
#pragma unroll
    for (int j = 0; j < 4; j++) { unsigned short hh, ll; bf16_split(f[j], hh, ll); h[j] = hh; l[j] = ll; }
    *(ushort4v*)(Hh + off) = h;
    *(ushort4v*)(Hl + off) = l;
}

// ---------------- mean-aggregation, F=40 (edges) ----------------
__global__ __launch_bounds__(256) void agg_mean40(
    const float* __restrict__ src, float* __restrict__ dst,
    const int* __restrict__ offs, const int* __restrict__ lists,
    const float* __restrict__ invdeg, int nseg)
{
    int w = (blockIdx.x * 256 + threadIdx.x) >> 6;
    int lane = threadIdx.x & 63;
    if (w >= nseg) return;
    int s = offs[w], e = offs[w + 1];
    float acc = 0.f;
    if (lane < 40) {
        for (int j = s; j < e; ++j) {
            int r = lists[j];
            acc += src[(size_t)r * 40 + lane];
        }
        dst[(size_t)w * 40 + lane] = acc * invdeg[w];
    }
}

// ------- final E->V mean at F=40 + bias + log_softmax, wave per node -------
__global__ __launch_bounds__(256) void agg_v40_lsm(
    const float* __restrict__ efeat, float* __restrict__ out,
    const int* __restrict__ offs, const int* __restrict__ lists,
    const float* __restrict__ invdeg, const float* __restrict__ bias,
    int nseg)
{
    int w = (blockIdx.x * 256 + threadIdx.x) >> 6;
    int lane = threadIdx.x & 63;
    if (w >= nseg) return;
    int s = offs[w], e = offs[w + 1];
    float acc = 0.f;
    if (lane < 40) {
        for (int j = s; j < e; ++j) {
            int r = lists[j];
            acc += efeat[(size_t)r * 40 + lane];
        }
    }
    float val = (lane < 40) ? (acc * invdeg[w] + bias[lane]) : -1e30f;
    float m = val;
#pragma unroll
    for (int o = 32; o; o >>= 1) m = fmaxf(m, __shfl_xor(m, o));
    float ex = (lane < 40) ? expf(val - m) : 0.f;
    float ssum = ex;
#pragma unroll
    for (int o = 32; o; o >>= 1) ssum += __shfl_xor(ssum, o);
    if (lane < 40) out[(size_t)w * 40 + lane] = val - m - logf(ssum);
}

// ---------------- launch ----------------
extern "C" void kernel_launch(void* const* d_in, const int* in_sizes, int n_in,
                              void* d_out, int out_size, void* d_ws, size_t ws_size,
                              hipStream_t stream)
{
    const float* X        = (const float*)d_in[0];
    const int*   node_idx = (const int*)d_in[1];
    const int*   edge_idx = (const int*)d_in[2];
    const float* W1 = (const float*)d_in[3];
    const float* b1 = (const float*)d_in[4];
    const float* W2 = (const float*)d_in[5];
    const float* b2 = (const float*)d_in[6];
    const float* W3 = (const float*)d_in[7];
    const float* b3 = (const float*)d_in[8];
    float* out = (float*)d_out;

    char* p = (char*)d_ws;
    auto alloc = [&](size_t bytes) -> char* {
        char* r = p;
        p += (bytes + 255) & ~(size_t)255;
        return r;
    };
    int*   cnt_e = (int*)alloc((size_t)N_EDGES * 4);
    int*   cnt_v = (int*)alloc((size_t)N_NODES * 4);
    int*   cur_e = (int*)alloc((size_t)N_EDGES * 4);
    int*   cur_v = (int*)alloc((size_t)N_NODES * 4);
    int*   off_e = (int*)alloc((size_t)(N_EDGES + 1) * 4);
    int*   off_v = (int*)alloc((size_t)(N_NODES + 1) * 4);
    float* inv_e = (float*)alloc((size_t)N_EDGES * 4);
    float* inv_v = (float*)alloc((size_t)N_NODES * 4);
    int*   csr_e = (int*)alloc((size_t)NNZ_CT * 4);
    int*   csr_v = (int*)alloc((size_t)NNZ_CT * 4);

    const int M16 = N_NODES / 16;              // 3125 (exact)
    const int M16_PAD = 391 * 8;               // 3128, grid-covered tiles
    unsigned short* At_hi = (unsigned short*)alloc((size_t)M16_PAD * 8 * 512 * 2);
    unsigned short* At_lo = (unsigned short*)alloc((size_t)M16_PAD * 8 * 512 * 2);
    unsigned short* W1t_hi = (unsigned short*)alloc((size_t)16 * 8 * 512 * 2);
    unsigned short* W1t_lo = (unsigned short*)alloc((size_t)16 * 8 * 512 * 2);
    unsigned short* W2t_hi = (unsigned short*)alloc((size_t)16 * 8 * 512 * 2);
    unsigned short* W2t_lo = (unsigned short*)alloc((size_t)16 * 8 * 512 * 2);
    unsigned short* W3t_hi = (unsigned short*)alloc((size_t)8 * 8 * 512 * 2);
    unsigned short* W3t_lo = (unsigned short*)alloc((size_t)8 * 8 * 512 * 2);
    float* bufC = (float*)alloc((size_t)N_NODES * 256 * 4);
    float* bufE = (float*)alloc((size_t)N_EDGES * 256 * 4);

    size_t zspan = (size_t)((char*)cur_v + (size_t)N_NODES * 4 - (char*)cnt_e);
    hipMemsetAsync(cnt_e, 0, zspan, stream);

    count_kernel<<<(NNZ_CT + 255) / 256, 256, 0, stream>>>(node_idx, edge_idx, cnt_e, cnt_v);
    scan_kernel<<<1, 1024, 0, stream>>>(cnt_e, off_e, inv_e, N_EDGES);
    scan_kernel<<<1, 1024, 0, stream>>>(cnt_v, off_v, inv_v, N_NODES);
    fill_kernel<<<(NNZ_CT + 255) / 256, 256, 0, stream>>>(
        node_idx, edge_idx, off_e, off_v, cur_e, cur_v, csr_e, csr_v);

    // conversions
    convert_A_tiled<<<(M16 * 8 * 64 + 255) / 256, 256, 0, stream>>>(X, At_hi, At_lo, M16);
    convert_B_tiled<<<(16 * 8 * 64 + 255) / 256, 256, 0, stream>>>(W1, W1t_hi, W1t_lo, 256, 16);
    convert_B_tiled<<<(16 * 8 * 64 + 255) / 256, 256, 0, stream>>>(W2, W2t_hi, W2t_lo, 256, 16);
    convert_B_tiled<<<(8 * 8 * 64 + 255) / 256, 256, 0, stream>>>(W3, W3t_hi, W3t_lo, 40, 8);

    dim3 gemm_big(2, 391), gemm_small(1, 391);
    const int gE = (N_EDGES + 3) / 4;
    const int gV = (N_NODES + 3) / 4;

    // layer 1
    gemm_mfma_split<<<gemm_big, 256, 0, stream>>>(At_hi, At_lo, W1t_hi, W1t_lo, bufC, N_NODES, 256, 256);
    agg_e256<<<gE, 256, 0, stream>>>(bufC, bufE, off_e, csr_e, inv_e, N_EDGES);
    agg_v256_tiled<<<gV, 256, 0, stream>>>(bufE, At_hi, At_lo, off_v, csr_v, inv_v, b1, N_NODES);

    // layer 2 (H1 lives in At_*)
    gemm_mfma_split<<<gemm_big, 256, 0, stream>>>(At_hi, At_lo, W2t_hi, W2t_lo, bufC, N_NODES, 256, 256);
    agg_e256<<<gE, 256, 0, stream>>>(bufC, bufE, off_e, csr_e, inv_e, N_EDGES);
    agg_v256_tiled<<<gV, 256, 0, stream>>>(bufE, At_hi, At_lo, off_v, csr_v, inv_v, b2, N_NODES);

    // layer 3 (H2 in At_*), N=40 padded to 128 in W3t
    gemm_mfma_split<<<gemm_small, 256, 0, stream>>>(At_hi, At_lo, W3t_hi, W3t_lo, bufC, N_NODES, 40, 40);
    agg_mean40<<<gE, 256, 0, stream>>>(bufC, bufE, off_e, csr_e, inv_e, N_EDGES);
    agg_v40_lsm<<<gV, 256, 0, stream>>>(bufE, out, off_v, csr_v, inv_v, b3, N_NODES);
    (void)in_sizes; (void)n_in; (void)out_size; (void)ws_size;
}

// Round 3
// 560.408 us; speedup vs baseline: 1.5333x; 1.2429x over previous
//
#include <hip/hip_runtime.h>
#include <math.h>

#define N_NODES 50000
#define N_EDGES 20000
#define NNZ_CT  500000
#define KDIM    256
#define K32     8

typedef __attribute__((ext_vector_type(8))) short    short8v;
typedef __attribute__((ext_vector_type(4))) float    f32x4;
typedef __attribute__((ext_vector_type(8))) unsigned short ushort8v;
typedef __attribute__((ext_vector_type(4))) unsigned short ushort4v;

#define GLD16(g, l) __builtin_amdgcn_global_load_lds( \
    (const __attribute__((address_space(1))) unsigned int*)(g), \
    (__attribute__((address_space(3))) unsigned int*)(l), 16, 0, 0)

__device__ __forceinline__ unsigned short bf16_rne(float f) {
    unsigned u = __float_as_uint(f);
    return (unsigned short)((u + 0x7FFFu + ((u >> 16) & 1u)) >> 16);
}
__device__ __forceinline__ float bf16_to_f(unsigned short h) {
    return __uint_as_float(((unsigned)h) << 16);
}
__device__ __forceinline__ void bf16_split(float f, unsigned short& h, unsigned short& l) {
    unsigned u = __float_as_uint(f);
    unsigned hb = (u + 0x7FFFu + ((u >> 16) & 1u)) >> 16;
    h = (unsigned short)hb;
    float r = f - __uint_as_float(hb << 16);
    unsigned ru = __float_as_uint(r);
    l = (unsigned short)((ru + 0x7FFFu + ((ru >> 16) & 1u)) >> 16);
}

// ---- convert fp32 A[M,256] -> fragment-tiled bf16 (hi only) ----
__global__ __launch_bounds__(256) void convert_A_tiled(
    const float* __restrict__ A, unsigned short* __restrict__ At, int m16_count)
{
    int t = blockIdx.x * 256 + threadIdx.x;
    if (t >= m16_count * 512) return;
    int lane = t & 63, k32 = (t >> 6) & 7, m16 = t >> 9;
    int row = m16 * 16 + (lane & 15);
    int k0  = k32 * 32 + (lane >> 4) * 8;
    const float* src = A + (size_t)row * KDIM + k0;
    float f[8];
    *(float4*)(f)     = *(const float4*)(src);
    *(float4*)(f + 4) = *(const float4*)(src + 4);
    ushort8v h;
#pragma unroll
    for (int j = 0; j < 8; j++) h[j] = bf16_rne(f[j]);
    *(ushort8v*)(At + (((size_t)m16 * 8 + k32) << 9) + lane * 8) = h;
}

// ---- convert fp32 B[K,Ncols] -> fragment-tiled bf16 hi/lo (zero-pad cols) ----
__global__ __launch_bounds__(256) void convert_B_tiled(
    const float* __restrict__ B, unsigned short* __restrict__ Bh,
    unsigned short* __restrict__ Bl, int Ncols, int n16_count)
{
    int t = blockIdx.x * 256 + threadIdx.x;
    if (t >= n16_count * 512) return;
    int lane = t & 63, k32 = (t >> 6) & 7, n16 = t >> 9;
    int col = n16 * 16 + (lane & 15);
    int k0  = k32 * 32 + (lane >> 4) * 8;
    ushort8v h, l;
#pragma unroll
    for (int j = 0; j < 8; j++) {
        float f = (col < Ncols) ? B[(size_t)(k0 + j) * Ncols + col] : 0.f;
        unsigned short hh, ll; bf16_split(f, hh, ll); h[j] = hh; l[j] = ll;
    }
    size_t off = (((size_t)n16 * 8 + k32) << 9) + lane * 8;
    *(ushort8v*)(Bh + off) = h;
    *(ushort8v*)(Bl + off) = l;
}

// ---- MFMA GEMM: A bf16, B split hi/lo; C out bf16 row-major, 128x128 tile ----
__global__ __launch_bounds__(256) void gemm_bf16(
    const unsigned short* __restrict__ At,
    const unsigned short* __restrict__ Bh, const unsigned short* __restrict__ Bl,
    unsigned short* __restrict__ C, int M, int Ncols, int ldC)
{
    __shared__ unsigned short lds[16384];   // 32KB: staging uses 24KB, bounce uses all
    const int tid  = threadIdx.x;
    const int lane = tid & 63, wid = tid >> 6;
    const int wr = wid >> 1, wc = wid & 1;
    const int m0t = blockIdx.y * 8;
    const int n0t = blockIdx.x * 8;

    f32x4 acc[4][4] = {};

    for (int k32 = 0; k32 < K32; ++k32) {
#pragma unroll
        for (int i = 0; i < 6; ++i) {
            int c = i * 4 + wid;               // 0..23
            if (c < 8) {
                const unsigned short* gA = At + (((size_t)(m0t + c) * 8 + k32) << 9) + lane * 8;
                GLD16(gA, &lds[c * 512 + lane * 8]);
            } else {
                int idx = c - 8, half = idx >> 3, st = idx & 7;
                const unsigned short* gB = (half ? Bl : Bh)
                    + (((size_t)(n0t + st) * 8 + k32) << 9) + lane * 8;
                GLD16(gB, &lds[4096 + idx * 512 + lane * 8]);
            }
        }
        __syncthreads();
        short8v a[4], bh[4], bl[4];
#pragma unroll
        for (int x = 0; x < 4; ++x) {
            a[x]  = *(const short8v*)&lds[(wr * 4 + x) * 512 + lane * 8];
            bh[x] = *(const short8v*)&lds[4096 + (wc * 4 + x) * 512 + lane * 8];
            bl[x] = *(const short8v*)&lds[4096 + (8 + wc * 4 + x) * 512 + lane * 8];
        }
#pragma unroll
        for (int mi = 0; mi < 4; ++mi)
#pragma unroll
            for (int ni = 0; ni < 4; ++ni) {
                acc[mi][ni] = __builtin_amdgcn_mfma_f32_16x16x32_bf16(a[mi], bh[ni], acc[mi][ni], 0, 0, 0);
                acc[mi][ni] = __builtin_amdgcn_mfma_f32_16x16x32_bf16(a[mi], bl[ni], acc[mi][ni], 0, 0, 0);
            }
        __syncthreads();
    }

    // epilogue: bounce through LDS (XOR-swizzled), write bf16 row-major
    {
        const int rg = lane >> 4, cl = lane & 15;
        const int base = wid * 4096;
#pragma unroll
        for (int mi = 0; mi < 4; ++mi) {
            int swz = ((mi * 4 + rg) & 3) << 4;
#pragma unroll
            for (int ni = 0; ni < 4; ++ni) {
                int colf = (ni * 16 + cl) ^ swz;
#pragma unroll
                for (int r = 0; r < 4; ++r)
                    lds[base + (mi * 16 + rg * 4 + r) * 64 + colf] = bf16_rne(acc[mi][ni][r]);
            }
        }
    }
    __syncthreads();
    {
        int row = tid >> 1, half = tid & 1;
        int grow = blockIdx.y * 128 + row;
        if (grow < M) {
            int wsrc = (row >> 6) * 2 + half;
            int rl = row & 63;
            int swz = ((rl >> 2) & 3) << 4;
            unsigned short* dst = C + (size_t)grow * ldC + n0t * 16 + half * 64;
#pragma unroll
            for (int s = 0; s < 8; ++s) {
                int c0 = half * 64 + s * 8;
                if (n0t * 16 + c0 + 8 <= Ncols) {
                    ushort8v v = *(const ushort8v*)&lds[wsrc * 4096 + rl * 64 + ((s * 8) ^ swz)];
                    *(ushort8v*)(dst + s * 8) = v;
                }
            }
        }
    }
}

// ---------------- degree count ----------------
__global__ void count_kernel(const int* __restrict__ node_idx,
                             const int* __restrict__ edge_idx,
                             int* __restrict__ cnt_e, int* __restrict__ cnt_v)
{
    int i = blockIdx.x * blockDim.x + threadIdx.x;
    if (i < NNZ_CT) {
        atomicAdd(&cnt_e[edge_idx[i]], 1);
        atomicAdd(&cnt_v[node_idx[i]], 1);
    }
}

// ---- dual single-pass scans (block 0: edges, block 1: nodes), int4 chunks ----
__global__ __launch_bounds__(1024) void scan_dual(
    const int* __restrict__ cnt_e, int* __restrict__ off_e, float* __restrict__ inv_e,
    const int* __restrict__ cnt_v, int* __restrict__ off_v, float* __restrict__ inv_v)
{
    const int* cnt; int* off; float* inv; int n;
    if (blockIdx.x == 0) { cnt = cnt_e; off = off_e; inv = inv_e; n = N_EDGES; }
    else                 { cnt = cnt_v; off = off_v; inv = inv_v; n = N_NODES; }
    __shared__ int wsum[16];
    __shared__ int carry_s;
    int tid = threadIdx.x, lane = tid & 63, wid = tid >> 6;
    if (tid == 0) carry_s = 0;
    __syncthreads();
    for (int base = 0; base < n; base += 4096) {
        int i4 = base + tid * 4;
        int4 x = make_int4(0, 0, 0, 0);
        if (i4 + 3 < n) x = *(const int4*)(cnt + i4);
        else if (i4 < n) {
            x.x = cnt[i4];
            if (i4 + 1 < n) x.y = cnt[i4 + 1];
            if (i4 + 2 < n) x.z = cnt[i4 + 2];
        }
        int s0 = x.x, s1 = s0 + x.y, s2 = s1 + x.z, s3 = s2 + x.w;
        int incl = s3;
#pragma unroll
        for (int o = 1; o < 64; o <<= 1) { int t = __shfl_up(incl, o, 64); if (lane >= o) incl += t; }
        if (lane == 63) wsum[wid] = incl;
        __syncthreads();
        if (wid == 0) {
            int v = (lane < 16) ? wsum[lane] : 0;
#pragma unroll
            for (int o = 1; o < 16; o <<= 1) { int t = __shfl_up(v, o, 64); if (lane >= o) v += t; }
            if (lane < 16) wsum[lane] = v;
        }
        __syncthreads();
        int wpre = (wid == 0) ? 0 : wsum[wid - 1];
        int carry = carry_s;
        int excl = carry + wpre + incl - s3;
        if (i4 < n) {
            int e0 = excl, e1 = excl + s0, e2 = excl + s1, e3 = excl + s2;
            if (i4 + 3 < n) { *(int4*)(off + i4) = make_int4(e0, e1, e2, e3); }
            else {
                off[i4] = e0;
                if (i4 + 1 < n) off[i4 + 1] = e1;
                if (i4 + 2 < n) off[i4 + 2] = e2;
            }
            inv[i4] = 1.0f / fmaxf((float)x.x, 1.0f);
            if (i4 + 1 < n) inv[i4 + 1] = 1.0f / fmaxf((float)x.y, 1.0f);
            if (i4 + 2 < n) inv[i4 + 2] = 1.0f / fmaxf((float)x.z, 1.0f);
            if (i4 + 3 < n) inv[i4 + 3] = 1.0f / fmaxf((float)x.w, 1.0f);
        }
        __syncthreads();
        if (tid == 1023) carry_s = carry + wpre + incl;
        __syncthreads();
    }
    if (tid == 0) off[n] = carry_s;
}

// ---------------- CSR fill ----------------
__global__ void fill_kernel(const int* __restrict__ node_idx,
                            const int* __restrict__ edge_idx,
                            const int* __restrict__ off_e, const int* __restrict__ off_v,
                            int* __restrict__ cur_e, int* __restrict__ cur_v,
                            int* __restrict__ csr_e_nodes, int* __restrict__ csr_v_edges)
{
    int i = blockIdx.x * blockDim.x + threadIdx.x;
    if (i < NNZ_CT) {
        int v = node_idx[i], e = edge_idx[i];
        int pe = atomicAdd(&cur_e[e], 1);
        csr_e_nodes[off_e[e] + pe] = v;
        int pv = atomicAdd(&cur_v[v], 1);
        csr_v_edges[off_v[v] + pv] = e;
    }
}

// ---- V->E mean, bf16 in, bf16 out, wave per edge ----
__global__ __launch_bounds__(256) void agg_e256(
    const unsigned short* __restrict__ src, unsigned short* __restrict__ dst,
    const int* __restrict__ offs, const int* __restrict__ lists,
    const float* __restrict__ invdeg, int nseg)
{
    int w = (blockIdx.x * 256 + threadIdx.x) >> 6;
    int lane = threadIdx.x & 63;
    if (w >= nseg) return;
    int s = offs[w], e = offs[w + 1];
    float a0 = 0.f, a1 = 0.f, a2 = 0.f, a3 = 0.f;
    for (int j = s; j < e; ++j) {
        int r = lists[j];
        ushort4v v = *(const ushort4v*)(src + (size_t)r * 256 + lane * 4);
        a0 += bf16_to_f(v[0]); a1 += bf16_to_f(v[1]);
        a2 += bf16_to_f(v[2]); a3 += bf16_to_f(v[3]);
    }
    float sc = invdeg[w];
    ushort4v o;
    o[0] = bf16_rne(a0 * sc); o[1] = bf16_rne(a1 * sc);
    o[2] = bf16_rne(a2 * sc); o[3] = bf16_rne(a3 * sc);
    *(ushort4v*)(dst + (size_t)w * 256 + lane * 4) = o;
}

// ---- E->V mean + bias + relu -> fragment-tiled bf16; block = one m16 tile ----
__global__ __launch_bounds__(256) void agg_v256_blk(
    const unsigned short* __restrict__ src, unsigned short* __restrict__ At,
    const int* __restrict__ offs, const int* __restrict__ lists,
    const float* __restrict__ invdeg, const float* __restrict__ bias)
{
    __shared__ unsigned short hbuf[16 * 264];   // pitch 264 ushorts (2-way max on banks)
    int tid = threadIdx.x, lane = tid & 63, wid = tid >> 6;
    int m16 = blockIdx.x;
    const float4 b = *(const float4*)(bias + lane * 4);
#pragma unroll
    for (int q = 0; q < 4; ++q) {
        int nl = wid * 4 + q;
        int w = m16 * 16 + nl;
        int s = offs[w], e = offs[w + 1];
        float a0 = 0.f, a1 = 0.f, a2 = 0.f, a3 = 0.f;
        for (int j = s; j < e; ++j) {
            int r = lists[j];
            ushort4v v = *(const ushort4v*)(src + (size_t)r * 256 + lane * 4);
            a0 += bf16_to_f(v[0]); a1 += bf16_to_f(v[1]);
            a2 += bf16_to_f(v[2]); a3 += bf16_to_f(v[3]);
        }
        float sc = invdeg[w];
        ushort4v o;
        o[0] = bf16_rne(fmaxf(a0 * sc + b.x, 0.f));
        o[1] = bf16_rne(fmaxf(a1 * sc + b.y, 0.f));
        o[2] = bf16_rne(fmaxf(a2 * sc + b.z, 0.f));
        o[3] = bf16_rne(fmaxf(a3 * sc + b.w, 0.f));
        *(ushort4v*)&hbuf[nl * 264 + lane * 4] = o;
    }
    __syncthreads();
#pragma unroll
    for (int u = 0; u < 2; ++u) {
        int sl = tid * 2 + u;
        int k32 = sl >> 6, lt = sl & 63;
        int row = lt & 15, hi = lt >> 4;
        int k0 = k32 * 32 + hi * 8;
        ushort8v v = *(const ushort8v*)&hbuf[row * 264 + k0];
        *(ushort8v*)(At + (((size_t)m16 * 8 + k32) << 9) + lt * 8) = v;
    }
}

// ---------------- mean-aggregation, F=40 (edges), bf16 in fp32 out ----------------
__global__ __launch_bounds__(256) void agg_mean40(
    const unsigned short* __restrict__ src, float* __restrict__ dst,
    const int* __restrict__ offs, const int* __restrict__ lists,
    const float* __restrict__ invdeg, int nseg)
{
    int w = (blockIdx.x * 256 + threadIdx.x) >> 6;
    int lane = threadIdx.x & 63;
    if (w >= nseg) return;
    int s = offs[w], e = offs[w + 1];
    float acc = 0.f;
    if (lane < 40) {
        for (int j = s; j < e; ++j) {
            int r = lists[j];
            acc += bf16_to_f(src[(size_t)r * 40 + lane]);
        }
        dst[(size_t)w * 40 + lane] = acc * invdeg[w];
    }
}

// ------- final E->V mean at F=40 + bias + log_softmax, wave per node -------
__global__ __launch_bounds__(256) void agg_v40_lsm(
    const float* __restrict__ efeat, float* __restrict__ out,
    const int* __restrict__ offs, const int* __restrict__ lists,
    const float* __restrict__ invdeg, const float* __restrict__ bias,
    int nseg)
{
    int w = (blockIdx.x * 256 + threadIdx.x) >> 6;
    int lane = threadIdx.x & 63;
    if (w >= nseg) return;
    int s = offs[w], e = offs[w + 1];
    float acc = 0.f;
    if (lane < 40) {
        for (int j = s; j < e; ++j) {
            int r = lists[j];
            acc += efeat[(size_t)r * 40 + lane];
        }
    }
    float val = (lane < 40) ? (acc * invdeg[w] + bias[lane]) : -1e30f;
    float m = val;
#pragma unroll
    for (int o = 32; o; o >>= 1) m = fmaxf(m, __shfl_xor(m, o));
    float ex = (lane < 40) ? expf(val - m) : 0.f;
    float ssum = ex;
#pragma unroll
    for (int o = 32; o; o >>= 1) ssum += __shfl_xor(ssum, o);
    if (lane < 40) out[(size_t)w * 40 + lane] = val - m - logf(ssum);
}

// ---------------- launch ----------------
extern "C" void kernel_launch(void* const* d_in, const int* in_sizes, int n_in,
                              void* d_out, int out_size, void* d_ws, size_t ws_size,
                              hipStream_t stream)
{
    const float* X        = (const float*)d_in[0];
    const int*   node_idx = (const int*)d_in[1];
    const int*   edge_idx = (const int*)d_in[2];
    const float* W1 = (const float*)d_in[3];
    const float* b1 = (const float*)d_in[4];
    const float* W2 = (const float*)d_in[5];
    const float* b2 = (const float*)d_in[6];
    const float* W3 = (const float*)d_in[7];
    const float* b3 = (const float*)d_in[8];
    float* out = (float*)d_out;

    char* p = (char*)d_ws;
    auto alloc = [&](size_t bytes) -> char* {
        char* r = p;
        p += (bytes + 255) & ~(size_t)255;
        return r;
    };
    int*   cnt_e = (int*)alloc((size_t)N_EDGES * 4);
    int*   cnt_v = (int*)alloc((size_t)N_NODES * 4);
    int*   cur_e = (int*)alloc((size_t)N_EDGES * 4);
    int*   cur_v = (int*)alloc((size_t)N_NODES * 4);
    int*   off_e = (int*)alloc((size_t)(N_EDGES + 1) * 4);
    int*   off_v = (int*)alloc((size_t)(N_NODES + 1) * 4);
    float* inv_e = (float*)alloc((size_t)N_EDGES * 4);
    float* inv_v = (float*)alloc((size_t)N_NODES * 4);
    int*   csr_e = (int*)alloc((size_t)NNZ_CT * 4);
    int*   csr_v = (int*)alloc((size_t)NNZ_CT * 4);

    const int M16 = N_NODES / 16;              // 3125
    const int M16_PAD = 391 * 8;               // 3128 tiles covered by grid
    unsigned short* At  = (unsigned short*)alloc((size_t)M16_PAD * 4096 * 2);
    unsigned short* W1h = (unsigned short*)alloc((size_t)16 * 4096 * 2);
    unsigned short* W1l = (unsigned short*)alloc((size_t)16 * 4096 * 2);
    unsigned short* W2h = (unsigned short*)alloc((size_t)16 * 4096 * 2);
    unsigned short* W2l = (unsigned short*)alloc((size_t)16 * 4096 * 2);
    unsigned short* W3h = (unsigned short*)alloc((size_t)8 * 4096 * 2);
    unsigned short* W3l = (unsigned short*)alloc((size_t)8 * 4096 * 2);
    unsigned short* bufC = (unsigned short*)alloc((size_t)N_NODES * 256 * 2);
    unsigned short* bufE = (unsigned short*)alloc((size_t)N_EDGES * 256 * 2);
    float* bufE40 = (float*)alloc((size_t)N_EDGES * 40 * 4);

    size_t zspan = (size_t)((char*)cur_v + (size_t)N_NODES * 4 - (char*)cnt_e);
    hipMemsetAsync(cnt_e, 0, zspan, stream);

    count_kernel<<<(NNZ_CT + 255) / 256, 256, 0, stream>>>(node_idx, edge_idx, cnt_e, cnt_v);
    scan_dual<<<2, 1024, 0, stream>>>(cnt_e, off_e, inv_e, cnt_v, off_v, inv_v);
    fill_kernel<<<(NNZ_CT + 255) / 256, 256, 0, stream>>>(
        node_idx, edge_idx, off_e, off_v, cur_e, cur_v, csr_e, csr_v);

    convert_A_tiled<<<(M16 * 512 + 255) / 256, 256, 0, stream>>>(X, At, M16);
    convert_B_tiled<<<(16 * 512 + 255) / 256, 256, 0, stream>>>(W1, W1h, W1l, 256, 16);
    convert_B_tiled<<<(16 * 512 + 255) / 256, 256, 0, stream>>>(W2, W2h, W2l, 256, 16);
    convert_B_tiled<<<(8 * 512 + 255) / 256, 256, 0, stream>>>(W3, W3h, W3l, 40, 8);

    dim3 gbig(2, 391), gsmall(1, 391);
    const int gE = (N_EDGES + 3) / 4;
    const int gV = (N_NODES + 3) / 4;

    // layer 1
    gemm_bf16<<<gbig, 256, 0, stream>>>(At, W1h, W1l, bufC, N_NODES, 256, 256);
    agg_e256<<<gE, 256, 0, stream>>>(bufC, bufE, off_e, csr_e, inv_e, N_EDGES);
    agg_v256_blk<<<M16, 256, 0, stream>>>(bufE, At, off_v, csr_v, inv_v, b1);

    // layer 2
    gemm_bf16<<<gbig, 256, 0, stream>>>(At, W2h, W2l, bufC, N_NODES, 256, 256);
    agg_e256<<<gE, 256, 0, stream>>>(bufC, bufE, off_e, csr_e, inv_e, N_EDGES);
    agg_v256_blk<<<M16, 256, 0, stream>>>(bufE, At, off_v, csr_v, inv_v, b2);

    // layer 3
    gemm_bf16<<<gsmall, 256, 0, stream>>>(At, W3h, W3l, bufC, N_NODES, 40, 40);
    agg_mean40<<<gE, 256, 0, stream>>>(bufC, bufE40, off_e, csr_e, inv_e, N_EDGES);
    agg_v40_lsm<<<gV, 256, 0, stream>>>(bufE40, out, off_v, csr_v, inv_v, b3, N_NODES);
    (void)in_sizes; (void)n_in; (void)out_size; (void)ws_size;
}

// Round 4
// 421.234 us; speedup vs baseline: 2.0399x; 1.3304x over previous
//
#include <hip/hip_runtime.h>
#include <math.h>

#define N_NODES 50000
#define N_EDGES 20000
#define NNZ_CT  500000
#define KDIM    256
#define K32     8

typedef __attribute__((ext_vector_type(8))) short    short8v;
typedef __attribute__((ext_vector_type(4))) float    f32x4;
typedef __attribute__((ext_vector_type(8))) unsigned short ushort8v;
typedef __attribute__((ext_vector_type(4))) unsigned short ushort4v;

#define GLD16(g, l) __builtin_amdgcn_global_load_lds( \
    (const __attribute__((address_space(1))) unsigned int*)(g), \
    (__attribute__((address_space(3))) unsigned int*)(l), 16, 0, 0)

__device__ __forceinline__ unsigned short bf16_rne(float f) {
    unsigned u = __float_as_uint(f);
    return (unsigned short)((u + 0x7FFFu + ((u >> 16) & 1u)) >> 16);
}
__device__ __forceinline__ float bf16_to_f(unsigned short h) {
    return __uint_as_float(((unsigned)h) << 16);
}
__device__ __forceinline__ void bf16_split(float f, unsigned short& h, unsigned short& l) {
    unsigned u = __float_as_uint(f);
    unsigned hb = (u + 0x7FFFu + ((u >> 16) & 1u)) >> 16;
    h = (unsigned short)hb;
    float r = f - __uint_as_float(hb << 16);
    unsigned ru = __float_as_uint(r);
    l = (unsigned short)((ru + 0x7FFFu + ((ru >> 16) & 1u)) >> 16);
}

// ---- convert fp32 A[M,256] -> fragment-tiled bf16 (hi only) ----
__global__ __launch_bounds__(256) void convert_A_tiled(
    const float* __restrict__ A, unsigned short* __restrict__ At, int m16_count)
{
    int t = blockIdx.x * 256 + threadIdx.x;
    if (t >= m16_count * 512) return;
    int lane = t & 63, k32 = (t >> 6) & 7, m16 = t >> 9;
    int row = m16 * 16 + (lane & 15);
    int k0  = k32 * 32 + (lane >> 4) * 8;
    const float* src = A + (size_t)row * KDIM + k0;
    float f[8];
    *(float4*)(f)     = *(const float4*)(src);
    *(float4*)(f + 4) = *(const float4*)(src + 4);
    ushort8v h;
#pragma unroll
    for (int j = 0; j < 8; j++) h[j] = bf16_rne(f[j]);
    *(ushort8v*)(At + (((size_t)m16 * 8 + k32) << 9) + lane * 8) = h;
}

// ---- convert fp32 B[K,Ncols] -> fragment-tiled bf16 hi/lo (zero-pad cols) ----
__global__ __launch_bounds__(256) void convert_B_tiled(
    const float* __restrict__ B, unsigned short* __restrict__ Bh,
    unsigned short* __restrict__ Bl, int Ncols, int n16_count)
{
    int t = blockIdx.x * 256 + threadIdx.x;
    if (t >= n16_count * 512) return;
    int lane = t & 63, k32 = (t >> 6) & 7, n16 = t >> 9;
    int col = n16 * 16 + (lane & 15);
    int k0  = k32 * 32 + (lane >> 4) * 8;
    ushort8v h, l;
#pragma unroll
    for (int j = 0; j < 8; j++) {
        float f = (col < Ncols) ? B[(size_t)(k0 + j) * Ncols + col] : 0.f;
        unsigned short hh, ll; bf16_split(f, hh, ll); h[j] = hh; l[j] = ll;
    }
    size_t off = (((size_t)n16 * 8 + k32) << 9) + lane * 8;
    *(ushort8v*)(Bh + off) = h;
    *(ushort8v*)(Bl + off) = l;
}

// ---- MFMA GEMM: A bf16, B split hi/lo; C out bf16 row-major, 128x128 tile ----
__global__ __launch_bounds__(256) void gemm_bf16(
    const unsigned short* __restrict__ At,
    const unsigned short* __restrict__ Bh, const unsigned short* __restrict__ Bl,
    unsigned short* __restrict__ C, int M, int Ncols, int ldC)
{
    __shared__ unsigned short lds[16384];
    const int tid  = threadIdx.x;
    const int lane = tid & 63, wid = tid >> 6;
    const int wr = wid >> 1, wc = wid & 1;
    const int m0t = blockIdx.y * 8;
    const int n0t = blockIdx.x * 8;

    f32x4 acc[4][4] = {};

    for (int k32 = 0; k32 < K32; ++k32) {
#pragma unroll
        for (int i = 0; i < 6; ++i) {
            int c = i * 4 + wid;               // 0..23
            if (c < 8) {
                const unsigned short* gA = At + (((size_t)(m0t + c) * 8 + k32) << 9) + lane * 8;
                GLD16(gA, &lds[c * 512 + lane * 8]);
            } else {
                int idx = c - 8, half = idx >> 3, st = idx & 7;
                const unsigned short* gB = (half ? Bl : Bh)
                    + (((size_t)(n0t + st) * 8 + k32) << 9) + lane * 8;
                GLD16(gB, &lds[4096 + idx * 512 + lane * 8]);
            }
        }
        __syncthreads();
        short8v a[4], bh[4], bl[4];
#pragma unroll
        for (int x = 0; x < 4; ++x) {
            a[x]  = *(const short8v*)&lds[(wr * 4 + x) * 512 + lane * 8];
            bh[x] = *(const short8v*)&lds[4096 + (wc * 4 + x) * 512 + lane * 8];
            bl[x] = *(const short8v*)&lds[4096 + (8 + wc * 4 + x) * 512 + lane * 8];
        }
#pragma unroll
        for (int mi = 0; mi < 4; ++mi)
#pragma unroll
            for (int ni = 0; ni < 4; ++ni) {
                acc[mi][ni] = __builtin_amdgcn_mfma_f32_16x16x32_bf16(a[mi], bh[ni], acc[mi][ni], 0, 0, 0);
                acc[mi][ni] = __builtin_amdgcn_mfma_f32_16x16x32_bf16(a[mi], bl[ni], acc[mi][ni], 0, 0, 0);
            }
        __syncthreads();
    }

    // epilogue: bounce through LDS (XOR-swizzled), write bf16 row-major
    {
        const int rg = lane >> 4, cl = lane & 15;
        const int base = wid * 4096;
#pragma unroll
        for (int mi = 0; mi < 4; ++mi) {
            int swz = ((mi * 4 + rg) & 3) << 4;
#pragma unroll
            for (int ni = 0; ni < 4; ++ni) {
                int colf = (ni * 16 + cl) ^ swz;
#pragma unroll
                for (int r = 0; r < 4; ++r)
                    lds[base + (mi * 16 + rg * 4 + r) * 64 + colf] = bf16_rne(acc[mi][ni][r]);
            }
        }
    }
    __syncthreads();
    {
        int row = tid >> 1, half = tid & 1;
        int grow = blockIdx.y * 128 + row;
        if (grow < M) {
            int wsrc = (row >> 6) * 2 + half;
            int rl = row & 63;
            int swz = ((rl >> 2) & 3) << 4;
            unsigned short* dst = C + (size_t)grow * ldC + n0t * 16 + half * 64;
#pragma unroll
            for (int s = 0; s < 8; ++s) {
                int c0 = half * 64 + s * 8;
                if (n0t * 16 + c0 + 8 <= Ncols) {
                    ushort8v v = *(const ushort8v*)&lds[wsrc * 4096 + rl * 64 + ((s * 8) ^ swz)];
                    *(ushort8v*)(dst + s * 8) = v;
                }
            }
        }
    }
}

// ---------------- degree count ----------------
__global__ void count_kernel(const int* __restrict__ node_idx,
                             const int* __restrict__ edge_idx,
                             int* __restrict__ cnt_e, int* __restrict__ cnt_v)
{
    int i = blockIdx.x * blockDim.x + threadIdx.x;
    if (i < NNZ_CT) {
        atomicAdd(&cnt_e[edge_idx[i]], 1);
        atomicAdd(&cnt_v[node_idx[i]], 1);
    }
}

// ---- dual single-pass scans (block 0: edges, block 1: nodes), int4 chunks ----
__global__ __launch_bounds__(1024) void scan_dual(
    const int* __restrict__ cnt_e, int* __restrict__ off_e, float* __restrict__ inv_e,
    const int* __restrict__ cnt_v, int* __restrict__ off_v, float* __restrict__ inv_v)
{
    const int* cnt; int* off; float* inv; int n;
    if (blockIdx.x == 0) { cnt = cnt_e; off = off_e; inv = inv_e; n = N_EDGES; }
    else                 { cnt = cnt_v; off = off_v; inv = inv_v; n = N_NODES; }
    __shared__ int wsum[16];
    __shared__ int carry_s;
    int tid = threadIdx.x, lane = tid & 63, wid = tid >> 6;
    if (tid == 0) carry_s = 0;
    __syncthreads();
    for (int base = 0; base < n; base += 4096) {
        int i4 = base + tid * 4;
        int4 x = make_int4(0, 0, 0, 0);
        if (i4 + 3 < n) x = *(const int4*)(cnt + i4);
        else if (i4 < n) {
            x.x = cnt[i4];
            if (i4 + 1 < n) x.y = cnt[i4 + 1];
            if (i4 + 2 < n) x.z = cnt[i4 + 2];
        }
        int s0 = x.x, s1 = s0 + x.y, s2 = s1 + x.z, s3 = s2 + x.w;
        int incl = s3;
#pragma unroll
        for (int o = 1; o < 64; o <<= 1) { int t = __shfl_up(incl, o, 64); if (lane >= o) incl += t; }
        if (lane == 63) wsum[wid] = incl;
        __syncthreads();
        if (wid == 0) {
            int v = (lane < 16) ? wsum[lane] : 0;
#pragma unroll
            for (int o = 1; o < 16; o <<= 1) { int t = __shfl_up(v, o, 64); if (lane >= o) v += t; }
            if (lane < 16) wsum[lane] = v;
        }
        __syncthreads();
        int wpre = (wid == 0) ? 0 : wsum[wid - 1];
        int carry = carry_s;
        int excl = carry + wpre + incl - s3;
        if (i4 < n) {
            int e0 = excl, e1 = excl + s0, e2 = excl + s1, e3 = excl + s2;
            if (i4 + 3 < n) { *(int4*)(off + i4) = make_int4(e0, e1, e2, e3); }
            else {
                off[i4] = e0;
                if (i4 + 1 < n) off[i4 + 1] = e1;
                if (i4 + 2 < n) off[i4 + 2] = e2;
            }
            inv[i4] = 1.0f / fmaxf((float)x.x, 1.0f);
            if (i4 + 1 < n) inv[i4 + 1] = 1.0f / fmaxf((float)x.y, 1.0f);
            if (i4 + 2 < n) inv[i4 + 2] = 1.0f / fmaxf((float)x.z, 1.0f);
            if (i4 + 3 < n) inv[i4 + 3] = 1.0f / fmaxf((float)x.w, 1.0f);
        }
        __syncthreads();
        if (tid == 1023) carry_s = carry + wpre + incl;
        __syncthreads();
    }
    if (tid == 0) off[n] = carry_s;
}

// ---------------- CSR fill ----------------
__global__ void fill_kernel(const int* __restrict__ node_idx,
                            const int* __restrict__ edge_idx,
                            const int* __restrict__ off_e, const int* __restrict__ off_v,
                            int* __restrict__ cur_e, int* __restrict__ cur_v,
                            int* __restrict__ csr_e_nodes, int* __restrict__ csr_v_edges)
{
    int i = blockIdx.x * blockDim.x + threadIdx.x;
    if (i < NNZ_CT) {
        int v = node_idx[i], e = edge_idx[i];
        int pe = atomicAdd(&cur_e[e], 1);
        csr_e_nodes[off_e[e] + pe] = v;
        int pv = atomicAdd(&cur_v[v], 1);
        csr_v_edges[off_v[v] + pv] = e;
    }
}

// ---- V->E mean, bf16 in/out, wave per edge, 8 rows in flight ----
__global__ __launch_bounds__(256) void agg_e256(
    const unsigned short* __restrict__ src, unsigned short* __restrict__ dst,
    const int* __restrict__ offs, const int* __restrict__ lists,
    const float* __restrict__ invdeg, int nseg)
{
    int w = (blockIdx.x * 256 + threadIdx.x) >> 6;
    int lane = threadIdx.x & 63;
    if (w >= nseg) return;
    int s = offs[w], e = offs[w + 1];
    float a0 = 0.f, a1 = 0.f, a2 = 0.f, a3 = 0.f;
    for (int j = s; j < e; j += 8) {
        int r[8]; float m[8];
        r[0] = lists[j]; m[0] = 1.f;
#pragma unroll
        for (int u = 1; u < 8; ++u) {
            bool ok = (j + u) < e;
            r[u] = ok ? lists[j + u] : r[0];
            m[u] = ok ? 1.f : 0.f;
        }
        ushort4v v[8];
#pragma unroll
        for (int u = 0; u < 8; ++u)
            v[u] = *(const ushort4v*)(src + (size_t)r[u] * 256 + lane * 4);
        a0 += bf16_to_f(v[0][0]); a1 += bf16_to_f(v[0][1]);
        a2 += bf16_to_f(v[0][2]); a3 += bf16_to_f(v[0][3]);
#pragma unroll
        for (int u = 1; u < 8; ++u) {
            a0 = fmaf(m[u], bf16_to_f(v[u][0]), a0);
            a1 = fmaf(m[u], bf16_to_f(v[u][1]), a1);
            a2 = fmaf(m[u], bf16_to_f(v[u][2]), a2);
            a3 = fmaf(m[u], bf16_to_f(v[u][3]), a3);
        }
    }
    float sc = invdeg[w];
    ushort4v o;
    o[0] = bf16_rne(a0 * sc); o[1] = bf16_rne(a1 * sc);
    o[2] = bf16_rne(a2 * sc); o[3] = bf16_rne(a3 * sc);
    *(ushort4v*)(dst + (size_t)w * 256 + lane * 4) = o;
}

// ---- E->V mean + bias + relu -> fragment-tiled bf16; block = one m16 tile ----
__global__ __launch_bounds__(256) void agg_v256_blk(
    const unsigned short* __restrict__ src, unsigned short* __restrict__ At,
    const int* __restrict__ offs, const int* __restrict__ lists,
    const float* __restrict__ invdeg, const float* __restrict__ bias)
{
    __shared__ unsigned short hbuf[16 * 264];
    int tid = threadIdx.x, lane = tid & 63, wid = tid >> 6;
    int m16 = blockIdx.x;
    const float4 b = *(const float4*)(bias + lane * 4);
#pragma unroll
    for (int q = 0; q < 4; ++q) {
        int nl = wid * 4 + q;
        int w = m16 * 16 + nl;
        int s = offs[w], e = offs[w + 1];
        float a0 = 0.f, a1 = 0.f, a2 = 0.f, a3 = 0.f;
        for (int j = s; j < e; j += 4) {
            int r[4]; float m[4];
            r[0] = lists[j]; m[0] = 1.f;
#pragma unroll
            for (int u = 1; u < 4; ++u) {
                bool ok = (j + u) < e;
                r[u] = ok ? lists[j + u] : r[0];
                m[u] = ok ? 1.f : 0.f;
            }
            ushort4v v[4];
#pragma unroll
            for (int u = 0; u < 4; ++u)
                v[u] = *(const ushort4v*)(src + (size_t)r[u] * 256 + lane * 4);
            a0 += bf16_to_f(v[0][0]); a1 += bf16_to_f(v[0][1]);
            a2 += bf16_to_f(v[0][2]); a3 += bf16_to_f(v[0][3]);
#pragma unroll
            for (int u = 1; u < 4; ++u) {
                a0 = fmaf(m[u], bf16_to_f(v[u][0]), a0);
                a1 = fmaf(m[u], bf16_to_f(v[u][1]), a1);
                a2 = fmaf(m[u], bf16_to_f(v[u][2]), a2);
                a3 = fmaf(m[u], bf16_to_f(v[u][3]), a3);
            }
        }
        float sc = invdeg[w];
        ushort4v o;
        o[0] = bf16_rne(fmaxf(a0 * sc + b.x, 0.f));
        o[1] = bf16_rne(fmaxf(a1 * sc + b.y, 0.f));
        o[2] = bf16_rne(fmaxf(a2 * sc + b.z, 0.f));
        o[3] = bf16_rne(fmaxf(a3 * sc + b.w, 0.f));
        *(ushort4v*)&hbuf[nl * 264 + lane * 4] = o;
    }
    __syncthreads();
#pragma unroll
    for (int u = 0; u < 2; ++u) {
        int sl = tid * 2 + u;
        int k32 = sl >> 6, lt = sl & 63;
        int row = lt & 15, hi = lt >> 4;
        int k0 = k32 * 32 + hi * 8;
        ushort8v v = *(const ushort8v*)&hbuf[row * 264 + k0];
        *(ushort8v*)(At + (((size_t)m16 * 8 + k32) << 9) + lt * 8) = v;
    }
}

// ---- mean-aggregation, F=40 (edges), bf16 in, bf16 out, 8 in flight ----
__global__ __launch_bounds__(256) void agg_mean40(
    const unsigned short* __restrict__ src, unsigned short* __restrict__ dst,
    const int* __restrict__ offs, const int* __restrict__ lists,
    const float* __restrict__ invdeg, int nseg)
{
    int w = (blockIdx.x * 256 + threadIdx.x) >> 6;
    int lane = threadIdx.x & 63;
    if (w >= nseg) return;
    int s = offs[w], e = offs[w + 1];
    if (lane < 40) {
        float acc = 0.f;
        for (int j = s; j < e; j += 8) {
            int r[8]; float m[8];
            r[0] = lists[j]; m[0] = 1.f;
#pragma unroll
            for (int u = 1; u < 8; ++u) {
                bool ok = (j + u) < e;
                r[u] = ok ? lists[j + u] : r[0];
                m[u] = ok ? 1.f : 0.f;
            }
            float v[8];
#pragma unroll
            for (int u = 0; u < 8; ++u)
                v[u] = bf16_to_f(src[(size_t)r[u] * 40 + lane]);
            acc += v[0];
#pragma unroll
            for (int u = 1; u < 8; ++u) acc = fmaf(m[u], v[u], acc);
        }
        dst[(size_t)w * 40 + lane] = bf16_rne(acc * invdeg[w]);
    }
}

// ------- final E->V mean at F=40 + bias + log_softmax, wave per node -------
__global__ __launch_bounds__(256) void agg_v40_lsm(
    const unsigned short* __restrict__ efeat, float* __restrict__ out,
    const int* __restrict__ offs, const int* __restrict__ lists,
    const float* __restrict__ invdeg, const float* __restrict__ bias,
    int nseg)
{
    int w = (blockIdx.x * 256 + threadIdx.x) >> 6;
    int lane = threadIdx.x & 63;
    if (w >= nseg) return;
    int s = offs[w], e = offs[w + 1];
    float acc = 0.f;
    if (lane < 40) {
        for (int j = s; j < e; j += 4) {
            int r[4]; float m[4];
            r[0] = lists[j]; m[0] = 1.f;
#pragma unroll
            for (int u = 1; u < 4; ++u) {
                bool ok = (j + u) < e;
                r[u] = ok ? lists[j + u] : r[0];
                m[u] = ok ? 1.f : 0.f;
            }
            float v[4];
#pragma unroll
            for (int u = 0; u < 4; ++u)
                v[u] = bf16_to_f(efeat[(size_t)r[u] * 40 + lane]);
            acc += v[0];
#pragma unroll
            for (int u = 1; u < 4; ++u) acc = fmaf(m[u], v[u], acc);
        }
    }
    float val = (lane < 40) ? (acc * invdeg[w] + bias[lane]) : -1e30f;
    float m = val;
#pragma unroll
    for (int o = 32; o; o >>= 1) m = fmaxf(m, __shfl_xor(m, o));
    float ex = (lane < 40) ? expf(val - m) : 0.f;
    float ssum = ex;
#pragma unroll
    for (int o = 32; o; o >>= 1) ssum += __shfl_xor(ssum, o);
    if (lane < 40) out[(size_t)w * 40 + lane] = val - m - logf(ssum);
}

// ---------------- launch ----------------
extern "C" void kernel_launch(void* const* d_in, const int* in_sizes, int n_in,
                              void* d_out, int out_size, void* d_ws, size_t ws_size,
                              hipStream_t stream)
{
    const float* X        = (const float*)d_in[0];
    const int*   node_idx = (const int*)d_in[1];
    const int*   edge_idx = (const int*)d_in[2];
    const float* W1 = (const float*)d_in[3];
    const float* b1 = (const float*)d_in[4];
    const float* W2 = (const float*)d_in[5];
    const float* b2 = (const float*)d_in[6];
    const float* W3 = (const float*)d_in[7];
    const float* b3 = (const float*)d_in[8];
    float* out = (float*)d_out;

    char* p = (char*)d_ws;
    auto alloc = [&](size_t bytes) -> char* {
        char* r = p;
        p += (bytes + 255) & ~(size_t)255;
        return r;
    };
    int*   cnt_e = (int*)alloc((size_t)N_EDGES * 4);
    int*   cnt_v = (int*)alloc((size_t)N_NODES * 4);
    int*   cur_e = (int*)alloc((size_t)N_EDGES * 4);
    int*   cur_v = (int*)alloc((size_t)N_NODES * 4);
    int*   off_e = (int*)alloc((size_t)(N_EDGES + 1) * 4);
    int*   off_v = (int*)alloc((size_t)(N_NODES + 1) * 4);
    float* inv_e = (float*)alloc((size_t)N_EDGES * 4);
    float* inv_v = (float*)alloc((size_t)N_NODES * 4);
    int*   csr_e = (int*)alloc((size_t)NNZ_CT * 4);
    int*   csr_v = (int*)alloc((size_t)NNZ_CT * 4);

    const int M16 = N_NODES / 16;              // 3125
    const int M16_PAD = 391 * 8;               // 3128 tiles covered by grid
    unsigned short* At  = (unsigned short*)alloc((size_t)M16_PAD * 4096 * 2);
    unsigned short* W1h = (unsigned short*)alloc((size_t)16 * 4096 * 2);
    unsigned short* W1l = (unsigned short*)alloc((size_t)16 * 4096 * 2);
    unsigned short* W2h = (unsigned short*)alloc((size_t)16 * 4096 * 2);
    unsigned short* W2l = (unsigned short*)alloc((size_t)16 * 4096 * 2);
    unsigned short* W3h = (unsigned short*)alloc((size_t)8 * 4096 * 2);
    unsigned short* W3l = (unsigned short*)alloc((size_t)8 * 4096 * 2);
    unsigned short* bufC = (unsigned short*)alloc((size_t)N_NODES * 256 * 2);
    unsigned short* bufE = (unsigned short*)alloc((size_t)N_EDGES * 256 * 2);
    unsigned short* bufE40 = (unsigned short*)alloc((size_t)N_EDGES * 40 * 2);

    size_t zspan = (size_t)((char*)cur_v + (size_t)N_NODES * 4 - (char*)cnt_e);
    hipMemsetAsync(cnt_e, 0, zspan, stream);

    count_kernel<<<(NNZ_CT + 255) / 256, 256, 0, stream>>>(node_idx, edge_idx, cnt_e, cnt_v);
    scan_dual<<<2, 1024, 0, stream>>>(cnt_e, off_e, inv_e, cnt_v, off_v, inv_v);
    fill_kernel<<<(NNZ_CT + 255) / 256, 256, 0, stream>>>(
        node_idx, edge_idx, off_e, off_v, cur_e, cur_v, csr_e, csr_v);

    convert_A_tiled<<<(M16 * 512 + 255) / 256, 256, 0, stream>>>(X, At, M16);
    convert_B_tiled<<<(16 * 512 + 255) / 256, 256, 0, stream>>>(W1, W1h, W1l, 256, 16);
    convert_B_tiled<<<(16 * 512 + 255) / 256, 256, 0, stream>>>(W2, W2h, W2l, 256, 16);
    convert_B_tiled<<<(8 * 512 + 255) / 256, 256, 0, stream>>>(W3, W3h, W3l, 40, 8);

    dim3 gbig(2, 391), gsmall(1, 391);
    const int gE = (N_EDGES + 3) / 4;
    const int gV = (N_NODES + 3) / 4;

    // layer 1
    gemm_bf16<<<gbig, 256, 0, stream>>>(At, W1h, W1l, bufC, N_NODES, 256, 256);
    agg_e256<<<gE, 256, 0, stream>>>(bufC, bufE, off_e, csr_e, inv_e, N_EDGES);
    agg_v256_blk<<<M16, 256, 0, stream>>>(bufE, At, off_v, csr_v, inv_v, b1);

    // layer 2
    gemm_bf16<<<gbig, 256, 0, stream>>>(At, W2h, W2l, bufC, N_NODES, 256, 256);
    agg_e256<<<gE, 256, 0, stream>>>(bufC, bufE, off_e, csr_e, inv_e, N_EDGES);
    agg_v256_blk<<<M16, 256, 0, stream>>>(bufE, At, off_v, csr_v, inv_v, b2);

    // layer 3
    gemm_bf16<<<gsmall, 256, 0, stream>>>(At, W3h, W3l, bufC, N_NODES, 40, 40);
    agg_mean40<<<gE, 256, 0, stream>>>(bufC, bufE40, off_e, csr_e, inv_e, N_EDGES);
    agg_v40_lsm<<<gV, 256, 0, stream>>>(bufE40, out, off_v, csr_v, inv_v, b3, N_NODES);
    (void)in_sizes; (void)n_in; (void)out_size; (void)ws_size;
}

// Round 5
// 393.104 us; speedup vs baseline: 2.1859x; 1.0716x over previous
//
#include <hip/hip_runtime.h>
#include <math.h>

#define N_NODES 50000
#define N_EDGES 20000
#define NNZ_CT  500000
#define KDIM    256
#define K32     8

typedef __attribute__((ext_vector_type(8))) short    short8v;
typedef __attribute__((ext_vector_type(4))) float    f32x4;
typedef __attribute__((ext_vector_type(8))) unsigned short ushort8v;
typedef __attribute__((ext_vector_type(4))) unsigned short ushort4v;

#define GLD16(g, l) __builtin_amdgcn_global_load_lds( \
    (const __attribute__((address_space(1))) unsigned int*)(g), \
    (__attribute__((address_space(3))) unsigned int*)(l), 16, 0, 0)

__device__ __forceinline__ unsigned short bf16_rne(float f) {
    unsigned u = __float_as_uint(f);
    return (unsigned short)((u + 0x7FFFu + ((u >> 16) & 1u)) >> 16);
}
__device__ __forceinline__ float bf16_to_f(unsigned short h) {
    return __uint_as_float(((unsigned)h) << 16);
}
__device__ __forceinline__ void bf16_split(float f, unsigned short& h, unsigned short& l) {
    unsigned u = __float_as_uint(f);
    unsigned hb = (u + 0x7FFFu + ((u >> 16) & 1u)) >> 16;
    h = (unsigned short)hb;
    float r = f - __uint_as_float(hb << 16);
    unsigned ru = __float_as_uint(r);
    l = (unsigned short)((ru + 0x7FFFu + ((ru >> 16) & 1u)) >> 16);
}

// ---- convert fp32 X[M,256] -> row-major bf16 ----
__global__ __launch_bounds__(256) void convert_X_row(
    const float* __restrict__ X, unsigned short* __restrict__ Xb, int n8)
{
    int t = blockIdx.x * 256 + threadIdx.x;
    if (t >= n8) return;
    const float* src = X + (size_t)t * 8;
    float f[8];
    *(float4*)(f)     = *(const float4*)(src);
    *(float4*)(f + 4) = *(const float4*)(src + 4);
    ushort8v h;
#pragma unroll
    for (int j = 0; j < 8; j++) h[j] = bf16_rne(f[j]);
    *(ushort8v*)(Xb + (size_t)t * 8) = h;
}

// ---- convert fp32 B[K,Ncols] -> fragment-tiled bf16 hi/lo (zero-pad cols) ----
__global__ __launch_bounds__(256) void convert_B_tiled(
    const float* __restrict__ B, unsigned short* __restrict__ Bh,
    unsigned short* __restrict__ Bl, int Ncols, int n16_count)
{
    int t = blockIdx.x * 256 + threadIdx.x;
    if (t >= n16_count * 512) return;
    int lane = t & 63, k32 = (t >> 6) & 7, n16 = t >> 9;
    int col = n16 * 16 + (lane & 15);
    int k0  = k32 * 32 + (lane >> 4) * 8;
    ushort8v h, l;
#pragma unroll
    for (int j = 0; j < 8; j++) {
        float f = (col < Ncols) ? B[(size_t)(k0 + j) * Ncols + col] : 0.f;
        unsigned short hh, ll; bf16_split(f, hh, ll); h[j] = hh; l[j] = ll;
    }
    size_t off = (((size_t)n16 * 8 + k32) << 9) + lane * 8;
    *(ushort8v*)(Bh + off) = h;
    *(ushort8v*)(Bl + off) = l;
}

// ---- MFMA GEMM: A tiled bf16, B tiled split hi/lo; C bf16 row-major ----
__global__ __launch_bounds__(256) void gemm_bf16(
    const unsigned short* __restrict__ At,
    const unsigned short* __restrict__ Bh, const unsigned short* __restrict__ Bl,
    unsigned short* __restrict__ C, int M, int Ncols, int ldC)
{
    __shared__ unsigned short lds[16384];
    const int tid  = threadIdx.x;
    const int lane = tid & 63, wid = tid >> 6;
    const int wr = wid >> 1, wc = wid & 1;
    const int m0t = blockIdx.y * 8;
    const int n0t = blockIdx.x * 8;

    f32x4 acc[4][4] = {};

    for (int k32 = 0; k32 < K32; ++k32) {
#pragma unroll
        for (int i = 0; i < 6; ++i) {
            int c = i * 4 + wid;               // 0..23
            if (c < 8) {
                const unsigned short* gA = At + (((size_t)(m0t + c) * 8 + k32) << 9) + lane * 8;
                GLD16(gA, &lds[c * 512 + lane * 8]);
            } else {
                int idx = c - 8, half = idx >> 3, st = idx & 7;
                const unsigned short* gB = (half ? Bl : Bh)
                    + (((size_t)(n0t + st) * 8 + k32) << 9) + lane * 8;
                GLD16(gB, &lds[4096 + idx * 512 + lane * 8]);
            }
        }
        __syncthreads();
        short8v a[4], bh[4], bl[4];
#pragma unroll
        for (int x = 0; x < 4; ++x) {
            a[x]  = *(const short8v*)&lds[(wr * 4 + x) * 512 + lane * 8];
            bh[x] = *(const short8v*)&lds[4096 + (wc * 4 + x) * 512 + lane * 8];
            bl[x] = *(const short8v*)&lds[4096 + (8 + wc * 4 + x) * 512 + lane * 8];
        }
#pragma unroll
        for (int mi = 0; mi < 4; ++mi)
#pragma unroll
            for (int ni = 0; ni < 4; ++ni) {
                acc[mi][ni] = __builtin_amdgcn_mfma_f32_16x16x32_bf16(a[mi], bh[ni], acc[mi][ni], 0, 0, 0);
                acc[mi][ni] = __builtin_amdgcn_mfma_f32_16x16x32_bf16(a[mi], bl[ni], acc[mi][ni], 0, 0, 0);
            }
        __syncthreads();
    }

    // epilogue: bounce through LDS (XOR-swizzled), write bf16 row-major
    {
        const int rg = lane >> 4, cl = lane & 15;
        const int base = wid * 4096;
#pragma unroll
        for (int mi = 0; mi < 4; ++mi) {
            int swz = ((mi * 4 + rg) & 3) << 4;
#pragma unroll
            for (int ni = 0; ni < 4; ++ni) {
                int colf = (ni * 16 + cl) ^ swz;
#pragma unroll
                for (int r = 0; r < 4; ++r)
                    lds[base + (mi * 16 + rg * 4 + r) * 64 + colf] = bf16_rne(acc[mi][ni][r]);
            }
        }
    }
    __syncthreads();
    {
        int row = tid >> 1, half = tid & 1;
        int grow = blockIdx.y * 128 + row;
        if (grow < M) {
            int wsrc = (row >> 6) * 2 + half;
            int rl = row & 63;
            int swz = ((rl >> 2) & 3) << 4;
            unsigned short* dst = C + (size_t)grow * ldC + n0t * 16 + half * 64;
#pragma unroll
            for (int s = 0; s < 8; ++s) {
                int c0 = half * 64 + s * 8;
                if (n0t * 16 + c0 + 8 <= Ncols) {
                    ushort8v v = *(const ushort8v*)&lds[wsrc * 4096 + rl * 64 + ((s * 8) ^ swz)];
                    *(ushort8v*)(dst + s * 8) = v;
                }
            }
        }
    }
}

// ---- partitioned degree count: partition p = blockIdx&7 owns key ranges ----
__global__ __launch_bounds__(256) void count8(
    const int* __restrict__ node_idx, const int* __restrict__ edge_idx,
    int* __restrict__ cnt_e, int* __restrict__ cnt_v)
{
    int part = blockIdx.x & 7, blk = blockIdx.x >> 3, nblk = gridDim.x >> 3;
    int elo = part * (N_EDGES / 8), ehi = elo + N_EDGES / 8;
    int vlo = part * (N_NODES / 8), vhi = vlo + N_NODES / 8;
    for (int i = blk * 256 + threadIdx.x; i < NNZ_CT; i += nblk * 256) {
        int e = edge_idx[i];
        if (e >= elo && e < ehi) atomicAdd(&cnt_e[e], 1);
        int v = node_idx[i];
        if (v >= vlo && v < vhi) atomicAdd(&cnt_v[v], 1);
    }
}

// ---- dual single-pass scans (block 0: edges, block 1: nodes), int4 chunks ----
__global__ __launch_bounds__(1024) void scan_dual(
    const int* __restrict__ cnt_e, int* __restrict__ off_e, float* __restrict__ inv_e,
    const int* __restrict__ cnt_v, int* __restrict__ off_v, float* __restrict__ inv_v)
{
    const int* cnt; int* off; float* inv; int n;
    if (blockIdx.x == 0) { cnt = cnt_e; off = off_e; inv = inv_e; n = N_EDGES; }
    else                 { cnt = cnt_v; off = off_v; inv = inv_v; n = N_NODES; }
    __shared__ int wsum[16];
    __shared__ int carry_s;
    int tid = threadIdx.x, lane = tid & 63, wid = tid >> 6;
    if (tid == 0) carry_s = 0;
    __syncthreads();
    for (int base = 0; base < n; base += 4096) {
        int i4 = base + tid * 4;
        int4 x = make_int4(0, 0, 0, 0);
        if (i4 + 3 < n) x = *(const int4*)(cnt + i4);
        else if (i4 < n) {
            x.x = cnt[i4];
            if (i4 + 1 < n) x.y = cnt[i4 + 1];
            if (i4 + 2 < n) x.z = cnt[i4 + 2];
        }
        int s0 = x.x, s1 = s0 + x.y, s2 = s1 + x.z, s3 = s2 + x.w;
        int incl = s3;
#pragma unroll
        for (int o = 1; o < 64; o <<= 1) { int t = __shfl_up(incl, o, 64); if (lane >= o) incl += t; }
        if (lane == 63) wsum[wid] = incl;
        __syncthreads();
        if (wid == 0) {
            int v = (lane < 16) ? wsum[lane] : 0;
#pragma unroll
            for (int o = 1; o < 16; o <<= 1) { int t = __shfl_up(v, o, 64); if (lane >= o) v += t; }
            if (lane < 16) wsum[lane] = v;
        }
        __syncthreads();
        int wpre = (wid == 0) ? 0 : wsum[wid - 1];
        int carry = carry_s;
        int excl = carry + wpre + incl - s3;
        if (i4 < n) {
            int e0 = excl, e1 = excl + s0, e2 = excl + s1, e3 = excl + s2;
            if (i4 + 3 < n) { *(int4*)(off + i4) = make_int4(e0, e1, e2, e3); }
            else {
                off[i4] = e0;
                if (i4 + 1 < n) off[i4 + 1] = e1;
                if (i4 + 2 < n) off[i4 + 2] = e2;
            }
            inv[i4] = 1.0f / fmaxf((float)x.x, 1.0f);
            if (i4 + 1 < n) inv[i4 + 1] = 1.0f / fmaxf((float)x.y, 1.0f);
            if (i4 + 2 < n) inv[i4 + 2] = 1.0f / fmaxf((float)x.z, 1.0f);
            if (i4 + 3 < n) inv[i4 + 3] = 1.0f / fmaxf((float)x.w, 1.0f);
        }
        __syncthreads();
        if (tid == 1023) carry_s = carry + wpre + incl;
        __syncthreads();
    }
    if (tid == 0) off[n] = carry_s;
}

// ---- partitioned CSR fill: writes and atomics stay in partition-local ranges ----
__global__ __launch_bounds__(256) void fill8(
    const int* __restrict__ node_idx, const int* __restrict__ edge_idx,
    const int* __restrict__ off_e, const int* __restrict__ off_v,
    int* __restrict__ cur_e, int* __restrict__ cur_v,
    int* __restrict__ csr_e_nodes, int* __restrict__ csr_v_edges)
{
    int part = blockIdx.x & 7, blk = blockIdx.x >> 3, nblk = gridDim.x >> 3;
    int elo = part * (N_EDGES / 8), ehi = elo + N_EDGES / 8;
    int vlo = part * (N_NODES / 8), vhi = vlo + N_NODES / 8;
    for (int i = blk * 256 + threadIdx.x; i < NNZ_CT; i += nblk * 256) {
        int e = edge_idx[i], v = node_idx[i];
        if (e >= elo && e < ehi) {
            int p0 = atomicAdd(&cur_e[e], 1);
            csr_e_nodes[off_e[e] + p0] = v;
        }
        if (v >= vlo && v < vhi) {
            int p1 = atomicAdd(&cur_v[v], 1);
            csr_v_edges[off_v[v] + p1] = e;
        }
    }
}

// ---- V->E mean (256-dim) -> fragment-tiled bf16; block = one e16 tile ----
__global__ __launch_bounds__(256) void agg_e256_tiled(
    const unsigned short* __restrict__ src, unsigned short* __restrict__ Et,
    const int* __restrict__ offs, const int* __restrict__ lists,
    const float* __restrict__ invdeg)
{
    __shared__ unsigned short hbuf[16 * 264];
    int tid = threadIdx.x, lane = tid & 63, wid = tid >> 6;
    int e16 = blockIdx.x;
#pragma unroll
    for (int q = 0; q < 4; ++q) {
        int el = wid * 4 + q;
        int w = e16 * 16 + el;
        int s = offs[w], e = offs[w + 1];
        float a0 = 0.f, a1 = 0.f, a2 = 0.f, a3 = 0.f;
        for (int j = s; j < e; j += 8) {
            int r[8]; float m[8];
            r[0] = lists[j]; m[0] = 1.f;
#pragma unroll
            for (int u = 1; u < 8; ++u) {
                bool ok = (j + u) < e;
                r[u] = ok ? lists[j + u] : r[0];
                m[u] = ok ? 1.f : 0.f;
            }
            ushort4v v[8];
#pragma unroll
            for (int u = 0; u < 8; ++u)
                v[u] = *(const ushort4v*)(src + (size_t)r[u] * 256 + lane * 4);
            a0 += bf16_to_f(v[0][0]); a1 += bf16_to_f(v[0][1]);
            a2 += bf16_to_f(v[0][2]); a3 += bf16_to_f(v[0][3]);
#pragma unroll
            for (int u = 1; u < 8; ++u) {
                a0 = fmaf(m[u], bf16_to_f(v[u][0]), a0);
                a1 = fmaf(m[u], bf16_to_f(v[u][1]), a1);
                a2 = fmaf(m[u], bf16_to_f(v[u][2]), a2);
                a3 = fmaf(m[u], bf16_to_f(v[u][3]), a3);
            }
        }
        float sc = invdeg[w];
        ushort4v o;
        o[0] = bf16_rne(a0 * sc); o[1] = bf16_rne(a1 * sc);
        o[2] = bf16_rne(a2 * sc); o[3] = bf16_rne(a3 * sc);
        *(ushort4v*)&hbuf[el * 264 + lane * 4] = o;
    }
    __syncthreads();
#pragma unroll
    for (int u = 0; u < 2; ++u) {
        int sl = tid * 2 + u;
        int k32 = sl >> 6, lt = sl & 63;
        int row = lt & 15, hi = lt >> 4;
        int k0 = k32 * 32 + hi * 8;
        ushort8v v = *(const ushort8v*)&hbuf[row * 264 + k0];
        *(ushort8v*)(Et + (((size_t)e16 * 8 + k32) << 9) + lt * 8) = v;
    }
}

// ---- E->V mean + bias + relu -> row-major bf16; wave per node ----
__global__ __launch_bounds__(256) void agg_v256_row(
    const unsigned short* __restrict__ src, unsigned short* __restrict__ Vb,
    const int* __restrict__ offs, const int* __restrict__ lists,
    const float* __restrict__ invdeg, const float* __restrict__ bias, int nseg)
{
    int w = (blockIdx.x * 256 + threadIdx.x) >> 6;
    int lane = threadIdx.x & 63;
    if (w >= nseg) return;
    int s = offs[w], e = offs[w + 1];
    float a0 = 0.f, a1 = 0.f, a2 = 0.f, a3 = 0.f;
    for (int j = s; j < e; j += 4) {
        int r[4]; float m[4];
        r[0] = lists[j]; m[0] = 1.f;
#pragma unroll
        for (int u = 1; u < 4; ++u) {
            bool ok = (j + u) < e;
            r[u] = ok ? lists[j + u] : r[0];
            m[u] = ok ? 1.f : 0.f;
        }
        ushort4v v[4];
#pragma unroll
        for (int u = 0; u < 4; ++u)
            v[u] = *(const ushort4v*)(src + (size_t)r[u] * 256 + lane * 4);
        a0 += bf16_to_f(v[0][0]); a1 += bf16_to_f(v[0][1]);
        a2 += bf16_to_f(v[0][2]); a3 += bf16_to_f(v[0][3]);
#pragma unroll
        for (int u = 1; u < 4; ++u) {
            a0 = fmaf(m[u], bf16_to_f(v[u][0]), a0);
            a1 = fmaf(m[u], bf16_to_f(v[u][1]), a1);
            a2 = fmaf(m[u], bf16_to_f(v[u][2]), a2);
            a3 = fmaf(m[u], bf16_to_f(v[u][3]), a3);
        }
    }
    float sc = invdeg[w];
    const float4 b = *(const float4*)(bias + lane * 4);
    ushort4v o;
    o[0] = bf16_rne(fmaxf(a0 * sc + b.x, 0.f));
    o[1] = bf16_rne(fmaxf(a1 * sc + b.y, 0.f));
    o[2] = bf16_rne(fmaxf(a2 * sc + b.z, 0.f));
    o[3] = bf16_rne(fmaxf(a3 * sc + b.w, 0.f));
    *(ushort4v*)(Vb + (size_t)w * 256 + lane * 4) = o;
}

// ---- E->V mean + bias + relu -> fragment-tiled bf16; block = one m16 tile ----
__global__ __launch_bounds__(256) void agg_v256_blk(
    const unsigned short* __restrict__ src, unsigned short* __restrict__ At,
    const int* __restrict__ offs, const int* __restrict__ lists,
    const float* __restrict__ invdeg, const float* __restrict__ bias)
{
    __shared__ unsigned short hbuf[16 * 264];
    int tid = threadIdx.x, lane = tid & 63, wid = tid >> 6;
    int m16 = blockIdx.x;
    const float4 b = *(const float4*)(bias + lane * 4);
#pragma unroll
    for (int q = 0; q < 4; ++q) {
        int nl = wid * 4 + q;
        int w = m16 * 16 + nl;
        int s = offs[w], e = offs[w + 1];
        float a0 = 0.f, a1 = 0.f, a2 = 0.f, a3 = 0.f;
        for (int j = s; j < e; j += 4) {
            int r[4]; float m[4];
            r[0] = lists[j]; m[0] = 1.f;
#pragma unroll
            for (int u = 1; u < 4; ++u) {
                bool ok = (j + u) < e;
                r[u] = ok ? lists[j + u] : r[0];
                m[u] = ok ? 1.f : 0.f;
            }
            ushort4v v[4];
#pragma unroll
            for (int u = 0; u < 4; ++u)
                v[u] = *(const ushort4v*)(src + (size_t)r[u] * 256 + lane * 4);
            a0 += bf16_to_f(v[0][0]); a1 += bf16_to_f(v[0][1]);
            a2 += bf16_to_f(v[0][2]); a3 += bf16_to_f(v[0][3]);
#pragma unroll
            for (int u = 1; u < 4; ++u) {
                a0 = fmaf(m[u], bf16_to_f(v[u][0]), a0);
                a1 = fmaf(m[u], bf16_to_f(v[u][1]), a1);
                a2 = fmaf(m[u], bf16_to_f(v[u][2]), a2);
                a3 = fmaf(m[u], bf16_to_f(v[u][3]), a3);
            }
        }
        float sc = invdeg[w];
        ushort4v o;
        o[0] = bf16_rne(fmaxf(a0 * sc + b.x, 0.f));
        o[1] = bf16_rne(fmaxf(a1 * sc + b.y, 0.f));
        o[2] = bf16_rne(fmaxf(a2 * sc + b.z, 0.f));
        o[3] = bf16_rne(fmaxf(a3 * sc + b.w, 0.f));
        *(ushort4v*)&hbuf[nl * 264 + lane * 4] = o;
    }
    __syncthreads();
#pragma unroll
    for (int u = 0; u < 2; ++u) {
        int sl = tid * 2 + u;
        int k32 = sl >> 6, lt = sl & 63;
        int row = lt & 15, hi = lt >> 4;
        int k0 = k32 * 32 + hi * 8;
        ushort8v v = *(const ushort8v*)&hbuf[row * 264 + k0];
        *(ushort8v*)(At + (((size_t)m16 * 8 + k32) << 9) + lt * 8) = v;
    }
}

// ---- mean-aggregation, F=40 (edges), bf16 in, bf16 out, 8 in flight ----
__global__ __launch_bounds__(256) void agg_mean40(
    const unsigned short* __restrict__ src, unsigned short* __restrict__ dst,
    const int* __restrict__ offs, const int* __restrict__ lists,
    const float* __restrict__ invdeg, int nseg)
{
    int w = (blockIdx.x * 256 + threadIdx.x) >> 6;
    int lane = threadIdx.x & 63;
    if (w >= nseg) return;
    int s = offs[w], e = offs[w + 1];
    if (lane < 40) {
        float acc = 0.f;
        for (int j = s; j < e; j += 8) {
            int r[8]; float m[8];
            r[0] = lists[j]; m[0] = 1.f;
#pragma unroll
            for (int u = 1; u < 8; ++u) {
                bool ok = (j + u) < e;
                r[u] = ok ? lists[j + u] : r[0];
                m[u] = ok ? 1.f : 0.f;
            }
            float v[8];
#pragma unroll
            for (int u = 0; u < 8; ++u)
                v[u] = bf16_to_f(src[(size_t)r[u] * 40 + lane]);
            acc += v[0];
#pragma unroll
            for (int u = 1; u < 8; ++u) acc = fmaf(m[u], v[u], acc);
        }
        dst[(size_t)w * 40 + lane] = bf16_rne(acc * invdeg[w]);
    }
}

// ------- final E->V mean at F=40 + bias + log_softmax, wave per node -------
__global__ __launch_bounds__(256) void agg_v40_lsm(
    const unsigned short* __restrict__ efeat, float* __restrict__ out,
    const int* __restrict__ offs, const int* __restrict__ lists,
    const float* __restrict__ invdeg, const float* __restrict__ bias,
    int nseg)
{
    int w = (blockIdx.x * 256 + threadIdx.x) >> 6;
    int lane = threadIdx.x & 63;
    if (w >= nseg) return;
    int s = offs[w], e = offs[w + 1];
    float acc = 0.f;
    if (lane < 40) {
        for (int j = s; j < e; j += 4) {
            int r[4]; float m[4];
            r[0] = lists[j]; m[0] = 1.f;
#pragma unroll
            for (int u = 1; u < 4; ++u) {
                bool ok = (j + u) < e;
                r[u] = ok ? lists[j + u] : r[0];
                m[u] = ok ? 1.f : 0.f;
            }
            float v[4];
#pragma unroll
            for (int u = 0; u < 4; ++u)
                v[u] = bf16_to_f(efeat[(size_t)r[u] * 40 + lane]);
            acc += v[0];
#pragma unroll
            for (int u = 1; u < 4; ++u) acc = fmaf(m[u], v[u], acc);
        }
    }
    float val = (lane < 40) ? (acc * invdeg[w] + bias[lane]) : -1e30f;
    float m = val;
#pragma unroll
    for (int o = 32; o; o >>= 1) m = fmaxf(m, __shfl_xor(m, o));
    float ex = (lane < 40) ? expf(val - m) : 0.f;
    float ssum = ex;
#pragma unroll
    for (int o = 32; o; o >>= 1) ssum += __shfl_xor(ssum, o);
    if (lane < 40) out[(size_t)w * 40 + lane] = val - m - logf(ssum);
}

// ---------------- launch ----------------
extern "C" void kernel_launch(void* const* d_in, const int* in_sizes, int n_in,
                              void* d_out, int out_size, void* d_ws, size_t ws_size,
                              hipStream_t stream)
{
    const float* X        = (const float*)d_in[0];
    const int*   node_idx = (const int*)d_in[1];
    const int*   edge_idx = (const int*)d_in[2];
    const float* W1 = (const float*)d_in[3];
    const float* b1 = (const float*)d_in[4];
    const float* W2 = (const float*)d_in[5];
    const float* b2 = (const float*)d_in[6];
    const float* W3 = (const float*)d_in[7];
    const float* b3 = (const float*)d_in[8];
    float* out = (float*)d_out;

    char* p = (char*)d_ws;
    auto alloc = [&](size_t bytes) -> char* {
        char* r = p;
        p += (bytes + 255) & ~(size_t)255;
        return r;
    };
    int*   cnt_e = (int*)alloc((size_t)N_EDGES * 4);
    int*   cnt_v = (int*)alloc((size_t)N_NODES * 4);
    int*   cur_e = (int*)alloc((size_t)N_EDGES * 4);
    int*   cur_v = (int*)alloc((size_t)N_NODES * 4);
    int*   off_e = (int*)alloc((size_t)(N_EDGES + 1) * 4);
    int*   off_v = (int*)alloc((size_t)(N_NODES + 1) * 4);
    float* inv_e = (float*)alloc((size_t)N_EDGES * 4);
    float* inv_v = (float*)alloc((size_t)N_NODES * 4);
    int*   csr_e = (int*)alloc((size_t)NNZ_CT * 4);
    int*   csr_v = (int*)alloc((size_t)NNZ_CT * 4);

    const int M16 = N_NODES / 16;              // 3125
    const int M16_PAD = 391 * 8;               // 3128 (GEMM-V grid coverage)
    const int E16 = N_EDGES / 16;              // 1250
    const int E16_PAD = 157 * 8;               // 1256 (GEMM-E grid coverage)
    unsigned short* Xb  = (unsigned short*)alloc((size_t)N_NODES * 256 * 2);   // row-major V activations
    unsigned short* At  = (unsigned short*)alloc((size_t)M16_PAD * 4096 * 2);  // tiled V acts (L3 GEMM in)
    unsigned short* Et  = (unsigned short*)alloc((size_t)E16_PAD * 4096 * 2);  // tiled E aggregates
    unsigned short* Ef  = (unsigned short*)alloc((size_t)N_EDGES * 256 * 2);   // row-major E features
    unsigned short* W1h = (unsigned short*)alloc((size_t)16 * 4096 * 2);
    unsigned short* W1l = (unsigned short*)alloc((size_t)16 * 4096 * 2);
    unsigned short* W2h = (unsigned short*)alloc((size_t)16 * 4096 * 2);
    unsigned short* W2l = (unsigned short*)alloc((size_t)16 * 4096 * 2);
    unsigned short* W3h = (unsigned short*)alloc((size_t)8 * 4096 * 2);
    unsigned short* W3l = (unsigned short*)alloc((size_t)8 * 4096 * 2);
    unsigned short* C40 = (unsigned short*)alloc((size_t)N_NODES * 40 * 2);
    unsigned short* E40 = (unsigned short*)alloc((size_t)N_EDGES * 40 * 2);

    size_t zspan = (size_t)((char*)cur_v + (size_t)N_NODES * 4 - (char*)cnt_e);
    hipMemsetAsync(cnt_e, 0, zspan, stream);

    count8<<<512, 256, 0, stream>>>(node_idx, edge_idx, cnt_e, cnt_v);
    scan_dual<<<2, 1024, 0, stream>>>(cnt_e, off_e, inv_e, cnt_v, off_v, inv_v);
    fill8<<<512, 256, 0, stream>>>(node_idx, edge_idx, off_e, off_v, cur_e, cur_v, csr_e, csr_v);

    convert_X_row<<<(N_NODES * 256 / 8 + 255) / 256, 256, 0, stream>>>(X, Xb, N_NODES * 256 / 8);
    convert_B_tiled<<<(16 * 512 + 255) / 256, 256, 0, stream>>>(W1, W1h, W1l, 256, 16);
    convert_B_tiled<<<(16 * 512 + 255) / 256, 256, 0, stream>>>(W2, W2h, W2l, 256, 16);
    convert_B_tiled<<<(8 * 512 + 255) / 256, 256, 0, stream>>>(W3, W3h, W3l, 40, 8);

    dim3 gE_gemm(2, 157);    // GEMM on 20000 edge rows
    dim3 gV_gemm(1, 391);    // GEMM on 50000 node rows (layer 3, 40 cols)
    const int gEw = (N_EDGES + 3) / 4;
    const int gVw = (N_NODES + 3) / 4;

    // layer 1: V->E agg first (commutes with GEMM), GEMM on edges, E->V to row-major
    agg_e256_tiled<<<E16, 256, 0, stream>>>(Xb, Et, off_e, csr_e, inv_e);
    gemm_bf16<<<gE_gemm, 256, 0, stream>>>(Et, W1h, W1l, Ef, N_EDGES, 256, 256);
    agg_v256_row<<<gVw, 256, 0, stream>>>(Ef, Xb, off_v, csr_v, inv_v, b1, N_NODES);

    // layer 2: same; E->V writes tiled (feeds layer-3 GEMM-V)
    agg_e256_tiled<<<E16, 256, 0, stream>>>(Xb, Et, off_e, csr_e, inv_e);
    gemm_bf16<<<gE_gemm, 256, 0, stream>>>(Et, W2h, W2l, Ef, N_EDGES, 256, 256);
    agg_v256_blk<<<M16, 256, 0, stream>>>(Ef, At, off_v, csr_v, inv_v, b2);

    // layer 3: GEMM-V to 40 cols, then 40-dim aggs + log_softmax
    gemm_bf16<<<gV_gemm, 256, 0, stream>>>(At, W3h, W3l, C40, N_NODES, 40, 40);
    agg_mean40<<<gEw, 256, 0, stream>>>(C40, E40, off_e, csr_e, inv_e, N_EDGES);
    agg_v40_lsm<<<gVw, 256, 0, stream>>>(E40, out, off_v, csr_v, inv_v, b3, N_NODES);
    (void)in_sizes; (void)n_in; (void)out_size; (void)ws_size;
}

// Round 6
// 391.107 us; speedup vs baseline: 2.1971x; 1.0051x over previous
//
#include <hip/hip_runtime.h>
#include <math.h>

#define N_NODES 50000
#define N_EDGES 20000
#define NNZ_CT  500000
#define KDIM    256
#define K32     8

typedef __attribute__((ext_vector_type(8))) short    short8v;
typedef __attribute__((ext_vector_type(4))) float    f32x4;
typedef __attribute__((ext_vector_type(8))) unsigned short ushort8v;
typedef __attribute__((ext_vector_type(4))) unsigned short ushort4v;

#define GLD16(g, l) __builtin_amdgcn_global_load_lds( \
    (const __attribute__((address_space(1))) unsigned int*)(g), \
    (__attribute__((address_space(3))) unsigned int*)(l), 16, 0, 0)

__device__ __forceinline__ unsigned short bf16_rne(float f) {
    unsigned u = __float_as_uint(f);
    return (unsigned short)((u + 0x7FFFu + ((u >> 16) & 1u)) >> 16);
}
__device__ __forceinline__ float bf16_to_f(unsigned short h) {
    return __uint_as_float(((unsigned)h) << 16);
}
__device__ __forceinline__ void bf16_split(float f, unsigned short& h, unsigned short& l) {
    unsigned u = __float_as_uint(f);
    unsigned hb = (u + 0x7FFFu + ((u >> 16) & 1u)) >> 16;
    h = (unsigned short)hb;
    float r = f - __uint_as_float(hb << 16);
    unsigned ru = __float_as_uint(r);
    l = (unsigned short)((ru + 0x7FFFu + ((ru >> 16) & 1u)) >> 16);
}

// ---- convert fp32 X[M,256] -> row-major bf16 ----
__global__ __launch_bounds__(256) void convert_X_row(
    const float* __restrict__ X, unsigned short* __restrict__ Xb, int n8)
{
    int t = blockIdx.x * 256 + threadIdx.x;
    if (t >= n8) return;
    const float* src = X + (size_t)t * 8;
    float f[8];
    *(float4*)(f)     = *(const float4*)(src);
    *(float4*)(f + 4) = *(const float4*)(src + 4);
    ushort8v h;
#pragma unroll
    for (int j = 0; j < 8; j++) h[j] = bf16_rne(f[j]);
    *(ushort8v*)(Xb + (size_t)t * 8) = h;
}

// ---- convert fp32 B[K,Ncols] -> fragment-tiled bf16 hi/lo (zero-pad cols) ----
__global__ __launch_bounds__(256) void convert_B_tiled(
    const float* __restrict__ B, unsigned short* __restrict__ Bh,
    unsigned short* __restrict__ Bl, int Ncols, int n16_count)
{
    int t = blockIdx.x * 256 + threadIdx.x;
    if (t >= n16_count * 512) return;
    int lane = t & 63, k32 = (t >> 6) & 7, n16 = t >> 9;
    int col = n16 * 16 + (lane & 15);
    int k0  = k32 * 32 + (lane >> 4) * 8;
    ushort8v h, l;
#pragma unroll
    for (int j = 0; j < 8; j++) {
        float f = (col < Ncols) ? B[(size_t)(k0 + j) * Ncols + col] : 0.f;
        unsigned short hh, ll; bf16_split(f, hh, ll); h[j] = hh; l[j] = ll;
    }
    size_t off = (((size_t)n16 * 8 + k32) << 9) + lane * 8;
    *(ushort8v*)(Bh + off) = h;
    *(ushort8v*)(Bl + off) = l;
}

// ---- MFMA GEMM: A tiled bf16, B tiled split hi/lo; C bf16 row-major ----
__global__ __launch_bounds__(256) void gemm_bf16(
    const unsigned short* __restrict__ At,
    const unsigned short* __restrict__ Bh, const unsigned short* __restrict__ Bl,
    unsigned short* __restrict__ C, int M, int Ncols, int ldC)
{
    __shared__ unsigned short lds[16384];
    const int tid  = threadIdx.x;
    const int lane = tid & 63, wid = tid >> 6;
    const int wr = wid >> 1, wc = wid & 1;
    const int m0t = blockIdx.y * 8;
    const int n0t = blockIdx.x * 8;

    f32x4 acc[4][4] = {};

    for (int k32 = 0; k32 < K32; ++k32) {
#pragma unroll
        for (int i = 0; i < 6; ++i) {
            int c = i * 4 + wid;               // 0..23
            if (c < 8) {
                const unsigned short* gA = At + (((size_t)(m0t + c) * 8 + k32) << 9) + lane * 8;
                GLD16(gA, &lds[c * 512 + lane * 8]);
            } else {
                int idx = c - 8, half = idx >> 3, st = idx & 7;
                const unsigned short* gB = (half ? Bl : Bh)
                    + (((size_t)(n0t + st) * 8 + k32) << 9) + lane * 8;
                GLD16(gB, &lds[4096 + idx * 512 + lane * 8]);
            }
        }
        __syncthreads();
        short8v a[4], bh[4], bl[4];
#pragma unroll
        for (int x = 0; x < 4; ++x) {
            a[x]  = *(const short8v*)&lds[(wr * 4 + x) * 512 + lane * 8];
            bh[x] = *(const short8v*)&lds[4096 + (wc * 4 + x) * 512 + lane * 8];
            bl[x] = *(const short8v*)&lds[4096 + (8 + wc * 4 + x) * 512 + lane * 8];
        }
#pragma unroll
        for (int mi = 0; mi < 4; ++mi)
#pragma unroll
            for (int ni = 0; ni < 4; ++ni) {
                acc[mi][ni] = __builtin_amdgcn_mfma_f32_16x16x32_bf16(a[mi], bh[ni], acc[mi][ni], 0, 0, 0);
                acc[mi][ni] = __builtin_amdgcn_mfma_f32_16x16x32_bf16(a[mi], bl[ni], acc[mi][ni], 0, 0, 0);
            }
        __syncthreads();
    }

    // epilogue: bounce through LDS (XOR-swizzled), write bf16 row-major
    {
        const int rg = lane >> 4, cl = lane & 15;
        const int base = wid * 4096;
#pragma unroll
        for (int mi = 0; mi < 4; ++mi) {
            int swz = ((mi * 4 + rg) & 3) << 4;
#pragma unroll
            for (int ni = 0; ni < 4; ++ni) {
                int colf = (ni * 16 + cl) ^ swz;
#pragma unroll
                for (int r = 0; r < 4; ++r)
                    lds[base + (mi * 16 + rg * 4 + r) * 64 + colf] = bf16_rne(acc[mi][ni][r]);
            }
        }
    }
    __syncthreads();
    {
        int row = tid >> 1, half = tid & 1;
        int grow = blockIdx.y * 128 + row;
        if (grow < M) {
            int wsrc = (row >> 6) * 2 + half;
            int rl = row & 63;
            int swz = ((rl >> 2) & 3) << 4;
            unsigned short* dst = C + (size_t)grow * ldC + n0t * 16 + half * 64;
#pragma unroll
            for (int s = 0; s < 8; ++s) {
                int c0 = half * 64 + s * 8;
                if (n0t * 16 + c0 + 8 <= Ncols) {
                    ushort8v v = *(const ushort8v*)&lds[wsrc * 4096 + rl * 64 + ((s * 8) ^ swz)];
                    *(ushort8v*)(dst + s * 8) = v;
                }
            }
        }
    }
}

// ---- partitioned degree count: partition p = blockIdx&7 owns key ranges ----
__global__ __launch_bounds__(256) void count8(
    const int* __restrict__ node_idx, const int* __restrict__ edge_idx,
    int* __restrict__ cnt_e, int* __restrict__ cnt_v)
{
    int part = blockIdx.x & 7, blk = blockIdx.x >> 3, nblk = gridDim.x >> 3;
    int elo = part * (N_EDGES / 8), ehi = elo + N_EDGES / 8;
    int vlo = part * (N_NODES / 8), vhi = vlo + N_NODES / 8;
    for (int i = blk * 256 + threadIdx.x; i < NNZ_CT; i += nblk * 256) {
        int e = edge_idx[i];
        if (e >= elo && e < ehi) atomicAdd(&cnt_e[e], 1);
        int v = node_idx[i];
        if (v >= vlo && v < vhi) atomicAdd(&cnt_v[v], 1);
    }
}

// ---- dual single-pass scans; writes off, a working copy (cur), and invdeg ----
__global__ __launch_bounds__(1024) void scan_dual(
    const int* __restrict__ cnt_e, int* __restrict__ off_e, int* __restrict__ cur_e,
    float* __restrict__ inv_e,
    const int* __restrict__ cnt_v, int* __restrict__ off_v, int* __restrict__ cur_v,
    float* __restrict__ inv_v)
{
    const int* cnt; int* off; int* cur; float* inv; int n;
    if (blockIdx.x == 0) { cnt = cnt_e; off = off_e; cur = cur_e; inv = inv_e; n = N_EDGES; }
    else                 { cnt = cnt_v; off = off_v; cur = cur_v; inv = inv_v; n = N_NODES; }
    __shared__ int wsum[16];
    __shared__ int carry_s;
    int tid = threadIdx.x, lane = tid & 63, wid = tid >> 6;
    if (tid == 0) carry_s = 0;
    __syncthreads();
    for (int base = 0; base < n; base += 4096) {
        int i4 = base + tid * 4;
        int4 x = make_int4(0, 0, 0, 0);
        if (i4 + 3 < n) x = *(const int4*)(cnt + i4);
        else if (i4 < n) {
            x.x = cnt[i4];
            if (i4 + 1 < n) x.y = cnt[i4 + 1];
            if (i4 + 2 < n) x.z = cnt[i4 + 2];
        }
        int s0 = x.x, s1 = s0 + x.y, s2 = s1 + x.z, s3 = s2 + x.w;
        int incl = s3;
#pragma unroll
        for (int o = 1; o < 64; o <<= 1) { int t = __shfl_up(incl, o, 64); if (lane >= o) incl += t; }
        if (lane == 63) wsum[wid] = incl;
        __syncthreads();
        if (wid == 0) {
            int v = (lane < 16) ? wsum[lane] : 0;
#pragma unroll
            for (int o = 1; o < 16; o <<= 1) { int t = __shfl_up(v, o, 64); if (lane >= o) v += t; }
            if (lane < 16) wsum[lane] = v;
        }
        __syncthreads();
        int wpre = (wid == 0) ? 0 : wsum[wid - 1];
        int carry = carry_s;
        int excl = carry + wpre + incl - s3;
        if (i4 < n) {
            int e0 = excl, e1 = excl + s0, e2 = excl + s1, e3 = excl + s2;
            if (i4 + 3 < n) {
                *(int4*)(off + i4) = make_int4(e0, e1, e2, e3);
                *(int4*)(cur + i4) = make_int4(e0, e1, e2, e3);
            } else {
                off[i4] = e0; cur[i4] = e0;
                if (i4 + 1 < n) { off[i4 + 1] = e1; cur[i4 + 1] = e1; }
                if (i4 + 2 < n) { off[i4 + 2] = e2; cur[i4 + 2] = e2; }
            }
            inv[i4] = 1.0f / fmaxf((float)x.x, 1.0f);
            if (i4 + 1 < n) inv[i4 + 1] = 1.0f / fmaxf((float)x.y, 1.0f);
            if (i4 + 2 < n) inv[i4 + 2] = 1.0f / fmaxf((float)x.z, 1.0f);
            if (i4 + 3 < n) inv[i4 + 3] = 1.0f / fmaxf((float)x.w, 1.0f);
        }
        __syncthreads();
        if (tid == 1023) carry_s = carry + wpre + incl;
        __syncthreads();
    }
    if (tid == 0) off[n] = carry_s;
}

// ---- partitioned CSR fill: cur holds absolute positions (off copy) ----
__global__ __launch_bounds__(256) void fill8(
    const int* __restrict__ node_idx, const int* __restrict__ edge_idx,
    int* __restrict__ cur_e, int* __restrict__ cur_v,
    int* __restrict__ csr_e_nodes, int* __restrict__ csr_v_edges)
{
    int part = blockIdx.x & 7, blk = blockIdx.x >> 3, nblk = gridDim.x >> 3;
    int elo = part * (N_EDGES / 8), ehi = elo + N_EDGES / 8;
    int vlo = part * (N_NODES / 8), vhi = vlo + N_NODES / 8;
    for (int i = blk * 256 + threadIdx.x; i < NNZ_CT; i += nblk * 256) {
        int e = edge_idx[i], v = node_idx[i];
        if (e >= elo && e < ehi) {
            int p0 = atomicAdd(&cur_e[e], 1);
            csr_e_nodes[p0] = v;
        }
        if (v >= vlo && v < vhi) {
            int p1 = atomicAdd(&cur_v[v], 1);
            csr_v_edges[p1] = e;
        }
    }
}

// ---- V->E mean (256-dim) -> fragment-tiled bf16; block = one e16 tile ----
__global__ __launch_bounds__(256) void agg_e256_tiled(
    const unsigned short* __restrict__ src, unsigned short* __restrict__ Et,
    const int* __restrict__ offs, const int* __restrict__ lists,
    const float* __restrict__ invdeg)
{
    __shared__ unsigned short hbuf[16 * 264];
    int tid = threadIdx.x, lane = tid & 63, wid = tid >> 6;
    int e16 = blockIdx.x;
#pragma unroll
    for (int q = 0; q < 4; ++q) {
        int el = wid * 4 + q;
        int w = e16 * 16 + el;
        int s = offs[w], e = offs[w + 1];
        float a0 = 0.f, a1 = 0.f, a2 = 0.f, a3 = 0.f;
        for (int j = s; j < e; j += 8) {
            int r[8]; float m[8];
            r[0] = lists[j]; m[0] = 1.f;
#pragma unroll
            for (int u = 1; u < 8; ++u) {
                bool ok = (j + u) < e;
                r[u] = ok ? lists[j + u] : r[0];
                m[u] = ok ? 1.f : 0.f;
            }
            ushort4v v[8];
#pragma unroll
            for (int u = 0; u < 8; ++u)
                v[u] = *(const ushort4v*)(src + (size_t)r[u] * 256 + lane * 4);
            a0 += bf16_to_f(v[0][0]); a1 += bf16_to_f(v[0][1]);
            a2 += bf16_to_f(v[0][2]); a3 += bf16_to_f(v[0][3]);
#pragma unroll
            for (int u = 1; u < 8; ++u) {
                a0 = fmaf(m[u], bf16_to_f(v[u][0]), a0);
                a1 = fmaf(m[u], bf16_to_f(v[u][1]), a1);
                a2 = fmaf(m[u], bf16_to_f(v[u][2]), a2);
                a3 = fmaf(m[u], bf16_to_f(v[u][3]), a3);
            }
        }
        float sc = invdeg[w];
        ushort4v o;
        o[0] = bf16_rne(a0 * sc); o[1] = bf16_rne(a1 * sc);
        o[2] = bf16_rne(a2 * sc); o[3] = bf16_rne(a3 * sc);
        *(ushort4v*)&hbuf[el * 264 + lane * 4] = o;
    }
    __syncthreads();
#pragma unroll
    for (int u = 0; u < 2; ++u) {
        int sl = tid * 2 + u;
        int k32 = sl >> 6, lt = sl & 63;
        int row = lt & 15, hi = lt >> 4;
        int k0 = k32 * 32 + hi * 8;
        ushort8v v = *(const ushort8v*)&hbuf[row * 264 + k0];
        *(ushort8v*)(Et + (((size_t)e16 * 8 + k32) << 9) + lt * 8) = v;
    }
}

// ---- E->V mean + bias + relu -> row-major bf16; wave per node ----
__global__ __launch_bounds__(256) void agg_v256_row(
    const unsigned short* __restrict__ src, unsigned short* __restrict__ Vb,
    const int* __restrict__ offs, const int* __restrict__ lists,
    const float* __restrict__ invdeg, const float* __restrict__ bias, int nseg)
{
    int w = (blockIdx.x * 256 + threadIdx.x) >> 6;
    int lane = threadIdx.x & 63;
    if (w >= nseg) return;
    int s = offs[w], e = offs[w + 1];
    float a0 = 0.f, a1 = 0.f, a2 = 0.f, a3 = 0.f;
    for (int j = s; j < e; j += 4) {
        int r[4]; float m[4];
        r[0] = lists[j]; m[0] = 1.f;
#pragma unroll
        for (int u = 1; u < 4; ++u) {
            bool ok = (j + u) < e;
            r[u] = ok ? lists[j + u] : r[0];
            m[u] = ok ? 1.f : 0.f;
        }
        ushort4v v[4];
#pragma unroll
        for (int u = 0; u < 4; ++u)
            v[u] = *(const ushort4v*)(src + (size_t)r[u] * 256 + lane * 4);
        a0 += bf16_to_f(v[0][0]); a1 += bf16_to_f(v[0][1]);
        a2 += bf16_to_f(v[0][2]); a3 += bf16_to_f(v[0][3]);
#pragma unroll
        for (int u = 1; u < 4; ++u) {
            a0 = fmaf(m[u], bf16_to_f(v[u][0]), a0);
            a1 = fmaf(m[u], bf16_to_f(v[u][1]), a1);
            a2 = fmaf(m[u], bf16_to_f(v[u][2]), a2);
            a3 = fmaf(m[u], bf16_to_f(v[u][3]), a3);
        }
    }
    float sc = invdeg[w];
    const float4 b = *(const float4*)(bias + lane * 4);
    ushort4v o;
    o[0] = bf16_rne(fmaxf(a0 * sc + b.x, 0.f));
    o[1] = bf16_rne(fmaxf(a1 * sc + b.y, 0.f));
    o[2] = bf16_rne(fmaxf(a2 * sc + b.z, 0.f));
    o[3] = bf16_rne(fmaxf(a3 * sc + b.w, 0.f));
    *(ushort4v*)(Vb + (size_t)w * 256 + lane * 4) = o;
}

// ---- E->V mean + bias + relu -> fragment-tiled bf16; block = one m16 tile ----
__global__ __launch_bounds__(256) void agg_v256_blk(
    const unsigned short* __restrict__ src, unsigned short* __restrict__ At,
    const int* __restrict__ offs, const int* __restrict__ lists,
    const float* __restrict__ invdeg, const float* __restrict__ bias)
{
    __shared__ unsigned short hbuf[16 * 264];
    int tid = threadIdx.x, lane = tid & 63, wid = tid >> 6;
    int m16 = blockIdx.x;
    const float4 b = *(const float4*)(bias + lane * 4);
#pragma unroll
    for (int q = 0; q < 4; ++q) {
        int nl = wid * 4 + q;
        int w = m16 * 16 + nl;
        int s = offs[w], e = offs[w + 1];
        float a0 = 0.f, a1 = 0.f, a2 = 0.f, a3 = 0.f;
        for (int j = s; j < e; j += 4) {
            int r[4]; float m[4];
            r[0] = lists[j]; m[0] = 1.f;
#pragma unroll
            for (int u = 1; u < 4; ++u) {
                bool ok = (j + u) < e;
                r[u] = ok ? lists[j + u] : r[0];
                m[u] = ok ? 1.f : 0.f;
            }
            ushort4v v[4];
#pragma unroll
            for (int u = 0; u < 4; ++u)
                v[u] = *(const ushort4v*)(src + (size_t)r[u] * 256 + lane * 4);
            a0 += bf16_to_f(v[0][0]); a1 += bf16_to_f(v[0][1]);
            a2 += bf16_to_f(v[0][2]); a3 += bf16_to_f(v[0][3]);
#pragma unroll
            for (int u = 1; u < 4; ++u) {
                a0 = fmaf(m[u], bf16_to_f(v[u][0]), a0);
                a1 = fmaf(m[u], bf16_to_f(v[u][1]), a1);
                a2 = fmaf(m[u], bf16_to_f(v[u][2]), a2);
                a3 = fmaf(m[u], bf16_to_f(v[u][3]), a3);
            }
        }
        float sc = invdeg[w];
        ushort4v o;
        o[0] = bf16_rne(fmaxf(a0 * sc + b.x, 0.f));
        o[1] = bf16_rne(fmaxf(a1 * sc + b.y, 0.f));
        o[2] = bf16_rne(fmaxf(a2 * sc + b.z, 0.f));
        o[3] = bf16_rne(fmaxf(a3 * sc + b.w, 0.f));
        *(ushort4v*)&hbuf[nl * 264 + lane * 4] = o;
    }
    __syncthreads();
#pragma unroll
    for (int u = 0; u < 2; ++u) {
        int sl = tid * 2 + u;
        int k32 = sl >> 6, lt = sl & 63;
        int row = lt & 15, hi = lt >> 4;
        int k0 = k32 * 32 + hi * 8;
        ushort8v v = *(const ushort8v*)&hbuf[row * 264 + k0];
        *(ushort8v*)(At + (((size_t)m16 * 8 + k32) << 9) + lt * 8) = v;
    }
}

// ---- mean-aggregation, F=40 (edges), bf16 in, bf16 out, 8 in flight ----
__global__ __launch_bounds__(256) void agg_mean40(
    const unsigned short* __restrict__ src, unsigned short* __restrict__ dst,
    const int* __restrict__ offs, const int* __restrict__ lists,
    const float* __restrict__ invdeg, int nseg)
{
    int w = (blockIdx.x * 256 + threadIdx.x) >> 6;
    int lane = threadIdx.x & 63;
    if (w >= nseg) return;
    int s = offs[w], e = offs[w + 1];
    if (lane < 40) {
        float acc = 0.f;
        for (int j = s; j < e; j += 8) {
            int r[8]; float m[8];
            r[0] = lists[j]; m[0] = 1.f;
#pragma unroll
            for (int u = 1; u < 8; ++u) {
                bool ok = (j + u) < e;
                r[u] = ok ? lists[j + u] : r[0];
                m[u] = ok ? 1.f : 0.f;
            }
            float v[8];
#pragma unroll
            for (int u = 0; u < 8; ++u)
                v[u] = bf16_to_f(src[(size_t)r[u] * 40 + lane]);
            acc += v[0];
#pragma unroll
            for (int u = 1; u < 8; ++u) acc = fmaf(m[u], v[u], acc);
        }
        dst[(size_t)w * 40 + lane] = bf16_rne(acc * invdeg[w]);
    }
}

// ------- final E->V mean at F=40 + bias + log_softmax, wave per node -------
__global__ __launch_bounds__(256) void agg_v40_lsm(
    const unsigned short* __restrict__ efeat, float* __restrict__ out,
    const int* __restrict__ offs, const int* __restrict__ lists,
    const float* __restrict__ invdeg, const float* __restrict__ bias,
    int nseg)
{
    int w = (blockIdx.x * 256 + threadIdx.x) >> 6;
    int lane = threadIdx.x & 63;
    if (w >= nseg) return;
    int s = offs[w], e = offs[w + 1];
    float acc = 0.f;
    if (lane < 40) {
        for (int j = s; j < e; j += 4) {
            int r[4]; float m[4];
            r[0] = lists[j]; m[0] = 1.f;
#pragma unroll
            for (int u = 1; u < 4; ++u) {
                bool ok = (j + u) < e;
                r[u] = ok ? lists[j + u] : r[0];
                m[u] = ok ? 1.f : 0.f;
            }
            float v[4];
#pragma unroll
            for (int u = 0; u < 4; ++u)
                v[u] = bf16_to_f(efeat[(size_t)r[u] * 40 + lane]);
            acc += v[0];
#pragma unroll
            for (int u = 1; u < 4; ++u) acc = fmaf(m[u], v[u], acc);
        }
    }
    float val = (lane < 40) ? (acc * invdeg[w] + bias[lane]) : -1e30f;
    float m = val;
#pragma unroll
    for (int o = 32; o; o >>= 1) m = fmaxf(m, __shfl_xor(m, o));
    float ex = (lane < 40) ? expf(val - m) : 0.f;
    float ssum = ex;
#pragma unroll
    for (int o = 32; o; o >>= 1) ssum += __shfl_xor(ssum, o);
    if (lane < 40) out[(size_t)w * 40 + lane] = val - m - logf(ssum);
}

// ---------------- launch ----------------
extern "C" void kernel_launch(void* const* d_in, const int* in_sizes, int n_in,
                              void* d_out, int out_size, void* d_ws, size_t ws_size,
                              hipStream_t stream)
{
    const float* X        = (const float*)d_in[0];
    const int*   node_idx = (const int*)d_in[1];
    const int*   edge_idx = (const int*)d_in[2];
    const float* W1 = (const float*)d_in[3];
    const float* b1 = (const float*)d_in[4];
    const float* W2 = (const float*)d_in[5];
    const float* b2 = (const float*)d_in[6];
    const float* W3 = (const float*)d_in[7];
    const float* b3 = (const float*)d_in[8];
    float* out = (float*)d_out;

    char* p = (char*)d_ws;
    auto alloc = [&](size_t bytes) -> char* {
        char* r = p;
        p += (bytes + 255) & ~(size_t)255;
        return r;
    };
    int*   cnt_e = (int*)alloc((size_t)N_EDGES * 4);
    int*   cnt_v = (int*)alloc((size_t)N_NODES * 4);
    int*   cur_e = (int*)alloc((size_t)N_EDGES * 4);
    int*   cur_v = (int*)alloc((size_t)N_NODES * 4);
    int*   off_e = (int*)alloc((size_t)(N_EDGES + 1) * 4);
    int*   off_v = (int*)alloc((size_t)(N_NODES + 1) * 4);
    float* inv_e = (float*)alloc((size_t)N_EDGES * 4);
    float* inv_v = (float*)alloc((size_t)N_NODES * 4);
    int*   csr_e = (int*)alloc((size_t)NNZ_CT * 4);
    int*   csr_v = (int*)alloc((size_t)NNZ_CT * 4);

    const int M16 = N_NODES / 16;              // 3125
    const int M16_PAD = 391 * 8;               // 3128 (GEMM-V grid coverage)
    const int E16 = N_EDGES / 16;              // 1250
    const int E16_PAD = 157 * 8;               // 1256 (GEMM-E grid coverage)
    unsigned short* Xb  = (unsigned short*)alloc((size_t)N_NODES * 256 * 2);   // row-major V activations
    unsigned short* At  = (unsigned short*)alloc((size_t)M16_PAD * 4096 * 2);  // tiled V acts (L3 GEMM in)
    unsigned short* Et  = (unsigned short*)alloc((size_t)E16_PAD * 4096 * 2);  // tiled E aggregates
    unsigned short* Ef  = (unsigned short*)alloc((size_t)N_EDGES * 256 * 2);   // row-major E features
    unsigned short* W1h = (unsigned short*)alloc((size_t)16 * 4096 * 2);
    unsigned short* W1l = (unsigned short*)alloc((size_t)16 * 4096 * 2);
    unsigned short* W2h = (unsigned short*)alloc((size_t)16 * 4096 * 2);
    unsigned short* W2l = (unsigned short*)alloc((size_t)16 * 4096 * 2);
    unsigned short* W3h = (unsigned short*)alloc((size_t)8 * 4096 * 2);
    unsigned short* W3l = (unsigned short*)alloc((size_t)8 * 4096 * 2);
    unsigned short* C40 = (unsigned short*)alloc((size_t)N_NODES * 40 * 2);
    unsigned short* E40 = (unsigned short*)alloc((size_t)N_EDGES * 40 * 2);

    // zero only the count arrays
    size_t zspan = (size_t)((char*)cnt_v + (size_t)N_NODES * 4 - (char*)cnt_e);
    hipMemsetAsync(cnt_e, 0, zspan, stream);

    count8<<<4096, 256, 0, stream>>>(node_idx, edge_idx, cnt_e, cnt_v);
    scan_dual<<<2, 1024, 0, stream>>>(cnt_e, off_e, cur_e, inv_e, cnt_v, off_v, cur_v, inv_v);
    fill8<<<4096, 256, 0, stream>>>(node_idx, edge_idx, cur_e, cur_v, csr_e, csr_v);

    convert_X_row<<<(N_NODES * 256 / 8 + 255) / 256, 256, 0, stream>>>(X, Xb, N_NODES * 256 / 8);
    convert_B_tiled<<<(16 * 512 + 255) / 256, 256, 0, stream>>>(W1, W1h, W1l, 256, 16);
    convert_B_tiled<<<(16 * 512 + 255) / 256, 256, 0, stream>>>(W2, W2h, W2l, 256, 16);
    convert_B_tiled<<<(8 * 512 + 255) / 256, 256, 0, stream>>>(W3, W3h, W3l, 40, 8);

    dim3 gE_gemm(2, 157);    // GEMM on 20000 edge rows
    dim3 gV_gemm(1, 391);    // GEMM on 50000 node rows (layer 3, 40 cols)
    const int gEw = (N_EDGES + 3) / 4;
    const int gVw = (N_NODES + 3) / 4;

    // layer 1: V->E agg first (commutes with GEMM), GEMM on edges, E->V to row-major
    agg_e256_tiled<<<E16, 256, 0, stream>>>(Xb, Et, off_e, csr_e, inv_e);
    gemm_bf16<<<gE_gemm, 256, 0, stream>>>(Et, W1h, W1l, Ef, N_EDGES, 256, 256);
    agg_v256_row<<<gVw, 256, 0, stream>>>(Ef, Xb, off_v, csr_v, inv_v, b1, N_NODES);

    // layer 2: same; E->V writes tiled (feeds layer-3 GEMM-V)
    agg_e256_tiled<<<E16, 256, 0, stream>>>(Xb, Et, off_e, csr_e, inv_e);
    gemm_bf16<<<gE_gemm, 256, 0, stream>>>(Et, W2h, W2l, Ef, N_EDGES, 256, 256);
    agg_v256_blk<<<M16, 256, 0, stream>>>(Ef, At, off_v, csr_v, inv_v, b2);

    // layer 3: GEMM-V to 40 cols, then 40-dim aggs + log_softmax
    gemm_bf16<<<gV_gemm, 256, 0, stream>>>(At, W3h, W3l, C40, N_NODES, 40, 40);
    agg_mean40<<<gEw, 256, 0, stream>>>(C40, E40, off_e, csr_e, inv_e, N_EDGES);
    agg_v40_lsm<<<gVw, 256, 0, stream>>>(E40, out, off_v, csr_v, inv_v, b3, N_NODES);
    (void)in_sizes; (void)n_in; (void)out_size; (void)ws_size;
}

// Round 7
// 364.585 us; speedup vs baseline: 2.3569x; 1.0727x over previous
//
#include <hip/hip_runtime.h>
#include <math.h>

#define N_NODES 50000
#define N_EDGES 20000
#define NNZ_CT  500000
#define KDIM    256
#define K32     8

typedef __attribute__((ext_vector_type(8))) short    short8v;
typedef __attribute__((ext_vector_type(4))) float    f32x4;
typedef __attribute__((ext_vector_type(8))) unsigned short ushort8v;
typedef __attribute__((ext_vector_type(4))) unsigned short ushort4v;

#define GLD16(g, l) __builtin_amdgcn_global_load_lds( \
    (const __attribute__((address_space(1))) unsigned int*)(g), \
    (__attribute__((address_space(3))) unsigned int*)(l), 16, 0, 0)

__device__ __forceinline__ unsigned short bf16_rne(float f) {
    unsigned u = __float_as_uint(f);
    return (unsigned short)((u + 0x7FFFu + ((u >> 16) & 1u)) >> 16);
}
__device__ __forceinline__ float bf16_to_f(unsigned short h) {
    return __uint_as_float(((unsigned)h) << 16);
}
__device__ __forceinline__ void bf16_split(float f, unsigned short& h, unsigned short& l) {
    unsigned u = __float_as_uint(f);
    unsigned hb = (u + 0x7FFFu + ((u >> 16) & 1u)) >> 16;
    h = (unsigned short)hb;
    float r = f - __uint_as_float(hb << 16);
    unsigned ru = __float_as_uint(r);
    l = (unsigned short)((ru + 0x7FFFu + ((ru >> 16) & 1u)) >> 16);
}

// ==== K1: fused {convert X -> bf16 row-major} + {rank-assign atomics} ====
// blocks [0, 6250): convert;  blocks [6250, 6250+2048): rank-assign
#define NB_CONVX 6250
__global__ __launch_bounds__(256) void rank_convX(
    const float* __restrict__ X, unsigned short* __restrict__ Xb,
    const int* __restrict__ node_idx, const int* __restrict__ edge_idx,
    int* __restrict__ cnt_e, int* __restrict__ cnt_v,
    int* __restrict__ rank_e, int* __restrict__ rank_v)
{
    if (blockIdx.x < NB_CONVX) {
        int t = blockIdx.x * 256 + threadIdx.x;    // < 1.6M exact
        const float* src = X + (size_t)t * 8;
        float f[8];
        *(float4*)(f)     = *(const float4*)(src);
        *(float4*)(f + 4) = *(const float4*)(src + 4);
        ushort8v h;
#pragma unroll
        for (int j = 0; j < 8; j++) h[j] = bf16_rne(f[j]);
        *(ushort8v*)(Xb + (size_t)t * 8) = h;
    } else {
        int i = (blockIdx.x - NB_CONVX) * 256 + threadIdx.x;
        if (i < NNZ_CT) {
            int e = edge_idx[i], v = node_idx[i];
            rank_e[i] = atomicAdd(&cnt_e[e], 1);
            rank_v[i] = atomicAdd(&cnt_v[v], 1);
        }
    }
}

// ---- device body: fp32 B[K,Ncols] -> fragment-tiled bf16 hi/lo ----
__device__ __forceinline__ void conv_B_body(
    const float* __restrict__ B, unsigned short* __restrict__ Bh,
    unsigned short* __restrict__ Bl, int Ncols, int n16_count, int t)
{
    if (t >= n16_count * 512) return;
    int lane = t & 63, k32 = (t >> 6) & 7, n16 = t >> 9;
    int col = n16 * 16 + (lane & 15);
    int k0  = k32 * 32 + (lane >> 4) * 8;
    ushort8v h, l;
#pragma unroll
    for (int j = 0; j < 8; j++) {
        float f = (col < Ncols) ? B[(size_t)(k0 + j) * Ncols + col] : 0.f;
        unsigned short hh, ll; bf16_split(f, hh, ll); h[j] = hh; l[j] = ll;
    }
    size_t off = (((size_t)n16 * 8 + k32) << 9) + lane * 8;
    *(ushort8v*)(Bh + off) = h;
    *(ushort8v*)(Bl + off) = l;
}

// ==== K2: fused {dual scans (blocks 0,1)} + {convert W1/W2/W3 (blocks 2..21)} ====
__global__ __launch_bounds__(1024) void scan_convW(
    const int* __restrict__ cnt_e, int* __restrict__ off_e, float* __restrict__ inv_e,
    const int* __restrict__ cnt_v, int* __restrict__ off_v, float* __restrict__ inv_v,
    const float* __restrict__ W1, unsigned short* __restrict__ W1h, unsigned short* __restrict__ W1l,
    const float* __restrict__ W2, unsigned short* __restrict__ W2h, unsigned short* __restrict__ W2l,
    const float* __restrict__ W3, unsigned short* __restrict__ W3h, unsigned short* __restrict__ W3l)
{
    int b = blockIdx.x;
    if (b >= 2) {
        if (b < 10)      conv_B_body(W1, W1h, W1l, 256, 16, (b - 2)  * 1024 + (int)threadIdx.x);
        else if (b < 18) conv_B_body(W2, W2h, W2l, 256, 16, (b - 10) * 1024 + (int)threadIdx.x);
        else             conv_B_body(W3, W3h, W3l, 40,  8,  (b - 18) * 1024 + (int)threadIdx.x);
        return;
    }
    const int* cnt; int* off; float* inv; int n;
    if (b == 0) { cnt = cnt_e; off = off_e; inv = inv_e; n = N_EDGES; }
    else        { cnt = cnt_v; off = off_v; inv = inv_v; n = N_NODES; }
    __shared__ int wsum[16];
    __shared__ int carry_s;
    int tid = threadIdx.x, lane = tid & 63, wid = tid >> 6;
    if (tid == 0) carry_s = 0;
    __syncthreads();
    for (int base = 0; base < n; base += 4096) {
        int i4 = base + tid * 4;
        int4 x = make_int4(0, 0, 0, 0);
        if (i4 + 3 < n) x = *(const int4*)(cnt + i4);
        else if (i4 < n) {
            x.x = cnt[i4];
            if (i4 + 1 < n) x.y = cnt[i4 + 1];
            if (i4 + 2 < n) x.z = cnt[i4 + 2];
        }
        int s0 = x.x, s1 = s0 + x.y, s2 = s1 + x.z, s3 = s2 + x.w;
        int incl = s3;
#pragma unroll
        for (int o = 1; o < 64; o <<= 1) { int t = __shfl_up(incl, o, 64); if (lane >= o) incl += t; }
        if (lane == 63) wsum[wid] = incl;
        __syncthreads();
        if (wid == 0) {
            int v = (lane < 16) ? wsum[lane] : 0;
#pragma unroll
            for (int o = 1; o < 16; o <<= 1) { int t = __shfl_up(v, o, 64); if (lane >= o) v += t; }
            if (lane < 16) wsum[lane] = v;
        }
        __syncthreads();
        int wpre = (wid == 0) ? 0 : wsum[wid - 1];
        int carry = carry_s;
        int excl = carry + wpre + incl - s3;
        if (i4 < n) {
            int e0 = excl, e1 = excl + s0, e2 = excl + s1, e3 = excl + s2;
            if (i4 + 3 < n) { *(int4*)(off + i4) = make_int4(e0, e1, e2, e3); }
            else {
                off[i4] = e0;
                if (i4 + 1 < n) off[i4 + 1] = e1;
                if (i4 + 2 < n) off[i4 + 2] = e2;
            }
            inv[i4] = 1.0f / fmaxf((float)x.x, 1.0f);
            if (i4 + 1 < n) inv[i4 + 1] = 1.0f / fmaxf((float)x.y, 1.0f);
            if (i4 + 2 < n) inv[i4 + 2] = 1.0f / fmaxf((float)x.z, 1.0f);
            if (i4 + 3 < n) inv[i4 + 3] = 1.0f / fmaxf((float)x.w, 1.0f);
        }
        __syncthreads();
        if (tid == 1023) carry_s = carry + wpre + incl;
        __syncthreads();
    }
    if (tid == 0) off[n] = carry_s;
}

// ==== K3: atomic-free CSR fill using precomputed ranks ====
__global__ __launch_bounds__(256) void fill_ranked(
    const int* __restrict__ node_idx, const int* __restrict__ edge_idx,
    const int* __restrict__ rank_e, const int* __restrict__ rank_v,
    const int* __restrict__ off_e, const int* __restrict__ off_v,
    int* __restrict__ csr_e_nodes, int* __restrict__ csr_v_edges)
{
    int i = blockIdx.x * 256 + threadIdx.x;
    if (i >= NNZ_CT) return;
    int e = edge_idx[i], v = node_idx[i];
    csr_e_nodes[off_e[e] + rank_e[i]] = v;
    csr_v_edges[off_v[v] + rank_v[i]] = e;
}

// ---- MFMA GEMM: A tiled bf16, B tiled split hi/lo; C bf16 row-major ----
__global__ __launch_bounds__(256) void gemm_bf16(
    const unsigned short* __restrict__ At,
    const unsigned short* __restrict__ Bh, const unsigned short* __restrict__ Bl,
    unsigned short* __restrict__ C, int M, int Ncols, int ldC)
{
    __shared__ unsigned short lds[16384];
    const int tid  = threadIdx.x;
    const int lane = tid & 63, wid = tid >> 6;
    const int wr = wid >> 1, wc = wid & 1;
    const int m0t = blockIdx.y * 8;
    const int n0t = blockIdx.x * 8;

    f32x4 acc[4][4] = {};

    for (int k32 = 0; k32 < K32; ++k32) {
#pragma unroll
        for (int i = 0; i < 6; ++i) {
            int c = i * 4 + wid;               // 0..23
            if (c < 8) {
                const unsigned short* gA = At + (((size_t)(m0t + c) * 8 + k32) << 9) + lane * 8;
                GLD16(gA, &lds[c * 512 + lane * 8]);
            } else {
                int idx = c - 8, half = idx >> 3, st = idx & 7;
                const unsigned short* gB = (half ? Bl : Bh)
                    + (((size_t)(n0t + st) * 8 + k32) << 9) + lane * 8;
                GLD16(gB, &lds[4096 + idx * 512 + lane * 8]);
            }
        }
        __syncthreads();
        short8v a[4], bh[4], bl[4];
#pragma unroll
        for (int x = 0; x < 4; ++x) {
            a[x]  = *(const short8v*)&lds[(wr * 4 + x) * 512 + lane * 8];
            bh[x] = *(const short8v*)&lds[4096 + (wc * 4 + x) * 512 + lane * 8];
            bl[x] = *(const short8v*)&lds[4096 + (8 + wc * 4 + x) * 512 + lane * 8];
        }
#pragma unroll
        for (int mi = 0; mi < 4; ++mi)
#pragma unroll
            for (int ni = 0; ni < 4; ++ni) {
                acc[mi][ni] = __builtin_amdgcn_mfma_f32_16x16x32_bf16(a[mi], bh[ni], acc[mi][ni], 0, 0, 0);
                acc[mi][ni] = __builtin_amdgcn_mfma_f32_16x16x32_bf16(a[mi], bl[ni], acc[mi][ni], 0, 0, 0);
            }
        __syncthreads();
    }

    {
        const int rg = lane >> 4, cl = lane & 15;
        const int base = wid * 4096;
#pragma unroll
        for (int mi = 0; mi < 4; ++mi) {
            int swz = ((mi * 4 + rg) & 3) << 4;
#pragma unroll
            for (int ni = 0; ni < 4; ++ni) {
                int colf = (ni * 16 + cl) ^ swz;
#pragma unroll
                for (int r = 0; r < 4; ++r)
                    lds[base + (mi * 16 + rg * 4 + r) * 64 + colf] = bf16_rne(acc[mi][ni][r]);
            }
        }
    }
    __syncthreads();
    {
        int row = tid >> 1, half = tid & 1;
        int grow = blockIdx.y * 128 + row;
        if (grow < M) {
            int wsrc = (row >> 6) * 2 + half;
            int rl = row & 63;
            int swz = ((rl >> 2) & 3) << 4;
            unsigned short* dst = C + (size_t)grow * ldC + n0t * 16 + half * 64;
#pragma unroll
            for (int s = 0; s < 8; ++s) {
                int c0 = half * 64 + s * 8;
                if (n0t * 16 + c0 + 8 <= Ncols) {
                    ushort8v v = *(const ushort8v*)&lds[wsrc * 4096 + rl * 64 + ((s * 8) ^ swz)];
                    *(ushort8v*)(dst + s * 8) = v;
                }
            }
        }
    }
}

// ---- V->E mean (256-dim) -> fragment-tiled bf16; block = one e16 tile ----
__global__ __launch_bounds__(256) void agg_e256_tiled(
    const unsigned short* __restrict__ src, unsigned short* __restrict__ Et,
    const int* __restrict__ offs, const int* __restrict__ lists,
    const float* __restrict__ invdeg)
{
    __shared__ unsigned short hbuf[16 * 264];
    int tid = threadIdx.x, lane = tid & 63, wid = tid >> 6;
    int e16 = blockIdx.x;
#pragma unroll
    for (int q = 0; q < 4; ++q) {
        int el = wid * 4 + q;
        int w = e16 * 16 + el;
        int s = offs[w], e = offs[w + 1];
        float a0 = 0.f, a1 = 0.f, a2 = 0.f, a3 = 0.f;
        for (int j = s; j < e; j += 8) {
            int r[8]; float m[8];
            r[0] = lists[j]; m[0] = 1.f;
#pragma unroll
            for (int u = 1; u < 8; ++u) {
                bool ok = (j + u) < e;
                r[u] = ok ? lists[j + u] : r[0];
                m[u] = ok ? 1.f : 0.f;
            }
            ushort4v v[8];
#pragma unroll
            for (int u = 0; u < 8; ++u)
                v[u] = *(const ushort4v*)(src + (size_t)r[u] * 256 + lane * 4);
            a0 += bf16_to_f(v[0][0]); a1 += bf16_to_f(v[0][1]);
            a2 += bf16_to_f(v[0][2]); a3 += bf16_to_f(v[0][3]);
#pragma unroll
            for (int u = 1; u < 8; ++u) {
                a0 = fmaf(m[u], bf16_to_f(v[u][0]), a0);
                a1 = fmaf(m[u], bf16_to_f(v[u][1]), a1);
                a2 = fmaf(m[u], bf16_to_f(v[u][2]), a2);
                a3 = fmaf(m[u], bf16_to_f(v[u][3]), a3);
            }
        }
        float sc = invdeg[w];
        ushort4v o;
        o[0] = bf16_rne(a0 * sc); o[1] = bf16_rne(a1 * sc);
        o[2] = bf16_rne(a2 * sc); o[3] = bf16_rne(a3 * sc);
        *(ushort4v*)&hbuf[el * 264 + lane * 4] = o;
    }
    __syncthreads();
#pragma unroll
    for (int u = 0; u < 2; ++u) {
        int sl = tid * 2 + u;
        int k32 = sl >> 6, lt = sl & 63;
        int row = lt & 15, hi = lt >> 4;
        int k0 = k32 * 32 + hi * 8;
        ushort8v v = *(const ushort8v*)&hbuf[row * 264 + k0];
        *(ushort8v*)(Et + (((size_t)e16 * 8 + k32) << 9) + lt * 8) = v;
    }
}

// ---- E->V mean + bias + relu -> row-major bf16; wave per node ----
__global__ __launch_bounds__(256) void agg_v256_row(
    const unsigned short* __restrict__ src, unsigned short* __restrict__ Vb,
    const int* __restrict__ offs, const int* __restrict__ lists,
    const float* __restrict__ invdeg, const float* __restrict__ bias, int nseg)
{
    int w = (blockIdx.x * 256 + threadIdx.x) >> 6;
    int lane = threadIdx.x & 63;
    if (w >= nseg) return;
    int s = offs[w], e = offs[w + 1];
    float a0 = 0.f, a1 = 0.f, a2 = 0.f, a3 = 0.f;
    for (int j = s; j < e; j += 4) {
        int r[4]; float m[4];
        r[0] = lists[j]; m[0] = 1.f;
#pragma unroll
        for (int u = 1; u < 4; ++u) {
            bool ok = (j + u) < e;
            r[u] = ok ? lists[j + u] : r[0];
            m[u] = ok ? 1.f : 0.f;
        }
        ushort4v v[4];
#pragma unroll
        for (int u = 0; u < 4; ++u)
            v[u] = *(const ushort4v*)(src + (size_t)r[u] * 256 + lane * 4);
        a0 += bf16_to_f(v[0][0]); a1 += bf16_to_f(v[0][1]);
        a2 += bf16_to_f(v[0][2]); a3 += bf16_to_f(v[0][3]);
#pragma unroll
        for (int u = 1; u < 4; ++u) {
            a0 = fmaf(m[u], bf16_to_f(v[u][0]), a0);
            a1 = fmaf(m[u], bf16_to_f(v[u][1]), a1);
            a2 = fmaf(m[u], bf16_to_f(v[u][2]), a2);
            a3 = fmaf(m[u], bf16_to_f(v[u][3]), a3);
        }
    }
    float sc = invdeg[w];
    const float4 b = *(const float4*)(bias + lane * 4);
    ushort4v o;
    o[0] = bf16_rne(fmaxf(a0 * sc + b.x, 0.f));
    o[1] = bf16_rne(fmaxf(a1 * sc + b.y, 0.f));
    o[2] = bf16_rne(fmaxf(a2 * sc + b.z, 0.f));
    o[3] = bf16_rne(fmaxf(a3 * sc + b.w, 0.f));
    *(ushort4v*)(Vb + (size_t)w * 256 + lane * 4) = o;
}

// ---- E->V mean + bias + relu -> fragment-tiled bf16; block = one m16 tile ----
__global__ __launch_bounds__(256) void agg_v256_blk(
    const unsigned short* __restrict__ src, unsigned short* __restrict__ At,
    const int* __restrict__ offs, const int* __restrict__ lists,
    const float* __restrict__ invdeg, const float* __restrict__ bias)
{
    __shared__ unsigned short hbuf[16 * 264];
    int tid = threadIdx.x, lane = tid & 63, wid = tid >> 6;
    int m16 = blockIdx.x;
    const float4 b = *(const float4*)(bias + lane * 4);
#pragma unroll
    for (int q = 0; q < 4; ++q) {
        int nl = wid * 4 + q;
        int w = m16 * 16 + nl;
        int s = offs[w], e = offs[w + 1];
        float a0 = 0.f, a1 = 0.f, a2 = 0.f, a3 = 0.f;
        for (int j = s; j < e; j += 4) {
            int r[4]; float m[4];
            r[0] = lists[j]; m[0] = 1.f;
#pragma unroll
            for (int u = 1; u < 4; ++u) {
                bool ok = (j + u) < e;
                r[u] = ok ? lists[j + u] : r[0];
                m[u] = ok ? 1.f : 0.f;
            }
            ushort4v v[4];
#pragma unroll
            for (int u = 0; u < 4; ++u)
                v[u] = *(const ushort4v*)(src + (size_t)r[u] * 256 + lane * 4);
            a0 += bf16_to_f(v[0][0]); a1 += bf16_to_f(v[0][1]);
            a2 += bf16_to_f(v[0][2]); a3 += bf16_to_f(v[0][3]);
#pragma unroll
            for (int u = 1; u < 4; ++u) {
                a0 = fmaf(m[u], bf16_to_f(v[u][0]), a0);
                a1 = fmaf(m[u], bf16_to_f(v[u][1]), a1);
                a2 = fmaf(m[u], bf16_to_f(v[u][2]), a2);
                a3 = fmaf(m[u], bf16_to_f(v[u][3]), a3);
            }
        }
        float sc = invdeg[w];
        ushort4v o;
        o[0] = bf16_rne(fmaxf(a0 * sc + b.x, 0.f));
        o[1] = bf16_rne(fmaxf(a1 * sc + b.y, 0.f));
        o[2] = bf16_rne(fmaxf(a2 * sc + b.z, 0.f));
        o[3] = bf16_rne(fmaxf(a3 * sc + b.w, 0.f));
        *(ushort4v*)&hbuf[nl * 264 + lane * 4] = o;
    }
    __syncthreads();
#pragma unroll
    for (int u = 0; u < 2; ++u) {
        int sl = tid * 2 + u;
        int k32 = sl >> 6, lt = sl & 63;
        int row = lt & 15, hi = lt >> 4;
        int k0 = k32 * 32 + hi * 8;
        ushort8v v = *(const ushort8v*)&hbuf[row * 264 + k0];
        *(ushort8v*)(At + (((size_t)m16 * 8 + k32) << 9) + lt * 8) = v;
    }
}

// ---- mean-aggregation, F=40 (edges), bf16 in, bf16 out, 8 in flight ----
__global__ __launch_bounds__(256) void agg_mean40(
    const unsigned short* __restrict__ src, unsigned short* __restrict__ dst,
    const int* __restrict__ offs, const int* __restrict__ lists,
    const float* __restrict__ invdeg, int nseg)
{
    int w = (blockIdx.x * 256 + threadIdx.x) >> 6;
    int lane = threadIdx.x & 63;
    if (w >= nseg) return;
    int s = offs[w], e = offs[w + 1];
    if (lane < 40) {
        float acc = 0.f;
        for (int j = s; j < e; j += 8) {
            int r[8]; float m[8];
            r[0] = lists[j]; m[0] = 1.f;
#pragma unroll
            for (int u = 1; u < 8; ++u) {
                bool ok = (j + u) < e;
                r[u] = ok ? lists[j + u] : r[0];
                m[u] = ok ? 1.f : 0.f;
            }
            float v[8];
#pragma unroll
            for (int u = 0; u < 8; ++u)
                v[u] = bf16_to_f(src[(size_t)r[u] * 40 + lane]);
            acc += v[0];
#pragma unroll
            for (int u = 1; u < 8; ++u) acc = fmaf(m[u], v[u], acc);
        }
        dst[(size_t)w * 40 + lane] = bf16_rne(acc * invdeg[w]);
    }
}

// ------- final E->V mean at F=40 + bias + log_softmax, wave per node -------
__global__ __launch_bounds__(256) void agg_v40_lsm(
    const unsigned short* __restrict__ efeat, float* __restrict__ out,
    const int* __restrict__ offs, const int* __restrict__ lists,
    const float* __restrict__ invdeg, const float* __restrict__ bias,
    int nseg)
{
    int w = (blockIdx.x * 256 + threadIdx.x) >> 6;
    int lane = threadIdx.x & 63;
    if (w >= nseg) return;
    int s = offs[w], e = offs[w + 1];
    float acc = 0.f;
    if (lane < 40) {
        for (int j = s; j < e; j += 4) {
            int r[4]; float m[4];
            r[0] = lists[j]; m[0] = 1.f;
#pragma unroll
            for (int u = 1; u < 4; ++u) {
                bool ok = (j + u) < e;
                r[u] = ok ? lists[j + u] : r[0];
                m[u] = ok ? 1.f : 0.f;
            }
            float v[4];
#pragma unroll
            for (int u = 0; u < 4; ++u)
                v[u] = bf16_to_f(efeat[(size_t)r[u] * 40 + lane]);
            acc += v[0];
#pragma unroll
            for (int u = 1; u < 4; ++u) acc = fmaf(m[u], v[u], acc);
        }
    }
    float val = (lane < 40) ? (acc * invdeg[w] + bias[lane]) : -1e30f;
    float m = val;
#pragma unroll
    for (int o = 32; o; o >>= 1) m = fmaxf(m, __shfl_xor(m, o));
    float ex = (lane < 40) ? expf(val - m) : 0.f;
    float ssum = ex;
#pragma unroll
    for (int o = 32; o; o >>= 1) ssum += __shfl_xor(ssum, o);
    if (lane < 40) out[(size_t)w * 40 + lane] = val - m - logf(ssum);
}

// ---------------- launch ----------------
extern "C" void kernel_launch(void* const* d_in, const int* in_sizes, int n_in,
                              void* d_out, int out_size, void* d_ws, size_t ws_size,
                              hipStream_t stream)
{
    const float* X        = (const float*)d_in[0];
    const int*   node_idx = (const int*)d_in[1];
    const int*   edge_idx = (const int*)d_in[2];
    const float* W1 = (const float*)d_in[3];
    const float* b1 = (const float*)d_in[4];
    const float* W2 = (const float*)d_in[5];
    const float* b2 = (const float*)d_in[6];
    const float* W3 = (const float*)d_in[7];
    const float* b3 = (const float*)d_in[8];
    float* out = (float*)d_out;

    char* p = (char*)d_ws;
    auto alloc = [&](size_t bytes) -> char* {
        char* r = p;
        p += (bytes + 255) & ~(size_t)255;
        return r;
    };
    int*   cnt_e = (int*)alloc((size_t)N_EDGES * 4);
    int*   cnt_v = (int*)alloc((size_t)N_NODES * 4);
    int*   off_e = (int*)alloc((size_t)(N_EDGES + 1) * 4);
    int*   off_v = (int*)alloc((size_t)(N_NODES + 1) * 4);
    float* inv_e = (float*)alloc((size_t)N_EDGES * 4);
    float* inv_v = (float*)alloc((size_t)N_NODES * 4);
    int*   rank_e = (int*)alloc((size_t)NNZ_CT * 4);
    int*   rank_v = (int*)alloc((size_t)NNZ_CT * 4);
    int*   csr_e = (int*)alloc((size_t)NNZ_CT * 4);
    int*   csr_v = (int*)alloc((size_t)NNZ_CT * 4);

    const int M16 = N_NODES / 16;              // 3125
    const int M16_PAD = 391 * 8;               // 3128 (GEMM-V grid coverage)
    const int E16 = N_EDGES / 16;              // 1250
    const int E16_PAD = 157 * 8;               // 1256 (GEMM-E grid coverage)
    unsigned short* Xb  = (unsigned short*)alloc((size_t)N_NODES * 256 * 2);
    unsigned short* At  = (unsigned short*)alloc((size_t)M16_PAD * 4096 * 2);
    unsigned short* Et  = (unsigned short*)alloc((size_t)E16_PAD * 4096 * 2);
    unsigned short* Ef  = (unsigned short*)alloc((size_t)N_EDGES * 256 * 2);
    unsigned short* W1h = (unsigned short*)alloc((size_t)16 * 4096 * 2);
    unsigned short* W1l = (unsigned short*)alloc((size_t)16 * 4096 * 2);
    unsigned short* W2h = (unsigned short*)alloc((size_t)16 * 4096 * 2);
    unsigned short* W2l = (unsigned short*)alloc((size_t)16 * 4096 * 2);
    unsigned short* W3h = (unsigned short*)alloc((size_t)8 * 4096 * 2);
    unsigned short* W3l = (unsigned short*)alloc((size_t)8 * 4096 * 2);
    unsigned short* C40 = (unsigned short*)alloc((size_t)N_NODES * 40 * 2);
    unsigned short* E40 = (unsigned short*)alloc((size_t)N_EDGES * 40 * 2);

    // zero the count arrays (adjacent allocs)
    size_t zspan = (size_t)((char*)cnt_v + (size_t)N_NODES * 4 - (char*)cnt_e);
    hipMemsetAsync(cnt_e, 0, zspan, stream);

    // CSR build: rank-assign (1M atomics, X-convert hidden) -> scan (+W converts) -> atomic-free fill
    rank_convX<<<NB_CONVX + 2048, 256, 0, stream>>>(X, Xb, node_idx, edge_idx,
                                                    cnt_e, cnt_v, rank_e, rank_v);
    scan_convW<<<22, 1024, 0, stream>>>(cnt_e, off_e, inv_e, cnt_v, off_v, inv_v,
                                        W1, W1h, W1l, W2, W2h, W2l, W3, W3h, W3l);
    fill_ranked<<<(NNZ_CT + 255) / 256, 256, 0, stream>>>(
        node_idx, edge_idx, rank_e, rank_v, off_e, off_v, csr_e, csr_v);

    dim3 gE_gemm(2, 157);    // GEMM on 20000 edge rows
    dim3 gV_gemm(1, 391);    // GEMM on 50000 node rows (layer 3, 40 cols)
    const int gEw = (N_EDGES + 3) / 4;
    const int gVw = (N_NODES + 3) / 4;

    // layer 1: V->E agg first (commutes with GEMM), GEMM on edges, E->V to row-major
    agg_e256_tiled<<<E16, 256, 0, stream>>>(Xb, Et, off_e, csr_e, inv_e);
    gemm_bf16<<<gE_gemm, 256, 0, stream>>>(Et, W1h, W1l, Ef, N_EDGES, 256, 256);
    agg_v256_row<<<gVw, 256, 0, stream>>>(Ef, Xb, off_v, csr_v, inv_v, b1, N_NODES);

    // layer 2: same; E->V writes tiled (feeds layer-3 GEMM-V)
    agg_e256_tiled<<<E16, 256, 0, stream>>>(Xb, Et, off_e, csr_e, inv_e);
    gemm_bf16<<<gE_gemm, 256, 0, stream>>>(Et, W2h, W2l, Ef, N_EDGES, 256, 256);
    agg_v256_blk<<<M16, 256, 0, stream>>>(Ef, At, off_v, csr_v, inv_v, b2);

    // layer 3: GEMM-V to 40 cols, then 40-dim aggs + log_softmax
    gemm_bf16<<<gV_gemm, 256, 0, stream>>>(At, W3h, W3l, C40, N_NODES, 40, 40);
    agg_mean40<<<gEw, 256, 0, stream>>>(C40, E40, off_e, csr_e, inv_e, N_EDGES);
    agg_v40_lsm<<<gVw, 256, 0, stream>>>(E40, out, off_v, csr_v, inv_v, b3, N_NODES);
    (void)in_sizes; (void)n_in; (void)out_size; (void)ws_size;
}

// Round 8
// 327.327 us; speedup vs baseline: 2.6252x; 1.1138x over previous
//
#include <hip/hip_runtime.h>
#include <math.h>

#define N_NODES 50000
#define N_EDGES 20000
#define NNZ_CT  500000
#define KDIM    256
#define K32     8

#define NB_RANK 62          // rank blocks; CHUNK*NB_RANK >= NNZ
#define CHUNK   8192        // items per rank block (pow2: b = i>>13)
#define EW      5000        // edge hist words (20000/4)
#define VW      12500       // node hist words (50000/4)

typedef __attribute__((ext_vector_type(8))) short    short8v;
typedef __attribute__((ext_vector_type(4))) float    f32x4;
typedef __attribute__((ext_vector_type(8))) unsigned short ushort8v;
typedef __attribute__((ext_vector_type(4))) unsigned short ushort4v;

#define GLD16(g, l) __builtin_amdgcn_global_load_lds( \
    (const __attribute__((address_space(1))) unsigned int*)(g), \
    (__attribute__((address_space(3))) unsigned int*)(l), 16, 0, 0)

__device__ __forceinline__ unsigned short bf16_rne(float f) {
    unsigned u = __float_as_uint(f);
    return (unsigned short)((u + 0x7FFFu + ((u >> 16) & 1u)) >> 16);
}
__device__ __forceinline__ float bf16_to_f(unsigned short h) {
    return __uint_as_float(((unsigned)h) << 16);
}
__device__ __forceinline__ void bf16_split(float f, unsigned short& h, unsigned short& l) {
    unsigned u = __float_as_uint(f);
    unsigned hb = (u + 0x7FFFu + ((u >> 16) & 1u)) >> 16;
    h = (unsigned short)hb;
    float r = f - __uint_as_float(hb << 16);
    unsigned ru = __float_as_uint(r);
    l = (unsigned short)((ru + 0x7FFFu + ((ru >> 16) & 1u)) >> 16);
}

// ==== K1: LDS-histogram rank assignment — ZERO device atomics ====
// Each block owns a CHUNK of the nnz stream; 8-bit counts packed 4/u32 in LDS.
__global__ __launch_bounds__(256) void rank_lds(
    const int* __restrict__ node_idx, const int* __restrict__ edge_idx,
    unsigned* __restrict__ bhe, unsigned* __restrict__ bhv,
    unsigned char* __restrict__ lrank_e, unsigned char* __restrict__ lrank_v)
{
    __shared__ unsigned hist[VW];
    int b = blockIdx.x;
    int i0 = b * CHUNK;
    int i1 = i0 + CHUNK; if (i1 > NNZ_CT) i1 = NNZ_CT;
    // ---- edges ----
    for (int w = threadIdx.x; w < EW; w += 256) hist[w] = 0;
    __syncthreads();
    for (int i = i0 + threadIdx.x; i < i1; i += 256) {
        int e = edge_idx[i];
        unsigned sh = 8u * (e & 3);
        unsigned old = atomicAdd(&hist[e >> 2], 1u << sh);
        lrank_e[i] = (unsigned char)((old >> sh) & 0xFFu);
    }
    __syncthreads();
    for (int w = threadIdx.x; w < EW; w += 256) bhe[b * EW + w] = hist[w];
    __syncthreads();
    // ---- nodes ----
    for (int w = threadIdx.x; w < VW; w += 256) hist[w] = 0;
    __syncthreads();
    for (int i = i0 + threadIdx.x; i < i1; i += 256) {
        int v = node_idx[i];
        unsigned sh = 8u * (v & 3);
        unsigned old = atomicAdd(&hist[v >> 2], 1u << sh);
        lrank_v[i] = (unsigned char)((old >> sh) & 0xFFu);
    }
    __syncthreads();
    for (int w = threadIdx.x; w < VW; w += 256) bhv[b * VW + w] = hist[w];
}

// ---- device body: fp32 B[K,Ncols] -> fragment-tiled bf16 hi/lo ----
__device__ __forceinline__ void conv_B_body(
    const float* __restrict__ B, unsigned short* __restrict__ Bh,
    unsigned short* __restrict__ Bl, int Ncols, int n16_count, int t)
{
    if (t >= n16_count * 512) return;
    int lane = t & 63, k32 = (t >> 6) & 7, n16 = t >> 9;
    int col = n16 * 16 + (lane & 15);
    int k0  = k32 * 32 + (lane >> 4) * 8;
    ushort8v h, l;
#pragma unroll
    for (int j = 0; j < 8; j++) {
        float f = (col < Ncols) ? B[(size_t)(k0 + j) * Ncols + col] : 0.f;
        unsigned short hh, ll; bf16_split(f, hh, ll); h[j] = hh; l[j] = ll;
    }
    size_t off = (((size_t)n16 * 8 + k32) << 9) + lane * 8;
    *(ushort8v*)(Bh + off) = h;
    *(ushort8v*)(Bl + off) = l;
}

// ==== K2: fused {cross-block bases + totals} + {convert X} + {convert W1/2/3} ====
// blocks [0,69): per-word base/total; [69,6319): convX; [6319,6399): convW
__global__ __launch_bounds__(256) void mid_fuse(
    const unsigned* __restrict__ bhe, const unsigned* __restrict__ bhv,
    unsigned* __restrict__ bbase_e, unsigned* __restrict__ bbase_v,
    int* __restrict__ cnt_e, int* __restrict__ cnt_v,
    const float* __restrict__ X, unsigned short* __restrict__ Xb,
    const float* __restrict__ W1, unsigned short* __restrict__ W1h, unsigned short* __restrict__ W1l,
    const float* __restrict__ W2, unsigned short* __restrict__ W2h, unsigned short* __restrict__ W2l,
    const float* __restrict__ W3, unsigned short* __restrict__ W3h, unsigned short* __restrict__ W3l)
{
    int b0 = blockIdx.x;
    if (b0 < 69) {
        int t = b0 * 256 + threadIdx.x;
        if (t >= EW + VW) return;
        const unsigned* bh; unsigned* bb; int* cnt; int w;
        if (t < EW) { bh = bhe; bb = bbase_e; cnt = cnt_e; w = t; }
        else        { bh = bhv; bb = bbase_v; cnt = cnt_v; w = t - EW; }
        int stride = (t < EW) ? EW : VW;
        unsigned s0 = 0, s1 = 0, s2 = 0, s3 = 0;
#pragma unroll 2
        for (int b = 0; b < NB_RANK; ++b) {
            unsigned h = bh[(size_t)b * stride + w];
            bb[(size_t)b * stride + w] = s0 | (s1 << 8) | (s2 << 16) | (s3 << 24);
            s0 += h & 255u; s1 += (h >> 8) & 255u; s2 += (h >> 16) & 255u; s3 += (h >> 24);
        }
        *(int4*)(cnt + 4 * w) = make_int4((int)s0, (int)s1, (int)s2, (int)s3);
    } else if (b0 < 6319) {
        int t = (b0 - 69) * 256 + threadIdx.x;      // < 1.6M exact
        const float* src = X + (size_t)t * 8;
        float f[8];
        *(float4*)(f)     = *(const float4*)(src);
        *(float4*)(f + 4) = *(const float4*)(src + 4);
        ushort8v h;
#pragma unroll
        for (int j = 0; j < 8; j++) h[j] = bf16_rne(f[j]);
        *(ushort8v*)(Xb + (size_t)t * 8) = h;
    } else {
        int j = b0 - 6319;
        if (j < 32)      conv_B_body(W1, W1h, W1l, 256, 16, j * 256 + (int)threadIdx.x);
        else if (j < 64) conv_B_body(W2, W2h, W2l, 256, 16, (j - 32) * 256 + (int)threadIdx.x);
        else             conv_B_body(W3, W3h, W3l, 40,  8,  (j - 64) * 256 + (int)threadIdx.x);
    }
}

// ==== K3: dual single-pass scans (block 0: edges, block 1: nodes) ====
__global__ __launch_bounds__(1024) void scan_dual(
    const int* __restrict__ cnt_e, int* __restrict__ off_e, float* __restrict__ inv_e,
    const int* __restrict__ cnt_v, int* __restrict__ off_v, float* __restrict__ inv_v)
{
    const int* cnt; int* off; float* inv; int n;
    if (blockIdx.x == 0) { cnt = cnt_e; off = off_e; inv = inv_e; n = N_EDGES; }
    else                 { cnt = cnt_v; off = off_v; inv = inv_v; n = N_NODES; }
    __shared__ int wsum[16];
    __shared__ int carry_s;
    int tid = threadIdx.x, lane = tid & 63, wid = tid >> 6;
    if (tid == 0) carry_s = 0;
    __syncthreads();
    for (int base = 0; base < n; base += 4096) {
        int i4 = base + tid * 4;
        int4 x = make_int4(0, 0, 0, 0);
        if (i4 + 3 < n) x = *(const int4*)(cnt + i4);
        else if (i4 < n) {
            x.x = cnt[i4];
            if (i4 + 1 < n) x.y = cnt[i4 + 1];
            if (i4 + 2 < n) x.z = cnt[i4 + 2];
        }
        int s0 = x.x, s1 = s0 + x.y, s2 = s1 + x.z, s3 = s2 + x.w;
        int incl = s3;
#pragma unroll
        for (int o = 1; o < 64; o <<= 1) { int t = __shfl_up(incl, o, 64); if (lane >= o) incl += t; }
        if (lane == 63) wsum[wid] = incl;
        __syncthreads();
        if (wid == 0) {
            int v = (lane < 16) ? wsum[lane] : 0;
#pragma unroll
            for (int o = 1; o < 16; o <<= 1) { int t = __shfl_up(v, o, 64); if (lane >= o) v += t; }
            if (lane < 16) wsum[lane] = v;
        }
        __syncthreads();
        int wpre = (wid == 0) ? 0 : wsum[wid - 1];
        int carry = carry_s;
        int excl = carry + wpre + incl - s3;
        if (i4 < n) {
            int e0 = excl, e1 = excl + s0, e2 = excl + s1, e3 = excl + s2;
            if (i4 + 3 < n) { *(int4*)(off + i4) = make_int4(e0, e1, e2, e3); }
            else {
                off[i4] = e0;
                if (i4 + 1 < n) off[i4 + 1] = e1;
                if (i4 + 2 < n) off[i4 + 2] = e2;
            }
            inv[i4] = 1.0f / fmaxf((float)x.x, 1.0f);
            if (i4 + 1 < n) inv[i4 + 1] = 1.0f / fmaxf((float)x.y, 1.0f);
            if (i4 + 2 < n) inv[i4 + 2] = 1.0f / fmaxf((float)x.z, 1.0f);
            if (i4 + 3 < n) inv[i4 + 3] = 1.0f / fmaxf((float)x.w, 1.0f);
        }
        __syncthreads();
        if (tid == 1023) carry_s = carry + wpre + incl;
        __syncthreads();
    }
    if (tid == 0) off[n] = carry_s;
}

// ==== K4: atomic-free key-partitioned CSR fill ====
__global__ __launch_bounds__(256) void fill_part(
    const int* __restrict__ node_idx, const int* __restrict__ edge_idx,
    const unsigned char* __restrict__ lrank_e, const unsigned char* __restrict__ lrank_v,
    const unsigned* __restrict__ bbase_e, const unsigned* __restrict__ bbase_v,
    const int* __restrict__ off_e, const int* __restrict__ off_v,
    int* __restrict__ csr_e_nodes, int* __restrict__ csr_v_edges)
{
    int part = blockIdx.x & 7, blk = blockIdx.x >> 3, nblk = gridDim.x >> 3;
    int elo = part * (N_EDGES / 8), ehi = elo + N_EDGES / 8;
    int vlo = part * (N_NODES / 8), vhi = vlo + N_NODES / 8;
    for (int i = blk * 256 + threadIdx.x; i < NNZ_CT; i += nblk * 256) {
        int e = edge_idx[i], v = node_idx[i];
        int b = i >> 13;                    // i / CHUNK
        if (e >= elo && e < ehi) {
            unsigned bb = (bbase_e[(size_t)b * EW + (e >> 2)] >> (8u * (e & 3))) & 0xFFu;
            csr_e_nodes[off_e[e] + (int)bb + (int)lrank_e[i]] = v;
        }
        if (v >= vlo && v < vhi) {
            unsigned bb = (bbase_v[(size_t)b * VW + (v >> 2)] >> (8u * (v & 3))) & 0xFFu;
            csr_v_edges[off_v[v] + (int)bb + (int)lrank_v[i]] = e;
        }
    }
}

// ---- MFMA GEMM: A tiled bf16, B tiled split hi/lo; C bf16 row-major ----
__global__ __launch_bounds__(256) void gemm_bf16(
    const unsigned short* __restrict__ At,
    const unsigned short* __restrict__ Bh, const unsigned short* __restrict__ Bl,
    unsigned short* __restrict__ C, int M, int Ncols, int ldC)
{
    __shared__ unsigned short lds[16384];
    const int tid  = threadIdx.x;
    const int lane = tid & 63, wid = tid >> 6;
    const int wr = wid >> 1, wc = wid & 1;
    const int m0t = blockIdx.y * 8;
    const int n0t = blockIdx.x * 8;

    f32x4 acc[4][4] = {};

    for (int k32 = 0; k32 < K32; ++k32) {
#pragma unroll
        for (int i = 0; i < 6; ++i) {
            int c = i * 4 + wid;               // 0..23
            if (c < 8) {
                const unsigned short* gA = At + (((size_t)(m0t + c) * 8 + k32) << 9) + lane * 8;
                GLD16(gA, &lds[c * 512 + lane * 8]);
            } else {
                int idx = c - 8, half = idx >> 3, st = idx & 7;
                const unsigned short* gB = (half ? Bl : Bh)
                    + (((size_t)(n0t + st) * 8 + k32) << 9) + lane * 8;
                GLD16(gB, &lds[4096 + idx * 512 + lane * 8]);
            }
        }
        __syncthreads();
        short8v a[4], bh[4], bl[4];
#pragma unroll
        for (int x = 0; x < 4; ++x) {
            a[x]  = *(const short8v*)&lds[(wr * 4 + x) * 512 + lane * 8];
            bh[x] = *(const short8v*)&lds[4096 + (wc * 4 + x) * 512 + lane * 8];
            bl[x] = *(const short8v*)&lds[4096 + (8 + wc * 4 + x) * 512 + lane * 8];
        }
#pragma unroll
        for (int mi = 0; mi < 4; ++mi)
#pragma unroll
            for (int ni = 0; ni < 4; ++ni) {
                acc[mi][ni] = __builtin_amdgcn_mfma_f32_16x16x32_bf16(a[mi], bh[ni], acc[mi][ni], 0, 0, 0);
                acc[mi][ni] = __builtin_amdgcn_mfma_f32_16x16x32_bf16(a[mi], bl[ni], acc[mi][ni], 0, 0, 0);
            }
        __syncthreads();
    }

    {
        const int rg = lane >> 4, cl = lane & 15;
        const int base = wid * 4096;
#pragma unroll
        for (int mi = 0; mi < 4; ++mi) {
            int swz = ((mi * 4 + rg) & 3) << 4;
#pragma unroll
            for (int ni = 0; ni < 4; ++ni) {
                int colf = (ni * 16 + cl) ^ swz;
#pragma unroll
                for (int r = 0; r < 4; ++r)
                    lds[base + (mi * 16 + rg * 4 + r) * 64 + colf] = bf16_rne(acc[mi][ni][r]);
            }
        }
    }
    __syncthreads();
    {
        int row = tid >> 1, half = tid & 1;
        int grow = blockIdx.y * 128 + row;
        if (grow < M) {
            int wsrc = (row >> 6) * 2 + half;
            int rl = row & 63;
            int swz = ((rl >> 2) & 3) << 4;
            unsigned short* dst = C + (size_t)grow * ldC + n0t * 16 + half * 64;
#pragma unroll
            for (int s = 0; s < 8; ++s) {
                int c0 = half * 64 + s * 8;
                if (n0t * 16 + c0 + 8 <= Ncols) {
                    ushort8v v = *(const ushort8v*)&lds[wsrc * 4096 + rl * 64 + ((s * 8) ^ swz)];
                    *(ushort8v*)(dst + s * 8) = v;
                }
            }
        }
    }
}

// ---- V->E mean (256-dim) -> fragment-tiled bf16; block = one e16 tile ----
__global__ __launch_bounds__(256) void agg_e256_tiled(
    const unsigned short* __restrict__ src, unsigned short* __restrict__ Et,
    const int* __restrict__ offs, const int* __restrict__ lists,
    const float* __restrict__ invdeg)
{
    __shared__ unsigned short hbuf[16 * 264];
    int tid = threadIdx.x, lane = tid & 63, wid = tid >> 6;
    int e16 = blockIdx.x;
#pragma unroll
    for (int q = 0; q < 4; ++q) {
        int el = wid * 4 + q;
        int w = e16 * 16 + el;
        int s = offs[w], e = offs[w + 1];
        float a0 = 0.f, a1 = 0.f, a2 = 0.f, a3 = 0.f;
        for (int j = s; j < e; j += 8) {
            int r[8]; float m[8];
            r[0] = lists[j]; m[0] = 1.f;
#pragma unroll
            for (int u = 1; u < 8; ++u) {
                bool ok = (j + u) < e;
                r[u] = ok ? lists[j + u] : r[0];
                m[u] = ok ? 1.f : 0.f;
            }
            ushort4v v[8];
#pragma unroll
            for (int u = 0; u < 8; ++u)
                v[u] = *(const ushort4v*)(src + (size_t)r[u] * 256 + lane * 4);
            a0 += bf16_to_f(v[0][0]); a1 += bf16_to_f(v[0][1]);
            a2 += bf16_to_f(v[0][2]); a3 += bf16_to_f(v[0][3]);
#pragma unroll
            for (int u = 1; u < 8; ++u) {
                a0 = fmaf(m[u], bf16_to_f(v[u][0]), a0);
                a1 = fmaf(m[u], bf16_to_f(v[u][1]), a1);
                a2 = fmaf(m[u], bf16_to_f(v[u][2]), a2);
                a3 = fmaf(m[u], bf16_to_f(v[u][3]), a3);
            }
        }
        float sc = invdeg[w];
        ushort4v o;
        o[0] = bf16_rne(a0 * sc); o[1] = bf16_rne(a1 * sc);
        o[2] = bf16_rne(a2 * sc); o[3] = bf16_rne(a3 * sc);
        *(ushort4v*)&hbuf[el * 264 + lane * 4] = o;
    }
    __syncthreads();
#pragma unroll
    for (int u = 0; u < 2; ++u) {
        int sl = tid * 2 + u;
        int k32 = sl >> 6, lt = sl & 63;
        int row = lt & 15, hi = lt >> 4;
        int k0 = k32 * 32 + hi * 8;
        ushort8v v = *(const ushort8v*)&hbuf[row * 264 + k0];
        *(ushort8v*)(Et + (((size_t)e16 * 8 + k32) << 9) + lt * 8) = v;
    }
}

// ---- E->V mean + bias + relu -> row-major bf16; wave per node, 8 in flight ----
__global__ __launch_bounds__(256) void agg_v256_row(
    const unsigned short* __restrict__ src, unsigned short* __restrict__ Vb,
    const int* __restrict__ offs, const int* __restrict__ lists,
    const float* __restrict__ invdeg, const float* __restrict__ bias, int nseg)
{
    int w = (blockIdx.x * 256 + threadIdx.x) >> 6;
    int lane = threadIdx.x & 63;
    if (w >= nseg) return;
    int s = offs[w], e = offs[w + 1];
    float a0 = 0.f, a1 = 0.f, a2 = 0.f, a3 = 0.f;
    for (int j = s; j < e; j += 8) {
        int r[8]; float m[8];
        r[0] = lists[j]; m[0] = 1.f;
#pragma unroll
        for (int u = 1; u < 8; ++u) {
            bool ok = (j + u) < e;
            r[u] = ok ? lists[j + u] : r[0];
            m[u] = ok ? 1.f : 0.f;
        }
        ushort4v v[8];
#pragma unroll
        for (int u = 0; u < 8; ++u)
            v[u] = *(const ushort4v*)(src + (size_t)r[u] * 256 + lane * 4);
        a0 += bf16_to_f(v[0][0]); a1 += bf16_to_f(v[0][1]);
        a2 += bf16_to_f(v[0][2]); a3 += bf16_to_f(v[0][3]);
#pragma unroll
        for (int u = 1; u < 8; ++u) {
            a0 = fmaf(m[u], bf16_to_f(v[u][0]), a0);
            a1 = fmaf(m[u], bf16_to_f(v[u][1]), a1);
            a2 = fmaf(m[u], bf16_to_f(v[u][2]), a2);
            a3 = fmaf(m[u], bf16_to_f(v[u][3]), a3);
        }
    }
    float sc = invdeg[w];
    const float4 b = *(const float4*)(bias + lane * 4);
    ushort4v o;
    o[0] = bf16_rne(fmaxf(a0 * sc + b.x, 0.f));
    o[1] = bf16_rne(fmaxf(a1 * sc + b.y, 0.f));
    o[2] = bf16_rne(fmaxf(a2 * sc + b.z, 0.f));
    o[3] = bf16_rne(fmaxf(a3 * sc + b.w, 0.f));
    *(ushort4v*)(Vb + (size_t)w * 256 + lane * 4) = o;
}

// ---- E->V mean + bias + relu -> fragment-tiled bf16; block = one m16 tile ----
__global__ __launch_bounds__(256) void agg_v256_blk(
    const unsigned short* __restrict__ src, unsigned short* __restrict__ At,
    const int* __restrict__ offs, const int* __restrict__ lists,
    const float* __restrict__ invdeg, const float* __restrict__ bias)
{
    __shared__ unsigned short hbuf[16 * 264];
    int tid = threadIdx.x, lane = tid & 63, wid = tid >> 6;
    int m16 = blockIdx.x;
    const float4 b = *(const float4*)(bias + lane * 4);
#pragma unroll
    for (int q = 0; q < 4; ++q) {
        int nl = wid * 4 + q;
        int w = m16 * 16 + nl;
        int s = offs[w], e = offs[w + 1];
        float a0 = 0.f, a1 = 0.f, a2 = 0.f, a3 = 0.f;
        for (int j = s; j < e; j += 8) {
            int r[8]; float m[8];
            r[0] = lists[j]; m[0] = 1.f;
#pragma unroll
            for (int u = 1; u < 8; ++u) {
                bool ok = (j + u) < e;
                r[u] = ok ? lists[j + u] : r[0];
                m[u] = ok ? 1.f : 0.f;
            }
            ushort4v v[8];
#pragma unroll
            for (int u = 0; u < 8; ++u)
                v[u] = *(const ushort4v*)(src + (size_t)r[u] * 256 + lane * 4);
            a0 += bf16_to_f(v[0][0]); a1 += bf16_to_f(v[0][1]);
            a2 += bf16_to_f(v[0][2]); a3 += bf16_to_f(v[0][3]);
#pragma unroll
            for (int u = 1; u < 8; ++u) {
                a0 = fmaf(m[u], bf16_to_f(v[u][0]), a0);
                a1 = fmaf(m[u], bf16_to_f(v[u][1]), a1);
                a2 = fmaf(m[u], bf16_to_f(v[u][2]), a2);
                a3 = fmaf(m[u], bf16_to_f(v[u][3]), a3);
            }
        }
        float sc = invdeg[w];
        ushort4v o;
        o[0] = bf16_rne(fmaxf(a0 * sc + b.x, 0.f));
        o[1] = bf16_rne(fmaxf(a1 * sc + b.y, 0.f));
        o[2] = bf16_rne(fmaxf(a2 * sc + b.z, 0.f));
        o[3] = bf16_rne(fmaxf(a3 * sc + b.w, 0.f));
        *(ushort4v*)&hbuf[nl * 264 + lane * 4] = o;
    }
    __syncthreads();
#pragma unroll
    for (int u = 0; u < 2; ++u) {
        int sl = tid * 2 + u;
        int k32 = sl >> 6, lt = sl & 63;
        int row = lt & 15, hi = lt >> 4;
        int k0 = k32 * 32 + hi * 8;
        ushort8v v = *(const ushort8v*)&hbuf[row * 264 + k0];
        *(ushort8v*)(At + (((size_t)m16 * 8 + k32) << 9) + lt * 8) = v;
    }
}

// ---- mean-aggregation, F=40 (edges), bf16 in, bf16 out, 8 in flight ----
__global__ __launch_bounds__(256) void agg_mean40(
    const unsigned short* __restrict__ src, unsigned short* __restrict__ dst,
    const int* __restrict__ offs, const int* __restrict__ lists,
    const float* __restrict__ invdeg, int nseg)
{
    int w = (blockIdx.x * 256 + threadIdx.x) >> 6;
    int lane = threadIdx.x & 63;
    if (w >= nseg) return;
    int s = offs[w], e = offs[w + 1];
    if (lane < 40) {
        float acc = 0.f;
        for (int j = s; j < e; j += 8) {
            int r[8]; float m[8];
            r[0] = lists[j]; m[0] = 1.f;
#pragma unroll
            for (int u = 1; u < 8; ++u) {
                bool ok = (j + u) < e;
                r[u] = ok ? lists[j + u] : r[0];
                m[u] = ok ? 1.f : 0.f;
            }
            float v[8];
#pragma unroll
            for (int u = 0; u < 8; ++u)
                v[u] = bf16_to_f(src[(size_t)r[u] * 40 + lane]);
            acc += v[0];
#pragma unroll
            for (int u = 1; u < 8; ++u) acc = fmaf(m[u], v[u], acc);
        }
        dst[(size_t)w * 40 + lane] = bf16_rne(acc * invdeg[w]);
    }
}

// ------- final E->V mean at F=40 + bias + log_softmax, wave per node -------
__global__ __launch_bounds__(256) void agg_v40_lsm(
    const unsigned short* __restrict__ efeat, float* __restrict__ out,
    const int* __restrict__ offs, const int* __restrict__ lists,
    const float* __restrict__ invdeg, const float* __restrict__ bias,
    int nseg)
{
    int w = (blockIdx.x * 256 + threadIdx.x) >> 6;
    int lane = threadIdx.x & 63;
    if (w >= nseg) return;
    int s = offs[w], e = offs[w + 1];
    float acc = 0.f;
    if (lane < 40) {
        for (int j = s; j < e; j += 4) {
            int r[4]; float m[4];
            r[0] = lists[j]; m[0] = 1.f;
#pragma unroll
            for (int u = 1; u < 4; ++u) {
                bool ok = (j + u) < e;
                r[u] = ok ? lists[j + u] : r[0];
                m[u] = ok ? 1.f : 0.f;
            }
            float v[4];
#pragma unroll
            for (int u = 0; u < 4; ++u)
                v[u] = bf16_to_f(efeat[(size_t)r[u] * 40 + lane]);
            acc += v[0];
#pragma unroll
            for (int u = 1; u < 4; ++u) acc = fmaf(m[u], v[u], acc);
        }
    }
    float val = (lane < 40) ? (acc * invdeg[w] + bias[lane]) : -1e30f;
    float m = val;
#pragma unroll
    for (int o = 32; o; o >>= 1) m = fmaxf(m, __shfl_xor(m, o));
    float ex = (lane < 40) ? expf(val - m) : 0.f;
    float ssum = ex;
#pragma unroll
    for (int o = 32; o; o >>= 1) ssum += __shfl_xor(ssum, o);
    if (lane < 40) out[(size_t)w * 40 + lane] = val - m - logf(ssum);
}

// ---------------- launch ----------------
extern "C" void kernel_launch(void* const* d_in, const int* in_sizes, int n_in,
                              void* d_out, int out_size, void* d_ws, size_t ws_size,
                              hipStream_t stream)
{
    const float* X        = (const float*)d_in[0];
    const int*   node_idx = (const int*)d_in[1];
    const int*   edge_idx = (const int*)d_in[2];
    const float* W1 = (const float*)d_in[3];
    const float* b1 = (const float*)d_in[4];
    const float* W2 = (const float*)d_in[5];
    const float* b2 = (const float*)d_in[6];
    const float* W3 = (const float*)d_in[7];
    const float* b3 = (const float*)d_in[8];
    float* out = (float*)d_out;

    char* p = (char*)d_ws;
    auto alloc = [&](size_t bytes) -> char* {
        char* r = p;
        p += (bytes + 255) & ~(size_t)255;
        return r;
    };
    int*   cnt_e = (int*)alloc((size_t)N_EDGES * 4);
    int*   cnt_v = (int*)alloc((size_t)N_NODES * 4);
    int*   off_e = (int*)alloc((size_t)(N_EDGES + 1) * 4);
    int*   off_v = (int*)alloc((size_t)(N_NODES + 1) * 4);
    float* inv_e = (float*)alloc((size_t)N_EDGES * 4);
    float* inv_v = (float*)alloc((size_t)N_NODES * 4);
    unsigned* bhe = (unsigned*)alloc((size_t)NB_RANK * EW * 4);
    unsigned* bhv = (unsigned*)alloc((size_t)NB_RANK * VW * 4);
    unsigned* bbase_e = (unsigned*)alloc((size_t)NB_RANK * EW * 4);
    unsigned* bbase_v = (unsigned*)alloc((size_t)NB_RANK * VW * 4);
    unsigned char* lrank_e = (unsigned char*)alloc((size_t)NNZ_CT);
    unsigned char* lrank_v = (unsigned char*)alloc((size_t)NNZ_CT);
    int*   csr_e = (int*)alloc((size_t)NNZ_CT * 4);
    int*   csr_v = (int*)alloc((size_t)NNZ_CT * 4);

    const int M16 = N_NODES / 16;              // 3125
    const int M16_PAD = 391 * 8;               // 3128 (GEMM-V grid coverage)
    const int E16 = N_EDGES / 16;              // 1250
    const int E16_PAD = 157 * 8;               // 1256 (GEMM-E grid coverage)
    unsigned short* Xb  = (unsigned short*)alloc((size_t)N_NODES * 256 * 2);
    unsigned short* At  = (unsigned short*)alloc((size_t)M16_PAD * 4096 * 2);
    unsigned short* Et  = (unsigned short*)alloc((size_t)E16_PAD * 4096 * 2);
    unsigned short* Ef  = (unsigned short*)alloc((size_t)N_EDGES * 256 * 2);
    unsigned short* W1h = (unsigned short*)alloc((size_t)16 * 4096 * 2);
    unsigned short* W1l = (unsigned short*)alloc((size_t)16 * 4096 * 2);
    unsigned short* W2h = (unsigned short*)alloc((size_t)16 * 4096 * 2);
    unsigned short* W2l = (unsigned short*)alloc((size_t)16 * 4096 * 2);
    unsigned short* W3h = (unsigned short*)alloc((size_t)8 * 4096 * 2);
    unsigned short* W3l = (unsigned short*)alloc((size_t)8 * 4096 * 2);
    unsigned short* C40 = (unsigned short*)alloc((size_t)N_NODES * 40 * 2);
    unsigned short* E40 = (unsigned short*)alloc((size_t)N_EDGES * 40 * 2);

    // CSR build: LDS-hist ranks (0 device atomics) -> bases+converts -> scan -> atomic-free fill
    rank_lds<<<NB_RANK, 256, 0, stream>>>(node_idx, edge_idx, bhe, bhv, lrank_e, lrank_v);
    mid_fuse<<<6399, 256, 0, stream>>>(bhe, bhv, bbase_e, bbase_v, cnt_e, cnt_v,
                                       X, Xb, W1, W1h, W1l, W2, W2h, W2l, W3, W3h, W3l);
    scan_dual<<<2, 1024, 0, stream>>>(cnt_e, off_e, inv_e, cnt_v, off_v, inv_v);
    fill_part<<<2048, 256, 0, stream>>>(node_idx, edge_idx, lrank_e, lrank_v,
                                        bbase_e, bbase_v, off_e, off_v, csr_e, csr_v);

    dim3 gE_gemm(2, 157);    // GEMM on 20000 edge rows
    dim3 gV_gemm(1, 391);    // GEMM on 50000 node rows (layer 3, 40 cols)
    const int gEw = (N_EDGES + 3) / 4;
    const int gVw = (N_NODES + 3) / 4;

    // layer 1: V->E agg first (commutes with GEMM), GEMM on edges, E->V to row-major
    agg_e256_tiled<<<E16, 256, 0, stream>>>(Xb, Et, off_e, csr_e, inv_e);
    gemm_bf16<<<gE_gemm, 256, 0, stream>>>(Et, W1h, W1l, Ef, N_EDGES, 256, 256);
    agg_v256_row<<<gVw, 256, 0, stream>>>(Ef, Xb, off_v, csr_v, inv_v, b1, N_NODES);

    // layer 2: same; E->V writes tiled (feeds layer-3 GEMM-V)
    agg_e256_tiled<<<E16, 256, 0, stream>>>(Xb, Et, off_e, csr_e, inv_e);
    gemm_bf16<<<gE_gemm, 256, 0, stream>>>(Et, W2h, W2l, Ef, N_EDGES, 256, 256);
    agg_v256_blk<<<M16, 256, 0, stream>>>(Ef, At, off_v, csr_v, inv_v, b2);

    // layer 3: GEMM-V to 40 cols, then 40-dim aggs + log_softmax
    gemm_bf16<<<gV_gemm, 256, 0, stream>>>(At, W3h, W3l, C40, N_NODES, 40, 40);
    agg_mean40<<<gEw, 256, 0, stream>>>(C40, E40, off_e, csr_e, inv_e, N_EDGES);
    agg_v40_lsm<<<gVw, 256, 0, stream>>>(E40, out, off_v, csr_v, inv_v, b3, N_NODES);
    (void)in_sizes; (void)n_in; (void)out_size; (void)ws_size;
}